// Round 8
// baseline (588.405 us; speedup 1.0000x reference)
//
#include <hip/hip_runtime.h>

typedef unsigned short u16;
typedef __attribute__((ext_vector_type(4))) float floatx4;
typedef __attribute__((ext_vector_type(8))) short shortx8;
typedef __attribute__((ext_vector_type(4))) short shortx4;

#define NOPS 8192
#define NMS  512
#define CQ   2560   // op qkv cols: q | k0 | v0 | k2 | v2
#define CM   1536   // machine qkv cols: q | k1 | v1
#define TOPC (NOPS*512)
#define TMC  (NMS*512)

__device__ __forceinline__ float bf2f(u16 u){ return __uint_as_float(((unsigned)u)<<16); }
__device__ __forceinline__ u16 f2bf(float f){
  unsigned u = __float_as_uint(f);
  u += 0x7FFFu + ((u>>16)&1u);
  return (u16)(u>>16);
}
__device__ __forceinline__ float wred(float v){
  #pragma unroll
  for (int o=32;o;o>>=1) v += __shfl_xor(v,o,64);
  return v;
}
__device__ __forceinline__ float geluf(float x){
  return 0.5f*x*(1.f+erff(x*0.70710678118654752f));
}
// block (s,s2) reduction -> one pair at pstat[slot]
__device__ __forceinline__ void block_stat_out2(float s, float s2, float* pstat, int slot){
  __shared__ float sb[8];
  s = wred(s); s2 = wred(s2);
  int wv = threadIdx.x >> 6;
  if ((threadIdx.x & 63) == 0){ sb[wv*2] = s; sb[wv*2+1] = s2; }
  __syncthreads();
  if (threadIdx.x == 0){
    float a = 0.f, b = 0.f;
    int nw = blockDim.x >> 6;
    for (int i=0;i<nw;++i){ a += sb[i*2]; b += sb[i*2+1]; }
    pstat[slot*2]   = a;
    pstat[slot*2+1] = b;
  }
}

// ---------------- mega setup: cnt2 | qb | cbias | tw | combine3 | embed2 (all independent) ----------------
// blocks: [0,2048) cnt2 ; [2048,2060) qb ; [2060,2204) cbias ; [2204,2972) tw ;
//         [2972,3548) combine3 ; [3548,4700) embed2
__global__ __launch_bounds__(256) void setup_all_k(
    const int* __restrict__ s1, float* __restrict__ Ct, float* __restrict__ Cn,
    const float* __restrict__ bq, float* bias_op, float* bias_m,
    const float* __restrict__ bk, const float* __restrict__ bv,
    const float* __restrict__ Ar, const float* __restrict__ Mr,
    const float* __restrict__ Wout, const float* __restrict__ Wq,
    u16* __restrict__ Wout_t, u16* __restrict__ Wc_op_t, u16* __restrict__ Wc_m_t,
    const float* __restrict__ Wk, const float* __restrict__ Wv,
    const float* __restrict__ Xop, const float* __restrict__ Wop, const float* __restrict__ bop,
    float* __restrict__ Yop, u16* __restrict__ Yop_bf,
    const float* __restrict__ Xm, const float* __restrict__ Wm, const float* __restrict__ bm_,
    float* __restrict__ Ym, u16* __restrict__ Ym_bf,
    float* pstat, float* pstat_m){
  __shared__ __align__(16) char smem[27648];
  int bid = blockIdx.x;
  int tid = threadIdx.x;
  if (bid < 2048){
    int idx = bid*256 + tid;      // 524288
    int n = idx >> 6, l = idx & 63;
    const int* row = s1 + n*8;
    int cnt = 0;
    #pragma unroll
    for (int j=0;j<8;++j) cnt += ((row[j] & 63) == l);
    float f = (float)cnt;
    Cn[(size_t)n*64 + l] = f;
    int b = n >> 10, nl = n & 1023;
    Ct[(size_t)((b<<6) + l)*1024 + nl] = f;
  } else if (bid < 2060){
    int i = (bid-2048)*256 + tid;   // < 3072
    int l = i >> 10, side = (i >> 9) & 1, f = i & 511;
    float v = bq[(l*2+side)*512 + f];
    if (side==0) bias_op[l*CQ + f] = v; else bias_m[l*CM + f] = v;
  } else if (bid < 2204){
    if (tid >= 64) return;
    int gx = bid - 2060; int e = tid;
    int l = gx/48; int rem = gx - l*48; int s = rem >> 3; int h = rem & 7;
    int side = (s < 4) ? 0 : 1;
    int r = (s < 4) ? (s+1) : (s-3);
    int useK = side==0 ? (s==0 || s==2) : (s==4);
    int rel  = side==0 ? ((s<2)?0:2) : 1;
    const float* bb  = (useK ? bk : bv) + (size_t)(l*2+side)*512 + h*64;
    const float* Rel = (useK ? Ar : Mr) + ((size_t)(l*3+rel)*8 + h)*4096;
    float acc = 0.f;
    for (int d=0; d<64; ++d) acc += bb[d]*Rel[d*64 + e];
    float* bias = side ? (bias_m + l*CM) : (bias_op + l*CQ);
    bias[r*512 + h*64 + e] = acc;
  } else if (bid < 2972){
    // tw: transpose W_out (6 slabs) + Wq (6 slabs)
    u16 (*t)[65] = (u16(*)[65])smem;
    int id2 = bid - 2204;
    int g = id2 >> 6; int rem = id2 & 63;
    int kb = (rem >> 3) * 64, nb = (rem & 7) * 64;
    const float* s; u16* d;
    if (g < 6){
      s = Wout + (size_t)g*262144;
      d = Wout_t + (size_t)g*262144;
    } else {
      int blk = g - 6; int l = blk >> 1, side = blk & 1;
      s = Wq + (size_t)blk*262144;
      d = side ? (Wc_m_t + (size_t)l*CM*512) : (Wc_op_t + (size_t)l*CQ*512);
    }
    int tx = tid & 63, ty4 = tid >> 6;
    #pragma unroll 4
    for (int p=0;p<16;++p){
      int k = ty4 + p*4;
      t[k][tx] = f2bf(s[(size_t)(kb+k)*512 + nb + tx]);
    }
    __syncthreads();
    #pragma unroll 4
    for (int p=0;p<16;++p){
      int n = ty4 + p*4;
      d[(size_t)(nb+n)*512 + kb + tx] = t[tx][n];
    }
  } else if (bid < 3548){
    // combine3: relation combine via MFMA
    u16* As = (u16*)smem;          // 64*72
    u16* Bs = As + 64*72;          // 128*72
    int id3 = bid - 2972;
    int gx = id3 >> 2;
    int cc0 = (id3 & 3) * 128;
    int l = gx/48; int rem = gx - l*48; int s = rem >> 3; int h = rem & 7;
    int side = (s < 4) ? 0 : 1;
    int r = (s < 4) ? (s+1) : (s-3);
    int useK = side==0 ? (s==0 || s==2) : (s==4);
    int rel  = side==0 ? ((s<2)?0:2) : 1;
    const float* W   = (useK ? Wk : Wv) + (size_t)(l*2+side)*262144;
    const float* Rel = (useK ? Ar : Mr) + ((size_t)(l*3+rel)*8 + h)*4096;
    int h64 = h*64;
    u16* Wt = side ? (Wc_m_t + (size_t)l*CM*512) : (Wc_op_t + (size_t)l*CQ*512);
    int rbase = r*512 + h64;
    int lane = tid & 63, wave = tid >> 6;
    {
      int d = tid >> 2, e0 = (tid & 3) * 16;
      #pragma unroll
      for (int j=0;j<16;++j) As[(e0+j)*72 + d] = f2bf(Rel[d*64 + e0 + j]);
    }
    {
      int ccl = tid >> 1, d0 = (tid & 1) * 32;
      const float* src = W + (size_t)(cc0+ccl)*512 + h64 + d0;
      #pragma unroll
      for (int j=0;j<32;j+=4){
        floatx4 v = *(const floatx4*)(src + j);
        shortx4 sv;
        #pragma unroll
        for (int e=0;e<4;++e) sv[e] = (short)f2bf(v[e]);
        *(shortx4*)(Bs + ccl*72 + d0 + j) = sv;
      }
    }
    __syncthreads();
    int wm = wave & 1, wn = wave >> 1;
    int mrow = lane & 15, quad = lane >> 4;
    floatx4 acc[2][4];
    #pragma unroll
    for (int a=0;a<2;++a)
      #pragma unroll
      for (int b=0;b<4;++b) acc[a][b] = (floatx4){0.f,0.f,0.f,0.f};
    #pragma unroll
    for (int ks=0; ks<2; ++ks){
      shortx8 af[2], bf[4];
      #pragma unroll
      for (int mt=0;mt<2;++mt) af[mt] = *(const shortx8*)(As + (wm*32 + mt*16 + mrow)*72 + ks*32 + quad*8);
      #pragma unroll
      for (int nt=0;nt<4;++nt) bf[nt] = *(const shortx8*)(Bs + (wn*64 + nt*16 + mrow)*72 + ks*32 + quad*8);
      #pragma unroll
      for (int mt=0;mt<2;++mt)
        #pragma unroll
        for (int nt=0;nt<4;++nt)
          acc[mt][nt] = __builtin_amdgcn_mfma_f32_16x16x32_bf16(af[mt], bf[nt], acc[mt][nt], 0, 0, 0);
    }
    #pragma unroll
    for (int mt=0;mt<2;++mt){
      #pragma unroll
      for (int nt=0;nt<4;++nt){
        int ccl = wn*64 + nt*16 + mrow;
        #pragma unroll
        for (int r2=0;r2<4;++r2){
          int e = wm*32 + mt*16 + quad*4 + r2;
          Wt[(size_t)(rbase + e)*512 + cc0 + ccl] = f2bf(acc[mt][nt][r2]);
        }
      }
    }
  } else {
    // embed2: op [3548,4572) / m [4572,4700)
    int eb = bid - 3548;
    const float *X, *W, *bias; float *Y, *ps; u16* Yb; int K, total, nb, lb;
    if (eb < 1024){ X=Xop; W=Wop; bias=bop; Y=Yop; Yb=Yop_bf; ps=pstat;   K=16; total=TOPC; nb=1024; lb=eb; }
    else          { X=Xm;  W=Wm;  bias=bm_; Y=Ym;  Yb=Ym_bf;  ps=pstat_m; K=8;  total=TMC;  nb=128;  lb=eb-1024; }
    float s = 0.f, s2 = 0.f;
    for (int idx = lb*256 + tid; idx < total; idx += nb*256){
      int n = idx >> 9, f = idx & 511;
      float v = bias[f];
      for (int c=0;c<K;++c) v += X[n*K+c] * W[c*512+f];
      Y[idx] = v;
      Yb[idx] = f2bf(v);
      s += v; s2 += v*v;
    }
    block_stat_out2(s, s2, ps, lb);
  }
}

// ---------------- LN fold: u=w@Wc, bias+=b@Wc, Wt *= w (in place) ----------------
// grid 192: [0,120) op rows (3*2560, 64/block); [120,192) m rows (3*1536)
__global__ __launch_bounds__(256) void foldk(u16* __restrict__ Wc_op_t, u16* __restrict__ Wc_m_t,
                                             float* __restrict__ bias_op, float* __restrict__ bias_m,
                                             float* __restrict__ u_op, float* __restrict__ u_m,
                                             const float* __restrict__ opn_w, const float* __restrict__ opn_b,
                                             const float* __restrict__ mn_w, const float* __restrict__ mn_b,
                                             const float* __restrict__ ln_w, const float* __restrict__ ln_b){
  int bid = blockIdx.x, tid = threadIdx.x;
  int rloc = tid >> 2, t = tid & 3;
  int side, l; u16* Wt; float* bias; float* u;
  if (bid < 120){
    int row = bid*64 + rloc; side = 0; l = row/2560; int j = row - l*2560;
    Wt = Wc_op_t + ((size_t)l*CQ + j)*512; bias = bias_op + l*CQ + j; u = u_op + l*CQ + j;
  } else {
    int row = (bid-120)*64 + rloc; side = 1; l = row/1536; int j = row - l*1536;
    Wt = Wc_m_t + ((size_t)l*CM + j)*512; bias = bias_m + l*CM + j; u = u_m + l*CM + j;
  }
  const float* w = side ? (l==0 ? mn_w : ln_w + (l-1)*512) : (l==0 ? opn_w : ln_w + (l-1)*512);
  const float* b = side ? (l==0 ? mn_b : ln_b + (l-1)*512) : (l==0 ? opn_b : ln_b + (l-1)*512);
  float up = 0.f, vp = 0.f;
  for (int k = t*128; k < t*128 + 128; k += 8){
    shortx8 wv = *(shortx8*)(Wt + k);
    #pragma unroll
    for (int e=0;e<8;++e){
      float x = bf2f((u16)wv[e]);
      float wk = w[k+e];
      up += wk*x; vp += b[k+e]*x;
      wv[e] = (short)f2bf(x*wk);
    }
    *(shortx8*)(Wt + k) = wv;
  }
  up += __shfl_xor(up,1,64); up += __shfl_xor(up,2,64);
  vp += __shfl_xor(vp,1,64); vp += __shfl_xor(vp,2,64);
  if (t == 0){ *u = up; *bias += vp; }
}

// ---------------- final graph-LN apply (used once, writes `out`) ----------------
__global__ __launch_bounds__(256) void ln2_k(const float* __restrict__ src_op, float* __restrict__ dst_op,
                                             const float* __restrict__ w_op, const float* __restrict__ b_op,
                                             const float* __restrict__ src_m, float* __restrict__ dst_m,
                                             const float* __restrict__ w_m, const float* __restrict__ b_m,
                                             const float* __restrict__ pstat, const float* __restrict__ pstat_m,
                                             int nbo, int nbm){
  int bid = blockIdx.x;
  const float *src, *w, *b, *ps; float* dst; int total4, nb, lb, nblk; float inv_n;
  if (bid < 1024){ src=src_op; dst=dst_op; w=w_op; b=b_op; ps=pstat;
                   total4=TOPC/4; nb=1024; lb=bid; nblk=nbo; inv_n=1.f/TOPC; }
  else           { src=src_m;  dst=dst_m;  w=w_m;  b=b_m;  ps=pstat_m;
                   total4=TMC/4;  nb=128;  lb=bid-1024; nblk=nbm; inv_n=1.f/TMC; }
  __shared__ float sb[8];
  __shared__ float mr[2];
  float s = 0.f, s2 = 0.f;
  for (int i = threadIdx.x; i < nblk; i += 256){ s += ps[2*i]; s2 += ps[2*i+1]; }
  s = wred(s); s2 = wred(s2);
  int wv = threadIdx.x >> 6;
  if ((threadIdx.x & 63) == 0){ sb[wv*2] = s; sb[wv*2+1] = s2; }
  __syncthreads();
  if (threadIdx.x == 0){
    float a = 0.f, bsum = 0.f;
    for (int i=0;i<4;++i){ a += sb[i*2]; bsum += sb[i*2+1]; }
    float mean = a * inv_n;
    float var  = fmaxf(bsum * inv_n - mean*mean, 0.f);
    mr[0] = mean;
    mr[1] = 1.f/(sqrtf(var) + 1e-5f);
  }
  __syncthreads();
  float mean = mr[0], rinv = mr[1];
  const floatx4* s4 = (const floatx4*)src;
  floatx4* d4 = (floatx4*)dst;
  const floatx4* w4 = (const floatx4*)w;
  const floatx4* b4 = (const floatx4*)b;
  for (int i = lb*256 + threadIdx.x; i < total4; i += nb*256){
    int f = i & 127;
    floatx4 v = s4[i], wv2 = w4[f], bv = b4[f];
    #pragma unroll
    for (int e=0;e<4;++e) v[e] = (v[e]-mean)*rinv*wv2[e] + bv[e];
    d4[i] = v;
  }
}

// ---------------- W_out GEMM + gated residual (LN-affine on x) + f32/bf16 out + LN partials ----------------
__device__ __forceinline__ void gemm_gate_core(u16* As, u16* Bs, float* stb,
                                               const u16* __restrict__ A, const u16* __restrict__ Bt,
                                               const float* __restrict__ xr, const float* __restrict__ bo,
                                               const float* __restrict__ sk,
                                               const float* __restrict__ lnw, const float* __restrict__ lnb,
                                               const float* __restrict__ psr, int np, float inv_n,
                                               float* __restrict__ Y, u16* __restrict__ Ybf,
                                               float* pstat, int slot, int bx, int by){
  const int tid = threadIdx.x;
  const int lane = tid & 63, wave = tid >> 6;
  // ---- stats of previous-layer pre-LN tensor ----
  {
    float s = 0.f, s2 = 0.f;
    for (int i = tid; i < np; i += 256){ s += psr[2*i]; s2 += psr[2*i+1]; }
    s = wred(s); s2 = wred(s2);
    if (lane == 0){ stb[wave*2] = s; stb[wave*2+1] = s2; }
    __syncthreads();
    if (tid == 0){
      float a = 0.f, bb = 0.f;
      for (int i=0;i<4;++i){ a += stb[2*i]; bb += stb[2*i+1]; }
      float mean = a * inv_n;
      float var = fmaxf(bb * inv_n - mean*mean, 0.f);
      stb[8] = mean;
      stb[9] = 1.f/(sqrtf(var) + 1e-5f);
    }
    __syncthreads();
  }
  const float mean = stb[8], rinv = stb[9];
  const int bm = by * 128, bn = bx * 128;
  const int wm = wave & 1, wn = wave >> 1;
  const int mrow = lane & 15, quad = lane >> 4;
  const u16* Ab = A + (size_t)bm*512;
  const u16* Bb = Bt + (size_t)bn*512;
  floatx4 acc[4][4];
  #pragma unroll
  for (int a=0;a<4;++a)
    #pragma unroll
    for (int b=0;b<4;++b) acc[a][b] = (floatx4){0.f,0.f,0.f,0.f};
  const int r0 = tid >> 2, c0 = (tid & 3) * 8;
  const int r1 = (tid+256) >> 2, c1 = ((tid+256) & 3) * 8;
  const int lds0 = wave*512;
  const int lds1 = wave*512 + 2048;
  for (int k0 = 0; k0 < 512; k0 += 32){
    __builtin_amdgcn_global_load_lds((const __attribute__((address_space(1))) void*)(Ab + (size_t)r0*512 + k0 + c0),
                                     (__attribute__((address_space(3))) void*)(As + lds0), 16, 0, 0);
    __builtin_amdgcn_global_load_lds((const __attribute__((address_space(1))) void*)(Ab + (size_t)r1*512 + k0 + c1),
                                     (__attribute__((address_space(3))) void*)(As + lds1), 16, 0, 0);
    __builtin_amdgcn_global_load_lds((const __attribute__((address_space(1))) void*)(Bb + (size_t)r0*512 + k0 + c0),
                                     (__attribute__((address_space(3))) void*)(Bs + lds0), 16, 0, 0);
    __builtin_amdgcn_global_load_lds((const __attribute__((address_space(1))) void*)(Bb + (size_t)r1*512 + k0 + c1),
                                     (__attribute__((address_space(3))) void*)(Bs + lds1), 16, 0, 0);
    __syncthreads();
    shortx8 af[4], bf[4];
    #pragma unroll
    for (int mt=0;mt<4;++mt) af[mt] = *(const shortx8*)(As + (wm*64 + mt*16 + mrow)*32 + quad*8);
    #pragma unroll
    for (int nt=0;nt<4;++nt) bf[nt] = *(const shortx8*)(Bs + (wn*64 + nt*16 + mrow)*32 + quad*8);
    #pragma unroll
    for (int mt=0;mt<4;++mt)
      #pragma unroll
      for (int nt=0;nt<4;++nt)
        acc[mt][nt] = __builtin_amdgcn_mfma_f32_16x16x32_bf16(af[mt], bf[nt], acc[mt][nt], 0, 0, 0);
    __syncthreads();
  }
  float g = 1.f/(1.f+expf(-(*sk)));
  float s = 0.f, s2 = 0.f;
  #pragma unroll
  for (int mt=0;mt<4;++mt){
    #pragma unroll
    for (int nt=0;nt<4;++nt){
      int col = bn + wn*64 + nt*16 + mrow;
      float bval = bo[col];
      float lw = lnw[col]*rinv, lb = lnb[col];
      #pragma unroll
      for (int r2=0;r2<4;++r2){
        int row = bm + wm*64 + mt*16 + quad*4 + r2;
        float v = acc[mt][nt][r2] + bval;
        float xv = (xr[(size_t)row*512 + col] - mean)*lw + lb;   // x = LN(prev)
        float o = g*v + (2.f-g)*xv;
        Y[(size_t)row*512 + col] = o;
        Ybf[(size_t)row*512 + col] = f2bf(o);
        s += o; s2 += o*o;
      }
    }
  }
  block_stat_out2(s, s2, pstat, slot);
}
__global__ __launch_bounds__(256) void gemmgate2_k(
    const u16* A1, const u16* B1, const float* x1, const float* bo1, const float* sk1,
    const float* lnw1, const float* lnb1, float* Y1, u16* Yb1, float* ps1w, int nblk1,
    const u16* A2, const u16* B2, const float* x2, const float* bo2, const float* sk2,
    const float* lnw2, const float* lnb2, float* Y2, u16* Yb2, float* ps2w,
    const float* ps1r, int np1, const float* ps2r, int np2){
  __shared__ u16 As[128*32];
  __shared__ u16 Bs[128*32];
  __shared__ float stb[12];
  int id = blockIdx.x;
  if (id < nblk1)
    gemm_gate_core(As, Bs, stb, A1, B1, x1, bo1, sk1, lnw1, lnb1, ps1r, np1, 1.f/TOPC,
                   Y1, Yb1, ps1w, id, id % 4, id / 4);
  else {
    int j = id - nblk1;
    gemm_gate_core(As, Bs, stb, A2, B2, x2, bo2, sk2, lnw2, lnb2, ps2r, np2, 1.f/TMC,
                   Y2, Yb2, ps2w, j, j % 4, j / 4);
  }
}

// ---------------- 256x256 8-phase GEMM (QKV projections), K=512, LN folded ----------------
__device__ __forceinline__ void stage_half8(const u16* __restrict__ src, int kc, u16* region, int tid){
  int wave = tid >> 6;
  #pragma unroll
  for (int j=0;j<2;++j){
    int idx = j*512 + tid;
    int row = idx >> 2, qp2 = idx & 3;
    int qs = qp2 ^ (((row >> 3) & 1) << 1);   // st_16x32 pre-swizzled global source
    __builtin_amdgcn_global_load_lds(
      (const __attribute__((address_space(1))) void*)(src + (size_t)row*512 + kc + qs*8),
      (__attribute__((address_space(3))) void*)(region + (j*512 + wave*64)*8),
      16, 0, 0);
  }
}

#define MFMA_QUAD(MH) do { \
  __builtin_amdgcn_s_barrier(); \
  asm volatile("s_waitcnt lgkmcnt(0)" ::: "memory"); \
  __builtin_amdgcn_sched_barrier(0); \
  __builtin_amdgcn_s_setprio(1); \
  _Pragma("unroll") \
  for (int mt=0;mt<4;++mt){ \
    _Pragma("unroll") \
    for (int nt=0;nt<4;++nt) \
      acc[(MH)*4+mt][nt] = __builtin_amdgcn_mfma_f32_16x16x32_bf16(af[mt], bf[nt], acc[(MH)*4+mt][nt], 0, 0, 0); \
  } \
  __builtin_amdgcn_s_setprio(0); \
} while(0)

__global__ __launch_bounds__(512, 2) void gemm8_k(
    const u16* __restrict__ A1, const u16* __restrict__ B1, const float* __restrict__ bias1,
    const float* __restrict__ u1, u16* __restrict__ C1, int N1, int nbx1, int nblk1,
    const u16* __restrict__ A2, const u16* __restrict__ B2, const float* __restrict__ bias2p,
    const float* __restrict__ u2, u16* __restrict__ C2, int N2, int nbx2,
    const float* __restrict__ ps1, int np1, const float* __restrict__ ps2, int np2){
  extern __shared__ u16 lds[];      // 131072 B staging + 64 B stats scratch
  float* statsh = (float*)(lds + 65536);
  int id = blockIdx.x;
  const u16 *A, *Bt; const float *bias, *uvec, *ps; u16* C; int N, bx, by, np; float inv_n;
  if (id < nblk1){
    int xcd = id & 7, loc = id >> 3;
    int wg = xcd * (nblk1 >> 3) + loc;
    A=A1; Bt=B1; bias=bias1; uvec=u1; C=C1; N=N1; bx=wg%nbx1; by=wg/nbx1;
    ps=ps1; np=np1; inv_n=1.f/TOPC;
  }
  else { int j=id-nblk1; A=A2; Bt=B2; bias=bias2p; uvec=u2; C=C2; N=N2; bx=j%nbx2; by=j/nbx2;
    ps=ps2; np=np2; inv_n=1.f/TMC; }
  const int tid = threadIdx.x, lane = tid & 63, wave = tid >> 6;
  // ---- stats (mean/rinv of pre-LN A tensor) ----
  {
    float s = 0.f, s2 = 0.f;
    for (int i = tid; i < np; i += 512){ s += ps[2*i]; s2 += ps[2*i+1]; }
    s = wred(s); s2 = wred(s2);
    if (lane == 0){ statsh[wave*2] = s; statsh[wave*2+1] = s2; }
    __syncthreads();
    if (tid == 0){
      float a = 0.f, bb = 0.f;
      for (int i=0;i<8;++i){ a += statsh[2*i]; bb += statsh[2*i+1]; }
      float mean = a * inv_n;
      float var = fmaxf(bb * inv_n - mean*mean, 0.f);
      statsh[16] = mean;
      statsh[17] = 1.f/(sqrtf(var) + 1e-5f);
    }
    __syncthreads();
  }
  const float mean = statsh[16], rinv = statsh[17];
  const int wm = wave & 1, wn = wave >> 1;
  const int mrow = lane & 15, quad = lane >> 4;
  const int qp = quad ^ ((mrow & 8) ? 2 : 0);
  const u16* Ab = A + (size_t)(by*256)*512;
  const u16* Bb = Bt + (size_t)(bx*256)*512;

  floatx4 acc[8][4];
  #pragma unroll
  for (int a=0;a<8;++a)
    #pragma unroll
    for (int b=0;b<4;++b) acc[a][b] = (floatx4){0.f,0.f,0.f,0.f};

  stage_half8(Ab, 0,  lds,          tid);
  stage_half8(Bb, 0,  lds + 16384,  tid);
  stage_half8(Ab, 32, lds + 8192,   tid);
  stage_half8(Bb, 32, lds + 24576,  tid);
  stage_half8(Ab, 64, lds + 32768,  tid);
  stage_half8(Bb, 64, lds + 49152,  tid);
  asm volatile("s_waitcnt vmcnt(8)" ::: "memory");
  __builtin_amdgcn_s_barrier();

  for (int t = 0; t < 8; ++t){
    const int s = t & 1;
    u16* Sbase = lds + s*32768;
    u16* Obase = lds + (s^1)*32768;
    const u16* a0 = Sbase + (wm*128 + mrow)*32 + qp*8;
    const u16* b0 = Sbase + 16384 + (wn*64 + mrow)*32 + qp*8;
    const int kc1 = ((t < 7) ? (t+1) : 7)*64 + 32;
    const int kc2 = ((t < 6) ? (t+2) : 7)*64;
    shortx8 af[4], bf[4];

    #pragma unroll
    for (int mt=0;mt<4;++mt) af[mt] = *(const shortx8*)(a0 + mt*512);
    #pragma unroll
    for (int nt=0;nt<4;++nt) bf[nt] = *(const shortx8*)(b0 + nt*512);
    stage_half8(Ab, kc1, Obase + 8192, tid);
    MFMA_QUAD(0);
    __builtin_amdgcn_s_barrier();

    #pragma unroll
    for (int mt=0;mt<4;++mt) af[mt] = *(const shortx8*)(a0 + 2048 + mt*512);
    stage_half8(Bb, kc1, Obase + 24576, tid);
    MFMA_QUAD(1);
    asm volatile("s_waitcnt vmcnt(8)" ::: "memory");
    __builtin_amdgcn_s_barrier();

    #pragma unroll
    for (int mt=0;mt<4;++mt) af[mt] = *(const shortx8*)(a0 + 8192 + mt*512);
    #pragma unroll
    for (int nt=0;nt<4;++nt) bf[nt] = *(const shortx8*)(b0 + 8192 + nt*512);
    stage_half8(Ab, kc2, Sbase, tid);
    MFMA_QUAD(0);
    __builtin_amdgcn_s_barrier();

    #pragma unroll
    for (int mt=0;mt<4;++mt) af[mt] = *(const shortx8*)(a0 + 8192 + 2048 + mt*512);
    stage_half8(Bb, kc2, Sbase + 16384, tid);
    MFMA_QUAD(1);
    asm volatile("s_waitcnt vmcnt(8)" ::: "memory");
    __builtin_amdgcn_s_barrier();
  }

  // epilogue: qkv = rinv*acc + bias2[col] - rinv*mean*u[col]
  const float rm = rinv*mean;
  const int crow0 = by*256 + wm*128 + quad*4;
  const int ccol0 = bx*256 + wn*64 + mrow;
  float bv[4], uv[4];
  #pragma unroll
  for (int nt=0;nt<4;++nt){
    int col = ccol0 + nt*16;
    bv[nt] = bias[col];
    uv[nt] = uvec[col];
  }
  #pragma unroll
  for (int mh=0;mh<2;++mh){
    #pragma unroll
    for (int mt=0;mt<4;++mt){
      int row = crow0 + mh*64 + mt*16;
      #pragma unroll
      for (int nt=0;nt<4;++nt){
        int col = ccol0 + nt*16;
        #pragma unroll
        for (int r2=0;r2<4;++r2)
          C[(size_t)(row+r2)*N + col] = f2bf(rinv*acc[mh*4+mt][nt][r2] + bv[nt] - rm*uv[nt]);
      }
    }
  }
}

// ---------------- merged attention: [0,1024) op-side fused attn ; [1024,1280) machine flash attn ----------------
__global__ __launch_bounds__(256) void attn_k(const u16* __restrict__ qkv_op, const u16* __restrict__ qkv_m,
                                              const float* __restrict__ prel, const float* __restrict__ Cn,
                                              const float* __restrict__ Ct,
                                              u16* __restrict__ agg_op, u16* __restrict__ agg_m){
  __shared__ __align__(16) char smem[43520];
  int id = blockIdx.x;
  int tid = threadIdx.x, lane = tid & 63, wave = tid >> 6;
  int mrow = lane & 15, quad = lane >> 4;
  if (id < 1024){
    // ---- op-side: S-GEMM + wave-parallel softmax + PV, QBLK=64 ----
    u16* smem16 = (u16*)smem;
    u16* As = smem16;                        // 64*72 u16
    u16* Bs = smem16 + 4608;                 // 64*72 u16
    float* Sbuf = (float*)smem;              // 64*66 f32, aliases As/Bs after S-GEMM
    u16* P   = smem16 + 9216;                // 64*72 u16
    u16* v1T = smem16 + 13824;               // 64*72 u16
    float* wpreS = (float*)(smem + 36864);   // 64 f32
    float* linvS = (float*)(smem + 37120);   // 64 f32
    int bh = id >> 4; int b = bh >> 3, h = bh & 7;
    int n0 = (id & 15) * 64;
    int wm = wave & 1, wn = wave >> 1;
    int srow = tid >> 2, scol = (tid & 3) * 16;
    float p1 = prel[8 + h] * 0.125f;
    { // q_op rows n0..n0+63
      const u16* src = qkv_op + (size_t)(b*1024 + n0 + srow)*CQ + h*64 + scol;
      *(shortx8*)(As + srow*72 + scol)     = *(const shortx8*)(src);
      *(shortx8*)(As + srow*72 + scol + 8) = *(const shortx8*)(src + 8);
    }
    { // k1 (64 machines)
      const u16* src = qkv_m + (size_t)(b*64 + srow)*CM + 512 + h*64 + scol;
      *(shortx8*)(Bs + srow*72 + scol)     = *(const shortx8*)(src);
      *(shortx8*)(Bs + srow*72 + scol + 8) = *(const shortx8*)(src + 8);
    }
    { // v1^T: v1T[d][m] = v1[m][d]
      const u16* src = qkv_m + (size_t)(b*64 + srow)*CM + 1024 + h*64 + scol;
      shortx8 v0 = *(const shortx8*)(src);
      shortx8 v1 = *(const shortx8*)(src + 8);
      #pragma unroll
      for (int e=0;e<8;++e){ v1T[(scol+e)*72 + srow] = (u16)v0[e]; v1T[(scol+8+e)*72 + srow] = (u16)v1[e]; }
    }
    __syncthreads();
    floatx4 acc[2][2];
    #pragma unroll
    for (int a=0;a<2;++a){ acc[a][0] = (floatx4){0,0,0,0}; acc[a][1] = (floatx4){0,0,0,0}; }
    #pragma unroll
    for (int ks=0; ks<2; ++ks){
      shortx8 af[2], bf[2];
      #pragma unroll
      for (int mt=0;mt<2;++mt) af[mt] = *(const shortx8*)(As + (wm*32 + mt*16 + mrow)*72 + ks*32 + quad*8);
      #pragma unroll
      for (int nt=0;nt<2;++nt) bf[nt] = *(const shortx8*)(Bs + (wn*32 + nt*16 + mrow)*72 + ks*32 + quad*8);
      #pragma unroll
      for (int mt=0;mt<2;++mt)
        #pragma unroll
        for (int nt=0;nt<2;++nt)
          acc[mt][nt] = __builtin_amdgcn_mfma_f32_16x16x32_bf16(af[mt], bf[nt], acc[mt][nt], 0, 0, 0);
    }
    __syncthreads();
    #pragma unroll
    for (int mt=0;mt<2;++mt){
      #pragma unroll
      for (int nt=0;nt<2;++nt){
        int m = wn*32 + nt*16 + mrow;
        #pragma unroll
        for (int r2=0;r2<4;++r2){
          int nl = wm*32 + mt*16 + quad*4 + r2;
          Sbuf[nl*66 + m] = acc[mt][nt][r2] * p1;
        }
      }
    }
    __syncthreads();
    { // wave-parallel softmax: 4 threads per row
      int row = srow;
      int mb  = scol;
      int n_g = b*1024 + n0 + row;
      int nl  = n0 + row;
      float sp = -1e30f;
      if (nl > 0){
        float p0 = prel[h] * 0.125f;
        const u16* qp = qkv_op + (size_t)n_g*CQ + h*64 + mb;
        const u16* kp = qkv_op + (size_t)(n_g-1)*CQ + 512 + h*64 + mb;
        shortx8 qa = *(const shortx8*)(qp), qb2 = *(const shortx8*)(qp + 8);
        shortx8 ka = *(const shortx8*)(kp), kb2 = *(const shortx8*)(kp + 8);
        float d = 0.f;
        #pragma unroll
        for (int e=0;e<8;++e) d += bf2f((u16)qa[e])*bf2f((u16)ka[e]) + bf2f((u16)qb2[e])*bf2f((u16)kb2[e]);
        d += __shfl_xor(d, 1, 64);
        d += __shfl_xor(d, 2, 64);
        sp = d * p0;
      }
      const float* crow = Cn + (size_t)n_g*64 + mb;
      float cv[16];
      float mx = sp;
      #pragma unroll
      for (int j=0;j<16;++j){
        cv[j] = crow[j];
        if (cv[j] > 0.f) mx = fmaxf(mx, Sbuf[row*66 + mb + j]);
      }
      mx = fmaxf(mx, __shfl_xor(mx, 1, 64));
      mx = fmaxf(mx, __shfl_xor(mx, 2, 64));
      float L = 0.f;
      #pragma unroll
      for (int j=0;j<16;j+=4){
        shortx4 pv;
        #pragma unroll
        for (int e=0;e<4;++e){
          float w = (cv[j+e] > 0.f) ? cv[j+e]*expf(Sbuf[row*66 + mb + j + e] - mx) : 0.f;
          L += w;
          pv[e] = (short)f2bf(w);
        }
        *(shortx4*)(P + row*72 + mb + j) = pv;
      }
      L += __shfl_xor(L, 1, 64);
      L += __shfl_xor(L, 2, 64);
      float ep = (nl > 0) ? expf(sp - mx) : 0.f;
      L += ep;
      if ((tid & 3) == 0){ wpreS[row] = ep; linvS[row] = 1.f/(L + 1e-16f); }
    }
    __syncthreads();
    floatx4 po[2][2];
    #pragma unroll
    for (int a=0;a<2;++a){ po[a][0] = (floatx4){0,0,0,0}; po[a][1] = (floatx4){0,0,0,0}; }
    #pragma unroll
    for (int ks=0; ks<2; ++ks){
      shortx8 paf[2], pbf[2];
      #pragma unroll
      for (int mt=0;mt<2;++mt) paf[mt] = *(const shortx8*)(P + (wm*32 + mt*16 + mrow)*72 + ks*32 + quad*8);
      #pragma unroll
      for (int nt=0;nt<2;++nt) pbf[nt] = *(const shortx8*)(v1T + (wn*32 + nt*16 + mrow)*72 + ks*32 + quad*8);
      #pragma unroll
      for (int mt=0;mt<2;++mt)
        #pragma unroll
        for (int nt=0;nt<2;++nt)
          po[mt][nt] = __builtin_amdgcn_mfma_f32_16x16x32_bf16(paf[mt], pbf[nt], po[mt][nt], 0, 0, 0);
    }
    #pragma unroll
    for (int mt=0;mt<2;++mt){
      #pragma unroll
      for (int nt=0;nt<2;++nt){
        int d = wn*32 + nt*16 + mrow;
        #pragma unroll
        for (int r2=0;r2<4;++r2){
          int rl = wm*32 + mt*16 + quad*4 + r2;
          int n = n0 + rl;
          size_t ng = (size_t)b*1024 + n;
          float v = po[mt][nt][r2];
          if (n > 0) v += wpreS[rl] * bf2f(qkv_op[(ng-1)*CQ + 1024 + h*64 + d]);
          v *= linvS[rl];
          agg_op[ng*512 + h*64 + d] = f2bf(geluf(v));
        }
      }
    }
  } else {
    // ---- machine-side flash two-pass ----
    u16* qs  = (u16*)smem;                 // 16*72 -> 2304B
    u16* ks  = (u16*)(smem + 2304);        // 128*72 -> 18432B
    u16* vsT = (u16*)(smem + 20736);       // 64*136 -> 17408B
    u16* Ps  = (u16*)(smem + 38144);       // 16*136 -> 4352B
    float (*redv)[4][16] = (float(*)[4][16])(smem + 42496);  // 2*4*16 f32
    int id2 = id - 1024;
    int g = id2 & 3; int bh = id2 >> 2; int b = bh >> 3, h = bh & 7;
    int w = wave;
    float p2 = prel[16 + h] * 0.125f;
    if (tid < 128){
      int r = tid >> 3, cg = (tid & 7) * 8;
      *(shortx8*)(qs + r*72 + cg) = *(const shortx8*)(qkv_m + (size_t)(b*64 + g*16 + r)*CM + h*64 + cg);
    }
    const float* ctbase = Ct + (size_t)(b*64 + g*16 + mrow)*1024;
    float mx = -1e30f;
    for (int ch = 0; ch < 8; ++ch){
      int nb = ch*128;
      #pragma unroll
      for (int i=0;i<4;++i){
        int idx = i*256 + tid;
        int r = idx >> 3, cg = (idx & 7) * 8;
        *(shortx8*)(ks + r*72 + cg) =
          *(const shortx8*)(qkv_op + (size_t)(b*1024 + nb + r)*CQ + 1536 + h*64 + cg);
      }
      __syncthreads();
      #pragma unroll
      for (int nt=0; nt<2; ++nt){
        floatx4 acc = (floatx4){0,0,0,0};
        #pragma unroll
        for (int kk=0; kk<2; ++kk){
          shortx8 af = *(const shortx8*)(ks + (w*32 + nt*16 + mrow)*72 + kk*32 + quad*8);
          shortx8 bf = *(const shortx8*)(qs + mrow*72 + kk*32 + quad*8);
          acc = __builtin_amdgcn_mfma_f32_16x16x32_bf16(af, bf, acc, 0, 0, 0);
        }
        int nloc = w*32 + nt*16 + quad*4;
        floatx4 cv = *(const floatx4*)(ctbase + nb + nloc);
        #pragma unroll
        for (int r2=0;r2<4;++r2)
          if (cv[r2] > 0.f) mx = fmaxf(mx, acc[r2]*p2);
      }
      __syncthreads();
    }
    mx = fmaxf(mx, __shfl_xor(mx, 16, 64));
    mx = fmaxf(mx, __shfl_xor(mx, 32, 64));
    if (lane < 16) redv[0][w][lane] = mx;
    __syncthreads();
    mx = fmaxf(fmaxf(redv[0][0][mrow], redv[0][1][mrow]), fmaxf(redv[0][2][mrow], redv[0][3][mrow]));
    float L = 0.f;
    floatx4 O = (floatx4){0,0,0,0};
    for (int ch = 0; ch < 8; ++ch){
      int nb = ch*128;
      #pragma unroll
      for (int i=0;i<4;++i){
        int idx = i*256 + tid;
        int r = idx >> 3, cg = (idx & 7) * 8;
        *(shortx8*)(ks + r*72 + cg) =
          *(const shortx8*)(qkv_op + (size_t)(b*1024 + nb + r)*CQ + 1536 + h*64 + cg);
        shortx8 vv = *(const shortx8*)(qkv_op + (size_t)(b*1024 + nb + r)*CQ + 2048 + h*64 + cg);
        #pragma unroll
        for (int e=0;e<8;++e) vsT[(cg+e)*136 + r] = (u16)vv[e];
      }
      __syncthreads();
      #pragma unroll
      for (int nt=0; nt<2; ++nt){
        floatx4 acc = (floatx4){0,0,0,0};
        #pragma unroll
        for (int kk=0; kk<2; ++kk){
          shortx8 af = *(const shortx8*)(ks + (w*32 + nt*16 + mrow)*72 + kk*32 + quad*8);
          shortx8 bf = *(const shortx8*)(qs + mrow*72 + kk*32 + quad*8);
          acc = __builtin_amdgcn_mfma_f32_16x16x32_bf16(af, bf, acc, 0, 0, 0);
        }
        int nloc = w*32 + nt*16 + quad*4;
        floatx4 cv = *(const floatx4*)(ctbase + nb + nloc);
        shortx4 pv;
        #pragma unroll
        for (int r2=0;r2<4;++r2){
          float e = (cv[r2] > 0.f) ? cv[r2]*expf(acc[r2]*p2 - mx) : 0.f;
          L += e;
          pv[r2] = (short)f2bf(e);
        }
        *(shortx4*)(Ps + mrow*136 + nloc) = pv;
      }
      __syncthreads();
      #pragma unroll
      for (int kk=0; kk<4; ++kk){
        shortx8 af = *(const shortx8*)(Ps + mrow*136 + kk*32 + quad*8);
        shortx8 bf = *(const shortx8*)(vsT + (w*16 + mrow)*136 + kk*32 + quad*8);
        O = __builtin_amdgcn_mfma_f32_16x16x32_bf16(af, bf, O, 0, 0, 0);
      }
      __syncthreads();
    }
    L += __shfl_xor(L, 16, 64);
    L += __shfl_xor(L, 32, 64);
    if (lane < 16) redv[1][w][lane] = L;
    __syncthreads();
    #pragma unroll
    for (int r2=0;r2<4;++r2){
      int m = quad*4 + r2;
      float Ls = redv[1][0][m] + redv[1][1][m] + redv[1][2][m] + redv[1][3][m];
      float v = O[r2] / (Ls + 1e-16f);
      agg_m[(size_t)(b*64 + g*16 + m)*512 + h*64 + w*16 + mrow] = f2bf(geluf(v));
    }
  }
}

// ---------------- means: partials (no atomics) + final merged ----------------
__global__ __launch_bounds__(512) void meanj_part_k(const float* __restrict__ xo, float* scratchJ){
  int b = blockIdx.x, chunk = blockIdx.y, f = threadIdx.x;
  float s = 0.f;
  for (int r=0;r<128;++r){
    int row = b*1024 + chunk*128 + r;
    s += xo[(size_t)row*512 + f];
  }
  scratchJ[(b*8 + chunk)*512 + f] = s;
}
__global__ __launch_bounds__(512) void mean2_k(const float* __restrict__ scratchJ, float* __restrict__ out){
  int i = blockIdx.x*512 + threadIdx.x;   // 8192
  if (i < 4096){
    int b = i >> 9, f = i & 511;
    float s = 0.f;
    #pragma unroll
    for (int c=0;c<8;++c) s += scratchJ[(b*8+c)*512 + f];
    out[4456448 + i] = s * (1.f/1024.f);
  } else {
    int j = i - 4096;
    int b = j >> 9, f = j & 511;
    float s = 0.f;
    for (int r=0;r<64;++r) s += out[(size_t)TOPC + (size_t)(b*64+r)*512 + f];
    out[4460544 + j] = s * (1.f/64.f);
  }
}

extern "C" void kernel_launch(void* const* d_in, const int* in_sizes, int n_in,
                              void* d_out, int out_size, void* d_ws, size_t ws_size,
                              hipStream_t stream){
  const float* op_x      = (const float*)d_in[0];
  const float* machine_x = (const float*)d_in[1];
  const float* W_emb_op  = (const float*)d_in[2];
  const float* b_emb_op  = (const float*)d_in[3];
  const float* W_emb_m   = (const float*)d_in[4];
  const float* b_emb_m   = (const float*)d_in[5];
  const float* opn_w     = (const float*)d_in[6];
  const float* opn_b     = (const float*)d_in[7];
  const float* mn_w      = (const float*)d_in[8];
  const float* mn_b      = (const float*)d_in[9];
  const float* Wk        = (const float*)d_in[10];
  const float* bk        = (const float*)d_in[11];
  const float* Wq        = (const float*)d_in[12];
  const float* bq        = (const float*)d_in[13];
  const float* Wv        = (const float*)d_in[14];
  const float* bv        = (const float*)d_in[15];
  const float* A_rel     = (const float*)d_in[16];
  const float* M_rel     = (const float*)d_in[17];
  const float* p_rel     = (const float*)d_in[18];
  const float* W_out     = (const float*)d_in[19];
  const float* b_out     = (const float*)d_in[20];
  const float* skip      = (const float*)d_in[21];
  const float* ln_w      = (const float*)d_in[22];
  const float* ln_b      = (const float*)d_in[23];
  const int* s1          = (const int*)d_in[25];
  float* out = (float*)d_out;

  char* ws = (char*)d_ws;
  size_t off = 0;
  auto alloc = [&](size_t bytes)->void*{
    void* p = ws + off;
    off = (off + bytes + 255) & ~(size_t)255;
    return p;
  };
  float* pstat     = (float*)alloc(8192*4);       // A: op@0(2048f) m@2048 ; B: op@4096 m@6144
  float* scratchJ  = (float*)alloc(32768*4);
  float* Ct        = (float*)alloc((size_t)NMS*1024*4);
  float* Cn        = (float*)alloc((size_t)NOPS*64*4);
  float* x_op      = (float*)alloc((size_t)NOPS*512*4);   // rolling pre-LN tensor (y, o0, o1, o2)
  u16*   x_op_bf   = (u16*)  alloc((size_t)NOPS*512*2);   // bf16 of same
  float* x_m       = (float*)alloc((size_t)NMS*512*4);
  u16*   x_m_bf    = (u16*)  alloc((size_t)NMS*512*2);
  u16*   qkv_op    = (u16*)  alloc((size_t)NOPS*CQ*2);
  u16*   qkv_m     = (u16*)  alloc((size_t)NMS*CM*2);
  u16*   agg_op    = (u16*)  alloc((size_t)NOPS*512*2);
  u16*   agg_m     = (u16*)  alloc((size_t)NMS*512*2);
  u16*   Wc_op_t   = (u16*)  alloc((size_t)3*CQ*512*2);
  float* bias_op   = (float*)alloc((size_t)3*CQ*4);
  u16*   Wc_m_t    = (u16*)  alloc((size_t)3*CM*512*2);
  float* bias_m    = (float*)alloc((size_t)3*CM*4);
  float* u_op      = (float*)alloc((size_t)3*CQ*4);
  float* u_m       = (float*)alloc((size_t)3*CM*4);
  u16*   Wout_t    = (u16*)  alloc((size_t)6*262144*2);
  float* psA   = pstat;          float* psA_m = pstat + 2048;
  float* psB   = pstat + 4096;   float* psB_m = pstat + 6144;

  // mega setup (everything independent in ONE dispatch), then the weight fold
  setup_all_k<<<4700,256,0,stream>>>(s1, Ct, Cn, bq, bias_op, bias_m, bk, bv, A_rel, M_rel,
                                     W_out, Wq, Wout_t, Wc_op_t, Wc_m_t, Wk, Wv,
                                     op_x, W_emb_op, b_emb_op, x_op, x_op_bf,
                                     machine_x, W_emb_m, b_emb_m, x_m, x_m_bf, psA, psA_m);
  foldk<<<192,256,0,stream>>>(Wc_op_t, Wc_m_t, bias_op, bias_m, u_op, u_m,
                              opn_w, opn_b, mn_w, mn_b, ln_w, ln_b);

  for (int l=0; l<3; ++l){
    // ping-pong: layer reads stats of prev pre-LN tensor, gate writes new partials
    float *psR, *psR_m, *psW, *psW_m; int npo, npm;
    if (l == 0){ psR=psA; psR_m=psA_m; psW=psB; psW_m=psB_m; npo=1024; npm=128; }
    else if (l == 1){ psR=psB; psR_m=psB_m; psW=psA; psW_m=psA_m; npo=256; npm=16; }
    else { psR=psA; psR_m=psA_m; psW=psB; psW_m=psB_m; npo=256; npm=16; }
    const float* lnw_o = (l==0) ? opn_w : ln_w + (l-1)*512;
    const float* lnb_o = (l==0) ? opn_b : ln_b + (l-1)*512;
    const float* lnw_m2 = (l==0) ? mn_w : ln_w + (l-1)*512;
    const float* lnb_m2 = (l==0) ? mn_b : ln_b + (l-1)*512;
    // QKV GEMM with LN folded (reads pre-LN bf16 A + stats)
    gemm8_k<<<332,512,131136,stream>>>(x_op_bf, Wc_op_t + (size_t)l*CQ*512, bias_op + l*CQ, u_op + l*CQ,
                                       qkv_op, CQ, 10, 320,
                                       x_m_bf, Wc_m_t + (size_t)l*CM*512, bias_m + l*CM, u_m + l*CM,
                                       qkv_m, CM, 6,
                                       psR, npo, psR_m, npm);
    // merged op + machine attention (one dispatch)
    attn_k<<<1280,256,0,stream>>>(qkv_op, qkv_m, p_rel + l*24, Cn, Ct, agg_op, agg_m);
    // W_out GEMM + gated residual (LN-affine) -> new pre-LN tensor (f32+bf16) + stats
    gemmgate2_k<<<272,256,0,stream>>>(agg_op, Wout_t + (size_t)(l*2+0)*262144, x_op,
                                      b_out + (size_t)(l*2+0)*512, skip + l*2+0,
                                      lnw_o, lnb_o, x_op, x_op_bf, psW, 256,
                                      agg_m, Wout_t + (size_t)(l*2+1)*262144, x_m,
                                      b_out + (size_t)(l*2+1)*512, skip + l*2+1,
                                      lnw_m2, lnb_m2, x_m, x_m_bf, psW_m,
                                      psR, npo, psR_m, npm);
  }

  // final graph-LN -> out (stats in psB from layer 2)
  ln2_k<<<1152,256,0,stream>>>(x_op, out, ln_w + 1024, ln_b + 1024,
                               x_m, out + TOPC, ln_w + 1024, ln_b + 1024,
                               psB, psB_m, 256, 16);

  meanj_part_k<<<dim3(8,8),512,0,stream>>>(out, scratchJ);
  mean2_k<<<16,512,0,stream>>>(scratchJ, out);
}

// Round 9
// 524.966 us; speedup vs baseline: 1.1208x; 1.1208x over previous
//
#include <hip/hip_runtime.h>

typedef unsigned short u16;
typedef __attribute__((ext_vector_type(4))) float floatx4;
typedef __attribute__((ext_vector_type(8))) short shortx8;
typedef __attribute__((ext_vector_type(4))) short shortx4;

#define NOPS 8192
#define NMS  512
#define CQ   2560   // op qkv cols: q | k0 | v0 | k2 | v2
#define CM   1536   // machine qkv cols: q | k1 | v1
#define TOPC (NOPS*512)
#define TMC  (NMS*512)

__device__ __forceinline__ float bf2f(u16 u){ return __uint_as_float(((unsigned)u)<<16); }
__device__ __forceinline__ u16 f2bf(float f){
  unsigned u = __float_as_uint(f);
  u += 0x7FFFu + ((u>>16)&1u);
  return (u16)(u>>16);
}
__device__ __forceinline__ float wred(float v){
  #pragma unroll
  for (int o=32;o;o>>=1) v += __shfl_xor(v,o,64);
  return v;
}
__device__ __forceinline__ float geluf(float x){
  return 0.5f*x*(1.f+erff(x*0.70710678118654752f));
}
// block (s,s2) reduction -> one pair at pstat[slot]
__device__ __forceinline__ void block_stat_out2(float s, float s2, float* pstat, int slot){
  __shared__ float sb[8];
  s = wred(s); s2 = wred(s2);
  int wv = threadIdx.x >> 6;
  if ((threadIdx.x & 63) == 0){ sb[wv*2] = s; sb[wv*2+1] = s2; }
  __syncthreads();
  if (threadIdx.x == 0){
    float a = 0.f, b = 0.f;
    int nw = blockDim.x >> 6;
    for (int i=0;i<nw;++i){ a += sb[i*2]; b += sb[i*2+1]; }
    pstat[slot*2]   = a;
    pstat[slot*2+1] = b;
  }
}

// ---------------- mega setup: cnt2 | qb | cbias | tw | combine3 | embed2 (all independent) ----------------
__global__ __launch_bounds__(256) void setup_all_k(
    const int* __restrict__ s1, float* __restrict__ Ct, float* __restrict__ Cn,
    const float* __restrict__ bq, float* bias_op, float* bias_m,
    const float* __restrict__ bk, const float* __restrict__ bv,
    const float* __restrict__ Ar, const float* __restrict__ Mr,
    const float* __restrict__ Wout, const float* __restrict__ Wq,
    u16* __restrict__ Wout_t, u16* __restrict__ Wc_op_t, u16* __restrict__ Wc_m_t,
    const float* __restrict__ Wk, const float* __restrict__ Wv,
    const float* __restrict__ Xop, const float* __restrict__ Wop, const float* __restrict__ bop,
    float* __restrict__ Yop, u16* __restrict__ Yop_bf,
    const float* __restrict__ Xm, const float* __restrict__ Wm, const float* __restrict__ bm_,
    float* __restrict__ Ym, u16* __restrict__ Ym_bf,
    float* pstat, float* pstat_m){
  __shared__ __align__(16) char smem[27648];
  int bid = blockIdx.x;
  int tid = threadIdx.x;
  if (bid < 2048){
    int idx = bid*256 + tid;      // 524288
    int n = idx >> 6, l = idx & 63;
    const int* row = s1 + n*8;
    int cnt = 0;
    #pragma unroll
    for (int j=0;j<8;++j) cnt += ((row[j] & 63) == l);
    float f = (float)cnt;
    Cn[(size_t)n*64 + l] = f;
    int b = n >> 10, nl = n & 1023;
    Ct[(size_t)((b<<6) + l)*1024 + nl] = f;
  } else if (bid < 2060){
    int i = (bid-2048)*256 + tid;   // < 3072
    int l = i >> 10, side = (i >> 9) & 1, f = i & 511;
    float v = bq[(l*2+side)*512 + f];
    if (side==0) bias_op[l*CQ + f] = v; else bias_m[l*CM + f] = v;
  } else if (bid < 2204){
    if (tid >= 64) return;
    int gx = bid - 2060; int e = tid;
    int l = gx/48; int rem = gx - l*48; int s = rem >> 3; int h = rem & 7;
    int side = (s < 4) ? 0 : 1;
    int r = (s < 4) ? (s+1) : (s-3);
    int useK = side==0 ? (s==0 || s==2) : (s==4);
    int rel  = side==0 ? ((s<2)?0:2) : 1;
    const float* bb  = (useK ? bk : bv) + (size_t)(l*2+side)*512 + h*64;
    const float* Rel = (useK ? Ar : Mr) + ((size_t)(l*3+rel)*8 + h)*4096;
    float acc = 0.f;
    for (int d=0; d<64; ++d) acc += bb[d]*Rel[d*64 + e];
    float* bias = side ? (bias_m + l*CM) : (bias_op + l*CQ);
    bias[r*512 + h*64 + e] = acc;
  } else if (bid < 2972){
    // tw: transpose W_out (6 slabs) + Wq (6 slabs)
    u16 (*t)[65] = (u16(*)[65])smem;
    int id2 = bid - 2204;
    int g = id2 >> 6; int rem = id2 & 63;
    int kb = (rem >> 3) * 64, nb = (rem & 7) * 64;
    const float* s; u16* d;
    if (g < 6){
      s = Wout + (size_t)g*262144;
      d = Wout_t + (size_t)g*262144;
    } else {
      int blk = g - 6; int l = blk >> 1, side = blk & 1;
      s = Wq + (size_t)blk*262144;
      d = side ? (Wc_m_t + (size_t)l*CM*512) : (Wc_op_t + (size_t)l*CQ*512);
    }
    int tx = tid & 63, ty4 = tid >> 6;
    #pragma unroll 4
    for (int p=0;p<16;++p){
      int k = ty4 + p*4;
      t[k][tx] = f2bf(s[(size_t)(kb+k)*512 + nb + tx]);
    }
    __syncthreads();
    #pragma unroll 4
    for (int p=0;p<16;++p){
      int n = ty4 + p*4;
      d[(size_t)(nb+n)*512 + kb + tx] = t[tx][n];
    }
  } else if (bid < 3548){
    // combine3: relation combine via MFMA
    u16* As = (u16*)smem;          // 64*72
    u16* Bs = As + 64*72;          // 128*72
    int id3 = bid - 2972;
    int gx = id3 >> 2;
    int cc0 = (id3 & 3) * 128;
    int l = gx/48; int rem = gx - l*48; int s = rem >> 3; int h = rem & 7;
    int side = (s < 4) ? 0 : 1;
    int r = (s < 4) ? (s+1) : (s-3);
    int useK = side==0 ? (s==0 || s==2) : (s==4);
    int rel  = side==0 ? ((s<2)?0:2) : 1;
    const float* W   = (useK ? Wk : Wv) + (size_t)(l*2+side)*262144;
    const float* Rel = (useK ? Ar : Mr) + ((size_t)(l*3+rel)*8 + h)*4096;
    int h64 = h*64;
    u16* Wt = side ? (Wc_m_t + (size_t)l*CM*512) : (Wc_op_t + (size_t)l*CQ*512);
    int rbase = r*512 + h64;
    int lane = tid & 63, wave = tid >> 6;
    {
      int d = tid >> 2, e0 = (tid & 3) * 16;
      #pragma unroll
      for (int j=0;j<16;++j) As[(e0+j)*72 + d] = f2bf(Rel[d*64 + e0 + j]);
    }
    {
      int ccl = tid >> 1, d0 = (tid & 1) * 32;
      const float* src = W + (size_t)(cc0+ccl)*512 + h64 + d0;
      #pragma unroll
      for (int j=0;j<32;j+=4){
        floatx4 v = *(const floatx4*)(src + j);
        shortx4 sv;
        #pragma unroll
        for (int e=0;e<4;++e) sv[e] = (short)f2bf(v[e]);
        *(shortx4*)(Bs + ccl*72 + d0 + j) = sv;
      }
    }
    __syncthreads();
    int wm = wave & 1, wn = wave >> 1;
    int mrow = lane & 15, quad = lane >> 4;
    floatx4 acc[2][4];
    #pragma unroll
    for (int a=0;a<2;++a)
      #pragma unroll
      for (int b=0;b<4;++b) acc[a][b] = (floatx4){0.f,0.f,0.f,0.f};
    #pragma unroll
    for (int ks=0; ks<2; ++ks){
      shortx8 af[2], bf[4];
      #pragma unroll
      for (int mt=0;mt<2;++mt) af[mt] = *(const shortx8*)(As + (wm*32 + mt*16 + mrow)*72 + ks*32 + quad*8);
      #pragma unroll
      for (int nt=0;nt<4;++nt) bf[nt] = *(const shortx8*)(Bs + (wn*64 + nt*16 + mrow)*72 + ks*32 + quad*8);
      #pragma unroll
      for (int mt=0;mt<2;++mt)
        #pragma unroll
        for (int nt=0;nt<4;++nt)
          acc[mt][nt] = __builtin_amdgcn_mfma_f32_16x16x32_bf16(af[mt], bf[nt], acc[mt][nt], 0, 0, 0);
    }
    #pragma unroll
    for (int mt=0;mt<2;++mt){
      #pragma unroll
      for (int nt=0;nt<4;++nt){
        int ccl = wn*64 + nt*16 + mrow;
        #pragma unroll
        for (int r2=0;r2<4;++r2){
          int e = wm*32 + mt*16 + quad*4 + r2;
          Wt[(size_t)(rbase + e)*512 + cc0 + ccl] = f2bf(acc[mt][nt][r2]);
        }
      }
    }
  } else {
    // embed2: op [3548,4572) / m [4572,4700)
    int eb = bid - 3548;
    const float *X, *W, *bias; float *Y, *ps; u16* Yb; int K, total, nb, lb;
    if (eb < 1024){ X=Xop; W=Wop; bias=bop; Y=Yop; Yb=Yop_bf; ps=pstat;   K=16; total=TOPC; nb=1024; lb=eb; }
    else          { X=Xm;  W=Wm;  bias=bm_; Y=Ym;  Yb=Ym_bf;  ps=pstat_m; K=8;  total=TMC;  nb=128;  lb=eb-1024; }
    float s = 0.f, s2 = 0.f;
    for (int idx = lb*256 + tid; idx < total; idx += nb*256){
      int n = idx >> 9, f = idx & 511;
      float v = bias[f];
      for (int c=0;c<K;++c) v += X[n*K+c] * W[c*512+f];
      Y[idx] = v;
      Yb[idx] = f2bf(v);
      s += v; s2 += v*v;
    }
    block_stat_out2(s, s2, ps, lb);
  }
}

// ---------------- LN fold: u=w@Wc, bias+=b@Wc, Wt *= w (in place) ----------------
__global__ __launch_bounds__(256) void foldk(u16* __restrict__ Wc_op_t, u16* __restrict__ Wc_m_t,
                                             float* __restrict__ bias_op, float* __restrict__ bias_m,
                                             float* __restrict__ u_op, float* __restrict__ u_m,
                                             const float* __restrict__ opn_w, const float* __restrict__ opn_b,
                                             const float* __restrict__ mn_w, const float* __restrict__ mn_b,
                                             const float* __restrict__ ln_w, const float* __restrict__ ln_b){
  int bid = blockIdx.x, tid = threadIdx.x;
  int rloc = tid >> 2, t = tid & 3;
  int side, l; u16* Wt; float* bias; float* u;
  if (bid < 120){
    int row = bid*64 + rloc; side = 0; l = row/2560; int j = row - l*2560;
    Wt = Wc_op_t + ((size_t)l*CQ + j)*512; bias = bias_op + l*CQ + j; u = u_op + l*CQ + j;
  } else {
    int row = (bid-120)*64 + rloc; side = 1; l = row/1536; int j = row - l*1536;
    Wt = Wc_m_t + ((size_t)l*CM + j)*512; bias = bias_m + l*CM + j; u = u_m + l*CM + j;
  }
  const float* w = side ? (l==0 ? mn_w : ln_w + (l-1)*512) : (l==0 ? opn_w : ln_w + (l-1)*512);
  const float* b = side ? (l==0 ? mn_b : ln_b + (l-1)*512) : (l==0 ? opn_b : ln_b + (l-1)*512);
  float up = 0.f, vp = 0.f;
  for (int k = t*128; k < t*128 + 128; k += 8){
    shortx8 wv = *(shortx8*)(Wt + k);
    #pragma unroll
    for (int e=0;e<8;++e){
      float x = bf2f((u16)wv[e]);
      float wk = w[k+e];
      up += wk*x; vp += b[k+e]*x;
      wv[e] = (short)f2bf(x*wk);
    }
    *(shortx8*)(Wt + k) = wv;
  }
  up += __shfl_xor(up,1,64); up += __shfl_xor(up,2,64);
  vp += __shfl_xor(vp,1,64); vp += __shfl_xor(vp,2,64);
  if (t == 0){ *u = up; *bias += vp; }
}

// ---------------- final graph-LN apply (used once, writes `out`) ----------------
__global__ __launch_bounds__(256) void ln2_k(const float* __restrict__ src_op, float* __restrict__ dst_op,
                                             const float* __restrict__ w_op, const float* __restrict__ b_op,
                                             const float* __restrict__ src_m, float* __restrict__ dst_m,
                                             const float* __restrict__ w_m, const float* __restrict__ b_m,
                                             const float* __restrict__ pstat, const float* __restrict__ pstat_m,
                                             int nbo, int nbm){
  int bid = blockIdx.x;
  const float *src, *w, *b, *ps; float* dst; int total4, nb, lb, nblk; float inv_n;
  if (bid < 1024){ src=src_op; dst=dst_op; w=w_op; b=b_op; ps=pstat;
                   total4=TOPC/4; nb=1024; lb=bid; nblk=nbo; inv_n=1.f/TOPC; }
  else           { src=src_m;  dst=dst_m;  w=w_m;  b=b_m;  ps=pstat_m;
                   total4=TMC/4;  nb=128;  lb=bid-1024; nblk=nbm; inv_n=1.f/TMC; }
  __shared__ float sb[8];
  __shared__ float mr[2];
  float s = 0.f, s2 = 0.f;
  for (int i = threadIdx.x; i < nblk; i += 256){ s += ps[2*i]; s2 += ps[2*i+1]; }
  s = wred(s); s2 = wred(s2);
  int wv = threadIdx.x >> 6;
  if ((threadIdx.x & 63) == 0){ sb[wv*2] = s; sb[wv*2+1] = s2; }
  __syncthreads();
  if (threadIdx.x == 0){
    float a = 0.f, bsum = 0.f;
    for (int i=0;i<4;++i){ a += sb[i*2]; bsum += sb[i*2+1]; }
    float mean = a * inv_n;
    float var  = fmaxf(bsum * inv_n - mean*mean, 0.f);
    mr[0] = mean;
    mr[1] = 1.f/(sqrtf(var) + 1e-5f);
  }
  __syncthreads();
  float mean = mr[0], rinv = mr[1];
  const floatx4* s4 = (const floatx4*)src;
  floatx4* d4 = (floatx4*)dst;
  const floatx4* w4 = (const floatx4*)w;
  const floatx4* b4 = (const floatx4*)b;
  for (int i = lb*256 + threadIdx.x; i < total4; i += nb*256){
    int f = i & 127;
    floatx4 v = s4[i], wv2 = w4[f], bv = b4[f];
    #pragma unroll
    for (int e=0;e<4;++e) v[e] = (v[e]-mean)*rinv*wv2[e] + bv[e];
    d4[i] = v;
  }
}

// ---------------- W_out GEMM + gated residual (LN-affine on x) + f32/bf16 out + LN partials ----------------
__device__ __forceinline__ void gemm_gate_core(u16* As, u16* Bs, float* stb,
                                               const u16* __restrict__ A, const u16* __restrict__ Bt,
                                               const float* __restrict__ xr, const float* __restrict__ bo,
                                               const float* __restrict__ sk,
                                               const float* __restrict__ lnw, const float* __restrict__ lnb,
                                               const float* __restrict__ psr, int np, float inv_n,
                                               float* __restrict__ Y, u16* __restrict__ Ybf,
                                               float* pstat, int slot, int bx, int by){
  const int tid = threadIdx.x;
  const int lane = tid & 63, wave = tid >> 6;
  // ---- stats of previous-layer pre-LN tensor ----
  {
    float s = 0.f, s2 = 0.f;
    for (int i = tid; i < np; i += 256){ s += psr[2*i]; s2 += psr[2*i+1]; }
    s = wred(s); s2 = wred(s2);
    if (lane == 0){ stb[wave*2] = s; stb[wave*2+1] = s2; }
    __syncthreads();
    if (tid == 0){
      float a = 0.f, bb = 0.f;
      for (int i=0;i<4;++i){ a += stb[2*i]; bb += stb[2*i+1]; }
      float mean = a * inv_n;
      float var = fmaxf(bb * inv_n - mean*mean, 0.f);
      stb[8] = mean;
      stb[9] = 1.f/(sqrtf(var) + 1e-5f);
    }
    __syncthreads();
  }
  const float mean = stb[8], rinv = stb[9];
  const int bm = by * 128, bn = bx * 128;
  const int wm = wave & 1, wn = wave >> 1;
  const int mrow = lane & 15, quad = lane >> 4;
  const u16* Ab = A + (size_t)bm*512;
  const u16* Bb = Bt + (size_t)bn*512;
  floatx4 acc[4][4];
  #pragma unroll
  for (int a=0;a<4;++a)
    #pragma unroll
    for (int b=0;b<4;++b) acc[a][b] = (floatx4){0.f,0.f,0.f,0.f};
  const int r0 = tid >> 2, c0 = (tid & 3) * 8;
  const int r1 = (tid+256) >> 2, c1 = ((tid+256) & 3) * 8;
  const int lds0 = wave*512;
  const int lds1 = wave*512 + 2048;
  for (int k0 = 0; k0 < 512; k0 += 32){
    __builtin_amdgcn_global_load_lds((const __attribute__((address_space(1))) void*)(Ab + (size_t)r0*512 + k0 + c0),
                                     (__attribute__((address_space(3))) void*)(As + lds0), 16, 0, 0);
    __builtin_amdgcn_global_load_lds((const __attribute__((address_space(1))) void*)(Ab + (size_t)r1*512 + k0 + c1),
                                     (__attribute__((address_space(3))) void*)(As + lds1), 16, 0, 0);
    __builtin_amdgcn_global_load_lds((const __attribute__((address_space(1))) void*)(Bb + (size_t)r0*512 + k0 + c0),
                                     (__attribute__((address_space(3))) void*)(Bs + lds0), 16, 0, 0);
    __builtin_amdgcn_global_load_lds((const __attribute__((address_space(1))) void*)(Bb + (size_t)r1*512 + k0 + c1),
                                     (__attribute__((address_space(3))) void*)(Bs + lds1), 16, 0, 0);
    __syncthreads();
    shortx8 af[4], bf[4];
    #pragma unroll
    for (int mt=0;mt<4;++mt) af[mt] = *(const shortx8*)(As + (wm*64 + mt*16 + mrow)*32 + quad*8);
    #pragma unroll
    for (int nt=0;nt<4;++nt) bf[nt] = *(const shortx8*)(Bs + (wn*64 + nt*16 + mrow)*32 + quad*8);
    #pragma unroll
    for (int mt=0;mt<4;++mt)
      #pragma unroll
      for (int nt=0;nt<4;++nt)
        acc[mt][nt] = __builtin_amdgcn_mfma_f32_16x16x32_bf16(af[mt], bf[nt], acc[mt][nt], 0, 0, 0);
    __syncthreads();
  }
  float g = 1.f/(1.f+expf(-(*sk)));
  float s = 0.f, s2 = 0.f;
  #pragma unroll
  for (int mt=0;mt<4;++mt){
    #pragma unroll
    for (int nt=0;nt<4;++nt){
      int col = bn + wn*64 + nt*16 + mrow;
      float bval = bo[col];
      float lw = lnw[col]*rinv, lb = lnb[col];
      #pragma unroll
      for (int r2=0;r2<4;++r2){
        int row = bm + wm*64 + mt*16 + quad*4 + r2;
        float v = acc[mt][nt][r2] + bval;
        float xv = (xr[(size_t)row*512 + col] - mean)*lw + lb;   // x = LN(prev)
        float o = g*v + (2.f-g)*xv;
        Y[(size_t)row*512 + col] = o;
        Ybf[(size_t)row*512 + col] = f2bf(o);
        s += o; s2 += o*o;
      }
    }
  }
  block_stat_out2(s, s2, pstat, slot);
}
__global__ __launch_bounds__(256) void gemmgate2_k(
    const u16* A1, const u16* B1, const float* x1, const float* bo1, const float* sk1,
    const float* lnw1, const float* lnb1, float* Y1, u16* Yb1, float* ps1w, int nblk1,
    const u16* A2, const u16* B2, const float* x2, const float* bo2, const float* sk2,
    const float* lnw2, const float* lnb2, float* Y2, u16* Yb2, float* ps2w,
    const float* ps1r, int np1, const float* ps2r, int np2){
  __shared__ u16 As[128*32];
  __shared__ u16 Bs[128*32];
  __shared__ float stb[12];
  int id = blockIdx.x;
  if (id < nblk1)
    gemm_gate_core(As, Bs, stb, A1, B1, x1, bo1, sk1, lnw1, lnb1, ps1r, np1, 1.f/TOPC,
                   Y1, Yb1, ps1w, id, id % 4, id / 4);
  else {
    int j = id - nblk1;
    gemm_gate_core(As, Bs, stb, A2, B2, x2, bo2, sk2, lnw2, lnb2, ps2r, np2, 1.f/TMC,
                   Y2, Yb2, ps2w, j, j % 4, j / 4);
  }
}

// ---------------- 256x256 8-phase GEMM (QKV projections), K=512, LN folded ----------------
__device__ __forceinline__ void stage_half8(const u16* __restrict__ src, int kc, u16* region, int tid){
  int wave = tid >> 6;
  #pragma unroll
  for (int j=0;j<2;++j){
    int idx = j*512 + tid;
    int row = idx >> 2, qp2 = idx & 3;
    int qs = qp2 ^ (((row >> 3) & 1) << 1);   // st_16x32 pre-swizzled global source
    __builtin_amdgcn_global_load_lds(
      (const __attribute__((address_space(1))) void*)(src + (size_t)row*512 + kc + qs*8),
      (__attribute__((address_space(3))) void*)(region + (j*512 + wave*64)*8),
      16, 0, 0);
  }
}

#define MFMA_QUAD(MH) do { \
  __builtin_amdgcn_s_barrier(); \
  asm volatile("s_waitcnt lgkmcnt(0)" ::: "memory"); \
  __builtin_amdgcn_sched_barrier(0); \
  __builtin_amdgcn_s_setprio(1); \
  _Pragma("unroll") \
  for (int mt=0;mt<4;++mt){ \
    _Pragma("unroll") \
    for (int nt=0;nt<4;++nt) \
      acc[(MH)*4+mt][nt] = __builtin_amdgcn_mfma_f32_16x16x32_bf16(af[mt], bf[nt], acc[(MH)*4+mt][nt], 0, 0, 0); \
  } \
  __builtin_amdgcn_s_setprio(0); \
} while(0)

__global__ __launch_bounds__(512, 2) void gemm8_k(
    const u16* __restrict__ A1, const u16* __restrict__ B1, const float* __restrict__ bias1,
    const float* __restrict__ u1, u16* __restrict__ C1, int N1, int nbx1, int nblk1,
    const u16* __restrict__ A2, const u16* __restrict__ B2, const float* __restrict__ bias2p,
    const float* __restrict__ u2, u16* __restrict__ C2, int N2, int nbx2,
    const float* __restrict__ ps1, int np1, const float* __restrict__ ps2, int np2){
  extern __shared__ u16 lds[];      // 131072 B staging + 64 B stats scratch
  float* statsh = (float*)(lds + 65536);
  int id = blockIdx.x;
  const u16 *A, *Bt; const float *bias, *uvec, *ps; u16* C; int N, bx, by, np; float inv_n;
  if (id < nblk1){
    int xcd = id & 7, loc = id >> 3;
    int wg = xcd * (nblk1 >> 3) + loc;
    A=A1; Bt=B1; bias=bias1; uvec=u1; C=C1; N=N1; bx=wg%nbx1; by=wg/nbx1;
    ps=ps1; np=np1; inv_n=1.f/TOPC;
  }
  else { int j=id-nblk1; A=A2; Bt=B2; bias=bias2p; uvec=u2; C=C2; N=N2; bx=j%nbx2; by=j/nbx2;
    ps=ps2; np=np2; inv_n=1.f/TMC; }
  const int tid = threadIdx.x, lane = tid & 63, wave = tid >> 6;
  // ---- stats (mean/rinv of pre-LN A tensor) ----
  {
    float s = 0.f, s2 = 0.f;
    for (int i = tid; i < np; i += 512){ s += ps[2*i]; s2 += ps[2*i+1]; }
    s = wred(s); s2 = wred(s2);
    if (lane == 0){ statsh[wave*2] = s; statsh[wave*2+1] = s2; }
    __syncthreads();
    if (tid == 0){
      float a = 0.f, bb = 0.f;
      for (int i=0;i<8;++i){ a += statsh[2*i]; bb += statsh[2*i+1]; }
      float mean = a * inv_n;
      float var = fmaxf(bb * inv_n - mean*mean, 0.f);
      statsh[16] = mean;
      statsh[17] = 1.f/(sqrtf(var) + 1e-5f);
    }
    __syncthreads();
  }
  const float mean = statsh[16], rinv = statsh[17];
  const int wm = wave & 1, wn = wave >> 1;
  const int mrow = lane & 15, quad = lane >> 4;
  const int qp = quad ^ ((mrow & 8) ? 2 : 0);
  const u16* Ab = A + (size_t)(by*256)*512;
  const u16* Bb = Bt + (size_t)(bx*256)*512;

  floatx4 acc[8][4];
  #pragma unroll
  for (int a=0;a<8;++a)
    #pragma unroll
    for (int b=0;b<4;++b) acc[a][b] = (floatx4){0.f,0.f,0.f,0.f};

  stage_half8(Ab, 0,  lds,          tid);
  stage_half8(Bb, 0,  lds + 16384,  tid);
  stage_half8(Ab, 32, lds + 8192,   tid);
  stage_half8(Bb, 32, lds + 24576,  tid);
  stage_half8(Ab, 64, lds + 32768,  tid);
  stage_half8(Bb, 64, lds + 49152,  tid);
  asm volatile("s_waitcnt vmcnt(8)" ::: "memory");
  __builtin_amdgcn_s_barrier();

  for (int t = 0; t < 8; ++t){
    const int s = t & 1;
    u16* Sbase = lds + s*32768;
    u16* Obase = lds + (s^1)*32768;
    const u16* a0 = Sbase + (wm*128 + mrow)*32 + qp*8;
    const u16* b0 = Sbase + 16384 + (wn*64 + mrow)*32 + qp*8;
    const int kc1 = ((t < 7) ? (t+1) : 7)*64 + 32;
    const int kc2 = ((t < 6) ? (t+2) : 7)*64;
    shortx8 af[4], bf[4];

    #pragma unroll
    for (int mt=0;mt<4;++mt) af[mt] = *(const shortx8*)(a0 + mt*512);
    #pragma unroll
    for (int nt=0;nt<4;++nt) bf[nt] = *(const shortx8*)(b0 + nt*512);
    stage_half8(Ab, kc1, Obase + 8192, tid);
    MFMA_QUAD(0);
    __builtin_amdgcn_s_barrier();

    #pragma unroll
    for (int mt=0;mt<4;++mt) af[mt] = *(const shortx8*)(a0 + 2048 + mt*512);
    stage_half8(Bb, kc1, Obase + 24576, tid);
    MFMA_QUAD(1);
    asm volatile("s_waitcnt vmcnt(8)" ::: "memory");
    __builtin_amdgcn_s_barrier();

    #pragma unroll
    for (int mt=0;mt<4;++mt) af[mt] = *(const shortx8*)(a0 + 8192 + mt*512);
    #pragma unroll
    for (int nt=0;nt<4;++nt) bf[nt] = *(const shortx8*)(b0 + 8192 + nt*512);
    stage_half8(Ab, kc2, Sbase, tid);
    MFMA_QUAD(0);
    __builtin_amdgcn_s_barrier();

    #pragma unroll
    for (int mt=0;mt<4;++mt) af[mt] = *(const shortx8*)(a0 + 8192 + 2048 + mt*512);
    stage_half8(Bb, kc2, Sbase + 16384, tid);
    MFMA_QUAD(1);
    asm volatile("s_waitcnt vmcnt(8)" ::: "memory");
    __builtin_amdgcn_s_barrier();
  }

  // epilogue: qkv = rinv*acc + bias2[col] - rinv*mean*u[col]
  const float rm = rinv*mean;
  const int crow0 = by*256 + wm*128 + quad*4;
  const int ccol0 = bx*256 + wn*64 + mrow;
  float bv[4], uv[4];
  #pragma unroll
  for (int nt=0;nt<4;++nt){
    int col = ccol0 + nt*16;
    bv[nt] = bias[col];
    uv[nt] = uvec[col];
  }
  #pragma unroll
  for (int mh=0;mh<2;++mh){
    #pragma unroll
    for (int mt=0;mt<4;++mt){
      int row = crow0 + mh*64 + mt*16;
      #pragma unroll
      for (int nt=0;nt<4;++nt){
        int col = ccol0 + nt*16;
        #pragma unroll
        for (int r2=0;r2<4;++r2)
          C[(size_t)(row+r2)*N + col] = f2bf(rinv*acc[mh*4+mt][nt][r2] + bv[nt] - rm*uv[nt]);
      }
    }
  }
}

// ---------------- merged attention: [0,256) machine ONLINE flash (long pole, scheduled first);
//                  [256,1280) op-side fused attn ----------------
__global__ __launch_bounds__(256) void attn_k(const u16* __restrict__ qkv_op, const u16* __restrict__ qkv_m,
                                              const float* __restrict__ prel, const float* __restrict__ Cn,
                                              const float* __restrict__ Ct,
                                              u16* __restrict__ agg_op, u16* __restrict__ agg_m){
  __shared__ __align__(16) char smem[43520];
  int id = blockIdx.x;
  int tid = threadIdx.x, lane = tid & 63, wave = tid >> 6;
  int mrow = lane & 15, quad = lane >> 4;
  if (id < 256){
    // ---- machine-side ONLINE flash (single pass, running max + rescale) ----
    u16* qs  = (u16*)smem;                 // 16*72 -> 2304B
    u16* ks  = (u16*)(smem + 2304);        // 128*72 -> 18432B
    u16* vsT = (u16*)(smem + 20736);       // 64*136 -> 17408B
    u16* Ps  = (u16*)(smem + 38144);       // 16*136 -> 4352B
    float (*redv)[4][16] = (float(*)[4][16])(smem + 42496);  // 2*4*16 f32
    int g = id & 3; int bh = id >> 2; int b = bh >> 3, h = bh & 7;
    int w = wave;
    float p2 = prel[16 + h] * 0.125f;
    if (tid < 128){
      int r = tid >> 3, cg = (tid & 7) * 8;
      *(shortx8*)(qs + r*72 + cg) = *(const shortx8*)(qkv_m + (size_t)(b*64 + g*16 + r)*CM + h*64 + cg);
    }
    const float* ctbase = Ct + (size_t)(b*64 + g*16 + mrow)*1024;
    float mold_m = -1e30f;                     // running max for P-row mrow
    float mold4[4] = {-1e30f,-1e30f,-1e30f,-1e30f};  // running max for O-rows quad*4+r2
    float L = 0.f;
    floatx4 O = (floatx4){0,0,0,0};
    for (int ch = 0; ch < 8; ++ch){
      int nb = ch*128;
      #pragma unroll
      for (int i=0;i<4;++i){
        int idx = i*256 + tid;
        int r = idx >> 3, cg = (idx & 7) * 8;
        *(shortx8*)(ks + r*72 + cg) =
          *(const shortx8*)(qkv_op + (size_t)(b*1024 + nb + r)*CQ + 1536 + h*64 + cg);
        shortx8 vv = *(const shortx8*)(qkv_op + (size_t)(b*1024 + nb + r)*CQ + 2048 + h*64 + cg);
        #pragma unroll
        for (int e=0;e<8;++e) vsT[(cg+e)*136 + r] = (u16)vv[e];
      }
      __syncthreads();   // ks/vsT (and qs on ch0) visible
      floatx4 sa[2], cv[2];
      #pragma unroll
      for (int nt=0; nt<2; ++nt){
        floatx4 acc = (floatx4){0,0,0,0};
        #pragma unroll
        for (int kk=0; kk<2; ++kk){
          shortx8 af = *(const shortx8*)(ks + (w*32 + nt*16 + mrow)*72 + kk*32 + quad*8);
          shortx8 bf = *(const shortx8*)(qs + mrow*72 + kk*32 + quad*8);
          acc = __builtin_amdgcn_mfma_f32_16x16x32_bf16(af, bf, acc, 0, 0, 0);
        }
        int nloc = w*32 + nt*16 + quad*4;
        cv[nt] = *(const floatx4*)(ctbase + nb + nloc);
        #pragma unroll
        for (int r2=0;r2<4;++r2) acc[r2] *= p2;
        sa[nt] = acc;
      }
      // masked chunk row-max
      float cm = -1e30f;
      #pragma unroll
      for (int nt=0;nt<2;++nt)
        #pragma unroll
        for (int r2=0;r2<4;++r2)
          if (cv[nt][r2] > 0.f) cm = fmaxf(cm, sa[nt][r2]);
      cm = fmaxf(cm, __shfl_xor(cm, 16, 64));
      cm = fmaxf(cm, __shfl_xor(cm, 32, 64));
      if (lane < 16) redv[0][w][lane] = cm;
      __syncthreads();   // redv visible
      float mnew_m = fmaxf(fmaxf(redv[0][0][mrow], redv[0][1][mrow]),
                           fmaxf(redv[0][2][mrow], redv[0][3][mrow]));
      mnew_m = fmaxf(mnew_m, mold_m);
      float sL = expf(mold_m - mnew_m);
      mold_m = mnew_m;
      float sO[4];
      #pragma unroll
      for (int r2=0;r2<4;++r2){
        int r = quad*4 + r2;
        float mn = fmaxf(fmaxf(redv[0][0][r], redv[0][1][r]),
                         fmaxf(redv[0][2][r], redv[0][3][r]));
        mn = fmaxf(mn, mold4[r2]);
        sO[r2] = expf(mold4[r2] - mn);
        mold4[r2] = mn;
      }
      float Lsum = 0.f;
      #pragma unroll
      for (int nt=0;nt<2;++nt){
        int nloc = w*32 + nt*16 + quad*4;
        shortx4 pv;
        #pragma unroll
        for (int r2=0;r2<4;++r2){
          float e = (cv[nt][r2] > 0.f) ? cv[nt][r2]*expf(sa[nt][r2] - mnew_m) : 0.f;
          Lsum += e;
          pv[r2] = (short)f2bf(e);
        }
        *(shortx4*)(Ps + mrow*136 + nloc) = pv;
      }
      L = L*sL + Lsum;
      __syncthreads();   // Ps visible (written cross-wave)
      #pragma unroll
      for (int r2=0;r2<4;++r2) O[r2] *= sO[r2];
      #pragma unroll
      for (int kk=0; kk<4; ++kk){
        shortx8 af = *(const shortx8*)(Ps + mrow*136 + kk*32 + quad*8);
        shortx8 bf = *(const shortx8*)(vsT + (w*16 + mrow)*136 + kk*32 + quad*8);
        O = __builtin_amdgcn_mfma_f32_16x16x32_bf16(af, bf, O, 0, 0, 0);
      }
      __syncthreads();   // before next chunk overwrites ks/vsT/Ps/redv
    }
    L += __shfl_xor(L, 16, 64);
    L += __shfl_xor(L, 32, 64);
    if (lane < 16) redv[1][w][lane] = L;
    __syncthreads();
    #pragma unroll
    for (int r2=0;r2<4;++r2){
      int m = quad*4 + r2;
      float Ls = redv[1][0][m] + redv[1][1][m] + redv[1][2][m] + redv[1][3][m];
      float v = O[r2] / (Ls + 1e-16f);
      agg_m[(size_t)(b*64 + g*16 + m)*512 + h*64 + w*16 + mrow] = f2bf(geluf(v));
    }
  } else {
    // ---- op-side: S-GEMM + wave-parallel softmax + PV, QBLK=64 ----
    u16* smem16 = (u16*)smem;
    u16* As = smem16;                        // 64*72 u16
    u16* Bs = smem16 + 4608;                 // 64*72 u16
    float* Sbuf = (float*)smem;              // 64*66 f32, aliases As/Bs after S-GEMM
    u16* P   = smem16 + 9216;                // 64*72 u16
    u16* v1T = smem16 + 13824;               // 64*72 u16
    float* wpreS = (float*)(smem + 36864);   // 64 f32
    float* linvS = (float*)(smem + 37120);   // 64 f32
    int id2 = id - 256;
    int bh = id2 >> 4; int b = bh >> 3, h = bh & 7;
    int n0 = (id2 & 15) * 64;
    int wm = wave & 1, wn = wave >> 1;
    int srow = tid >> 2, scol = (tid & 3) * 16;
    float p1 = prel[8 + h] * 0.125f;
    { // q_op rows n0..n0+63
      const u16* src = qkv_op + (size_t)(b*1024 + n0 + srow)*CQ + h*64 + scol;
      *(shortx8*)(As + srow*72 + scol)     = *(const shortx8*)(src);
      *(shortx8*)(As + srow*72 + scol + 8) = *(const shortx8*)(src + 8);
    }
    { // k1 (64 machines)
      const u16* src = qkv_m + (size_t)(b*64 + srow)*CM + 512 + h*64 + scol;
      *(shortx8*)(Bs + srow*72 + scol)     = *(const shortx8*)(src);
      *(shortx8*)(Bs + srow*72 + scol + 8) = *(const shortx8*)(src + 8);
    }
    { // v1^T: v1T[d][m] = v1[m][d]
      const u16* src = qkv_m + (size_t)(b*64 + srow)*CM + 1024 + h*64 + scol;
      shortx8 v0 = *(const shortx8*)(src);
      shortx8 v1 = *(const shortx8*)(src + 8);
      #pragma unroll
      for (int e=0;e<8;++e){ v1T[(scol+e)*72 + srow] = (u16)v0[e]; v1T[(scol+8+e)*72 + srow] = (u16)v1[e]; }
    }
    __syncthreads();
    floatx4 acc[2][2];
    #pragma unroll
    for (int a=0;a<2;++a){ acc[a][0] = (floatx4){0,0,0,0}; acc[a][1] = (floatx4){0,0,0,0}; }
    #pragma unroll
    for (int ks=0; ks<2; ++ks){
      shortx8 af[2], bf[2];
      #pragma unroll
      for (int mt=0;mt<2;++mt) af[mt] = *(const shortx8*)(As + (wm*32 + mt*16 + mrow)*72 + ks*32 + quad*8);
      #pragma unroll
      for (int nt=0;nt<2;++nt) bf[nt] = *(const shortx8*)(Bs + (wn*32 + nt*16 + mrow)*72 + ks*32 + quad*8);
      #pragma unroll
      for (int mt=0;mt<2;++mt)
        #pragma unroll
        for (int nt=0;nt<2;++nt)
          acc[mt][nt] = __builtin_amdgcn_mfma_f32_16x16x32_bf16(af[mt], bf[nt], acc[mt][nt], 0, 0, 0);
    }
    __syncthreads();
    #pragma unroll
    for (int mt=0;mt<2;++mt){
      #pragma unroll
      for (int nt=0;nt<2;++nt){
        int m = wn*32 + nt*16 + mrow;
        #pragma unroll
        for (int r2=0;r2<4;++r2){
          int nl = wm*32 + mt*16 + quad*4 + r2;
          Sbuf[nl*66 + m] = acc[mt][nt][r2] * p1;
        }
      }
    }
    __syncthreads();
    { // wave-parallel softmax: 4 threads per row
      int row = srow;
      int mb  = scol;
      int n_g = b*1024 + n0 + row;
      int nl  = n0 + row;
      float sp = -1e30f;
      if (nl > 0){
        float p0 = prel[h] * 0.125f;
        const u16* qp = qkv_op + (size_t)n_g*CQ + h*64 + mb;
        const u16* kp = qkv_op + (size_t)(n_g-1)*CQ + 512 + h*64 + mb;
        shortx8 qa = *(const shortx8*)(qp), qb2 = *(const shortx8*)(qp + 8);
        shortx8 ka = *(const shortx8*)(kp), kb2 = *(const shortx8*)(kp + 8);
        float d = 0.f;
        #pragma unroll
        for (int e=0;e<8;++e) d += bf2f((u16)qa[e])*bf2f((u16)ka[e]) + bf2f((u16)qb2[e])*bf2f((u16)kb2[e]);
        d += __shfl_xor(d, 1, 64);
        d += __shfl_xor(d, 2, 64);
        sp = d * p0;
      }
      const float* crow = Cn + (size_t)n_g*64 + mb;
      float cv[16];
      float mx = sp;
      #pragma unroll
      for (int j=0;j<16;++j){
        cv[j] = crow[j];
        if (cv[j] > 0.f) mx = fmaxf(mx, Sbuf[row*66 + mb + j]);
      }
      mx = fmaxf(mx, __shfl_xor(mx, 1, 64));
      mx = fmaxf(mx, __shfl_xor(mx, 2, 64));
      float L = 0.f;
      #pragma unroll
      for (int j=0;j<16;j+=4){
        shortx4 pv;
        #pragma unroll
        for (int e=0;e<4;++e){
          float w = (cv[j+e] > 0.f) ? cv[j+e]*expf(Sbuf[row*66 + mb + j + e] - mx) : 0.f;
          L += w;
          pv[e] = (short)f2bf(w);
        }
        *(shortx4*)(P + row*72 + mb + j) = pv;
      }
      L += __shfl_xor(L, 1, 64);
      L += __shfl_xor(L, 2, 64);
      float ep = (nl > 0) ? expf(sp - mx) : 0.f;
      L += ep;
      if ((tid & 3) == 0){ wpreS[row] = ep; linvS[row] = 1.f/(L + 1e-16f); }
    }
    __syncthreads();
    floatx4 po[2][2];
    #pragma unroll
    for (int a=0;a<2;++a){ po[a][0] = (floatx4){0,0,0,0}; po[a][1] = (floatx4){0,0,0,0}; }
    #pragma unroll
    for (int ks=0; ks<2; ++ks){
      shortx8 paf[2], pbf[2];
      #pragma unroll
      for (int mt=0;mt<2;++mt) paf[mt] = *(const shortx8*)(P + (wm*32 + mt*16 + mrow)*72 + ks*32 + quad*8);
      #pragma unroll
      for (int nt=0;nt<2;++nt) pbf[nt] = *(const shortx8*)(v1T + (wn*32 + nt*16 + mrow)*72 + ks*32 + quad*8);
      #pragma unroll
      for (int mt=0;mt<2;++mt)
        #pragma unroll
        for (int nt=0;nt<2;++nt)
          po[mt][nt] = __builtin_amdgcn_mfma_f32_16x16x32_bf16(paf[mt], pbf[nt], po[mt][nt], 0, 0, 0);
    }
    #pragma unroll
    for (int mt=0;mt<2;++mt){
      #pragma unroll
      for (int nt=0;nt<2;++nt){
        int d = wn*32 + nt*16 + mrow;
        #pragma unroll
        for (int r2=0;r2<4;++r2){
          int rl = wm*32 + mt*16 + quad*4 + r2;
          int n = n0 + rl;
          size_t ng = (size_t)b*1024 + n;
          float v = po[mt][nt][r2];
          if (n > 0) v += wpreS[rl] * bf2f(qkv_op[(ng-1)*CQ + 1024 + h*64 + d]);
          v *= linvS[rl];
          agg_op[ng*512 + h*64 + d] = f2bf(geluf(v));
        }
      }
    }
  }
}

// ---------------- means: partials (no atomics) + final merged ----------------
__global__ __launch_bounds__(512) void meanj_part_k(const float* __restrict__ xo, float* scratchJ){
  int b = blockIdx.x, chunk = blockIdx.y, f = threadIdx.x;
  float s = 0.f;
  for (int r=0;r<128;++r){
    int row = b*1024 + chunk*128 + r;
    s += xo[(size_t)row*512 + f];
  }
  scratchJ[(b*8 + chunk)*512 + f] = s;
}
__global__ __launch_bounds__(512) void mean2_k(const float* __restrict__ scratchJ, float* __restrict__ out){
  int i = blockIdx.x*512 + threadIdx.x;   // 8192
  if (i < 4096){
    int b = i >> 9, f = i & 511;
    float s = 0.f;
    #pragma unroll
    for (int c=0;c<8;++c) s += scratchJ[(b*8+c)*512 + f];
    out[4456448 + i] = s * (1.f/1024.f);
  } else {
    int j = i - 4096;
    int b = j >> 9, f = j & 511;
    float s = 0.f;
    for (int r=0;r<64;++r) s += out[(size_t)TOPC + (size_t)(b*64+r)*512 + f];
    out[4460544 + j] = s * (1.f/64.f);
  }
}

extern "C" void kernel_launch(void* const* d_in, const int* in_sizes, int n_in,
                              void* d_out, int out_size, void* d_ws, size_t ws_size,
                              hipStream_t stream){
  const float* op_x      = (const float*)d_in[0];
  const float* machine_x = (const float*)d_in[1];
  const float* W_emb_op  = (const float*)d_in[2];
  const float* b_emb_op  = (const float*)d_in[3];
  const float* W_emb_m   = (const float*)d_in[4];
  const float* b_emb_m   = (const float*)d_in[5];
  const float* opn_w     = (const float*)d_in[6];
  const float* opn_b     = (const float*)d_in[7];
  const float* mn_w      = (const float*)d_in[8];
  const float* mn_b      = (const float*)d_in[9];
  const float* Wk        = (const float*)d_in[10];
  const float* bk        = (const float*)d_in[11];
  const float* Wq        = (const float*)d_in[12];
  const float* bq        = (const float*)d_in[13];
  const float* Wv        = (const float*)d_in[14];
  const float* bv        = (const float*)d_in[15];
  const float* A_rel     = (const float*)d_in[16];
  const float* M_rel     = (const float*)d_in[17];
  const float* p_rel     = (const float*)d_in[18];
  const float* W_out     = (const float*)d_in[19];
  const float* b_out     = (const float*)d_in[20];
  const float* skip      = (const float*)d_in[21];
  const float* ln_w      = (const float*)d_in[22];
  const float* ln_b      = (const float*)d_in[23];
  const int* s1          = (const int*)d_in[25];
  float* out = (float*)d_out;

  char* ws = (char*)d_ws;
  size_t off = 0;
  auto alloc = [&](size_t bytes)->void*{
    void* p = ws + off;
    off = (off + bytes + 255) & ~(size_t)255;
    return p;
  };
  float* pstat     = (float*)alloc(8192*4);       // A: op@0(2048f) m@2048 ; B: op@4096 m@6144
  float* scratchJ  = (float*)alloc(32768*4);
  float* Ct        = (float*)alloc((size_t)NMS*1024*4);
  float* Cn        = (float*)alloc((size_t)NOPS*64*4);
  float* x_op      = (float*)alloc((size_t)NOPS*512*4);   // rolling pre-LN tensor (y, o0, o1, o2)
  u16*   x_op_bf   = (u16*)  alloc((size_t)NOPS*512*2);   // bf16 of same
  float* x_m       = (float*)alloc((size_t)NMS*512*4);
  u16*   x_m_bf    = (u16*)  alloc((size_t)NMS*512*2);
  u16*   qkv_op    = (u16*)  alloc((size_t)NOPS*CQ*2);
  u16*   qkv_m     = (u16*)  alloc((size_t)NMS*CM*2);
  u16*   agg_op    = (u16*)  alloc((size_t)NOPS*512*2);
  u16*   agg_m     = (u16*)  alloc((size_t)NMS*512*2);
  u16*   Wc_op_t   = (u16*)  alloc((size_t)3*CQ*512*2);
  float* bias_op   = (float*)alloc((size_t)3*CQ*4);
  u16*   Wc_m_t    = (u16*)  alloc((size_t)3*CM*512*2);
  float* bias_m    = (float*)alloc((size_t)3*CM*4);
  float* u_op      = (float*)alloc((size_t)3*CQ*4);
  float* u_m       = (float*)alloc((size_t)3*CM*4);
  u16*   Wout_t    = (u16*)  alloc((size_t)6*262144*2);
  float* psA   = pstat;          float* psA_m = pstat + 2048;
  float* psB   = pstat + 4096;   float* psB_m = pstat + 6144;

  // mega setup (everything independent in ONE dispatch), then the weight fold
  setup_all_k<<<4700,256,0,stream>>>(s1, Ct, Cn, bq, bias_op, bias_m, bk, bv, A_rel, M_rel,
                                     W_out, Wq, Wout_t, Wc_op_t, Wc_m_t, Wk, Wv,
                                     op_x, W_emb_op, b_emb_op, x_op, x_op_bf,
                                     machine_x, W_emb_m, b_emb_m, x_m, x_m_bf, psA, psA_m);
  foldk<<<192,256,0,stream>>>(Wc_op_t, Wc_m_t, bias_op, bias_m, u_op, u_m,
                              opn_w, opn_b, mn_w, mn_b, ln_w, ln_b);

  for (int l=0; l<3; ++l){
    // ping-pong: layer reads stats of prev pre-LN tensor, gate writes new partials
    float *psR, *psR_m, *psW, *psW_m; int npo, npm;
    if (l == 0){ psR=psA; psR_m=psA_m; psW=psB; psW_m=psB_m; npo=1024; npm=128; }
    else if (l == 1){ psR=psB; psR_m=psB_m; psW=psA; psW_m=psA_m; npo=256; npm=16; }
    else { psR=psA; psR_m=psA_m; psW=psB; psW_m=psB_m; npo=256; npm=16; }
    const float* lnw_o = (l==0) ? opn_w : ln_w + (l-1)*512;
    const float* lnb_o = (l==0) ? opn_b : ln_b + (l-1)*512;
    const float* lnw_m2 = (l==0) ? mn_w : ln_w + (l-1)*512;
    const float* lnb_m2 = (l==0) ? mn_b : ln_b + (l-1)*512;
    // QKV GEMM with LN folded (reads pre-LN bf16 A + stats)
    gemm8_k<<<332,512,131136,stream>>>(x_op_bf, Wc_op_t + (size_t)l*CQ*512, bias_op + l*CQ, u_op + l*CQ,
                                       qkv_op, CQ, 10, 320,
                                       x_m_bf, Wc_m_t + (size_t)l*CM*512, bias_m + l*CM, u_m + l*CM,
                                       qkv_m, CM, 6,
                                       psR, npo, psR_m, npm);
    // merged attention: machine flash first (long pole), op-side fills around it
    attn_k<<<1280,256,0,stream>>>(qkv_op, qkv_m, p_rel + l*24, Cn, Ct, agg_op, agg_m);
    // W_out GEMM + gated residual (LN-affine) -> new pre-LN tensor (f32+bf16) + stats
    gemmgate2_k<<<272,256,0,stream>>>(agg_op, Wout_t + (size_t)(l*2+0)*262144, x_op,
                                      b_out + (size_t)(l*2+0)*512, skip + l*2+0,
                                      lnw_o, lnb_o, x_op, x_op_bf, psW, 256,
                                      agg_m, Wout_t + (size_t)(l*2+1)*262144, x_m,
                                      b_out + (size_t)(l*2+1)*512, skip + l*2+1,
                                      lnw_m2, lnb_m2, x_m, x_m_bf, psW_m,
                                      psR, npo, psR_m, npm);
  }

  // final graph-LN -> out (stats in psB from layer 2)
  ln2_k<<<1152,256,0,stream>>>(x_op, out, ln_w + 1024, ln_b + 1024,
                               x_m, out + TOPC, ln_w + 1024, ln_b + 1024,
                               psB, psB_m, 256, 16);

  meanj_part_k<<<dim3(8,8),512,0,stream>>>(out, scratchJ);
  mean2_k<<<16,512,0,stream>>>(scratchJ, out);
}

// Round 10
// 523.409 us; speedup vs baseline: 1.1242x; 1.0030x over previous
//
#include <hip/hip_runtime.h>

typedef unsigned short u16;
typedef __attribute__((ext_vector_type(4))) float floatx4;
typedef __attribute__((ext_vector_type(8))) short shortx8;
typedef __attribute__((ext_vector_type(4))) short shortx4;

#define NOPS 8192
#define NMS  512
#define CQ   2560   // op qkv cols: q | k0 | v0 | k2 | v2
#define CM   1536   // machine qkv cols: q | k1 | v1
#define TOPC (NOPS*512)
#define TMC  (NMS*512)

__device__ __forceinline__ float bf2f(u16 u){ return __uint_as_float(((unsigned)u)<<16); }
__device__ __forceinline__ u16 f2bf(float f){
  unsigned u = __float_as_uint(f);
  u += 0x7FFFu + ((u>>16)&1u);
  return (u16)(u>>16);
}
__device__ __forceinline__ float wred(float v){
  #pragma unroll
  for (int o=32;o;o>>=1) v += __shfl_xor(v,o,64);
  return v;
}
__device__ __forceinline__ float geluf(float x){
  return 0.5f*x*(1.f+erff(x*0.70710678118654752f));
}
// block (s,s2) reduction -> one pair at pstat[slot]
__device__ __forceinline__ void block_stat_out2(float s, float s2, float* pstat, int slot){
  __shared__ float sb[8];
  s = wred(s); s2 = wred(s2);
  int wv = threadIdx.x >> 6;
  if ((threadIdx.x & 63) == 0){ sb[wv*2] = s; sb[wv*2+1] = s2; }
  __syncthreads();
  if (threadIdx.x == 0){
    float a = 0.f, b = 0.f;
    int nw = blockDim.x >> 6;
    for (int i=0;i<nw;++i){ a += sb[i*2]; b += sb[i*2+1]; }
    pstat[slot*2]   = a;
    pstat[slot*2+1] = b;
  }
}

// ---------------- mega setup, LONG-POLE-FIRST ordering ----------------
// blocks: [0,1152) embed ; [1152,1920) tw ; [1920,2496) combine3 ;
//         [2496,4544) cnt2 ; [4544,4556) qb ; [4556,4700) cbias
__global__ __launch_bounds__(256) void setup_all_k(
    const int* __restrict__ s1, float* __restrict__ Ct, float* __restrict__ Cn,
    const float* __restrict__ bq, float* bias_op, float* bias_m,
    const float* __restrict__ bk, const float* __restrict__ bv,
    const float* __restrict__ Ar, const float* __restrict__ Mr,
    const float* __restrict__ Wout, const float* __restrict__ Wq,
    u16* __restrict__ Wout_t, u16* __restrict__ Wc_op_t, u16* __restrict__ Wc_m_t,
    const float* __restrict__ Wk, const float* __restrict__ Wv,
    const float* __restrict__ Xop, const float* __restrict__ Wop, const float* __restrict__ bop,
    float* __restrict__ Yop, u16* __restrict__ Yop_bf,
    const float* __restrict__ Xm, const float* __restrict__ Wm, const float* __restrict__ bm_,
    float* __restrict__ Ym, u16* __restrict__ Ym_bf,
    float* pstat, float* pstat_m){
  __shared__ __align__(16) char smem[27648];
  int bid = blockIdx.x;
  int tid = threadIdx.x;
  if (bid < 1152){
    // embed (longest blocks first): op [0,1024) / m [1024,1152)
    int eb = bid;
    const float *X, *W, *bias; float *Y, *ps; u16* Yb; int K, total, nb, lb;
    if (eb < 1024){ X=Xop; W=Wop; bias=bop; Y=Yop; Yb=Yop_bf; ps=pstat;   K=16; total=TOPC; nb=1024; lb=eb; }
    else          { X=Xm;  W=Wm;  bias=bm_; Y=Ym;  Yb=Ym_bf;  ps=pstat_m; K=8;  total=TMC;  nb=128;  lb=eb-1024; }
    float s = 0.f, s2 = 0.f;
    for (int idx = lb*256 + tid; idx < total; idx += nb*256){
      int n = idx >> 9, f = idx & 511;
      float v = bias[f];
      for (int c=0;c<K;++c) v += X[n*K+c] * W[c*512+f];
      Y[idx] = v;
      Yb[idx] = f2bf(v);
      s += v; s2 += v*v;
    }
    block_stat_out2(s, s2, ps, lb);
  } else if (bid < 1920){
    // tw: transpose W_out (6 slabs) + Wq (6 slabs)
    u16 (*t)[65] = (u16(*)[65])smem;
    int id2 = bid - 1152;
    int g = id2 >> 6; int rem = id2 & 63;
    int kb = (rem >> 3) * 64, nb = (rem & 7) * 64;
    const float* s; u16* d;
    if (g < 6){
      s = Wout + (size_t)g*262144;
      d = Wout_t + (size_t)g*262144;
    } else {
      int blk = g - 6; int l = blk >> 1, side = blk & 1;
      s = Wq + (size_t)blk*262144;
      d = side ? (Wc_m_t + (size_t)l*CM*512) : (Wc_op_t + (size_t)l*CQ*512);
    }
    int tx = tid & 63, ty4 = tid >> 6;
    #pragma unroll 4
    for (int p=0;p<16;++p){
      int k = ty4 + p*4;
      t[k][tx] = f2bf(s[(size_t)(kb+k)*512 + nb + tx]);
    }
    __syncthreads();
    #pragma unroll 4
    for (int p=0;p<16;++p){
      int n = ty4 + p*4;
      d[(size_t)(nb+n)*512 + kb + tx] = t[tx][n];
    }
  } else if (bid < 2496){
    // combine3: relation combine via MFMA
    u16* As = (u16*)smem;          // 64*72
    u16* Bs = As + 64*72;          // 128*72
    int id3 = bid - 1920;
    int gx = id3 >> 2;
    int cc0 = (id3 & 3) * 128;
    int l = gx/48; int rem = gx - l*48; int s = rem >> 3; int h = rem & 7;
    int side = (s < 4) ? 0 : 1;
    int r = (s < 4) ? (s+1) : (s-3);
    int useK = side==0 ? (s==0 || s==2) : (s==4);
    int rel  = side==0 ? ((s<2)?0:2) : 1;
    const float* W   = (useK ? Wk : Wv) + (size_t)(l*2+side)*262144;
    const float* Rel = (useK ? Ar : Mr) + ((size_t)(l*3+rel)*8 + h)*4096;
    int h64 = h*64;
    u16* Wt = side ? (Wc_m_t + (size_t)l*CM*512) : (Wc_op_t + (size_t)l*CQ*512);
    int rbase = r*512 + h64;
    int lane = tid & 63, wave = tid >> 6;
    {
      int d = tid >> 2, e0 = (tid & 3) * 16;
      #pragma unroll
      for (int j=0;j<16;++j) As[(e0+j)*72 + d] = f2bf(Rel[d*64 + e0 + j]);
    }
    {
      int ccl = tid >> 1, d0 = (tid & 1) * 32;
      const float* src = W + (size_t)(cc0+ccl)*512 + h64 + d0;
      #pragma unroll
      for (int j=0;j<32;j+=4){
        floatx4 v = *(const floatx4*)(src + j);
        shortx4 sv;
        #pragma unroll
        for (int e=0;e<4;++e) sv[e] = (short)f2bf(v[e]);
        *(shortx4*)(Bs + ccl*72 + d0 + j) = sv;
      }
    }
    __syncthreads();
    int wm = wave & 1, wn = wave >> 1;
    int mrow = lane & 15, quad = lane >> 4;
    floatx4 acc[2][4];
    #pragma unroll
    for (int a=0;a<2;++a)
      #pragma unroll
      for (int b=0;b<4;++b) acc[a][b] = (floatx4){0.f,0.f,0.f,0.f};
    #pragma unroll
    for (int ks=0; ks<2; ++ks){
      shortx8 af[2], bf[4];
      #pragma unroll
      for (int mt=0;mt<2;++mt) af[mt] = *(const shortx8*)(As + (wm*32 + mt*16 + mrow)*72 + ks*32 + quad*8);
      #pragma unroll
      for (int nt=0;nt<4;++nt) bf[nt] = *(const shortx8*)(Bs + (wn*64 + nt*16 + mrow)*72 + ks*32 + quad*8);
      #pragma unroll
      for (int mt=0;mt<2;++mt)
        #pragma unroll
        for (int nt=0;nt<4;++nt)
          acc[mt][nt] = __builtin_amdgcn_mfma_f32_16x16x32_bf16(af[mt], bf[nt], acc[mt][nt], 0, 0, 0);
    }
    #pragma unroll
    for (int mt=0;mt<2;++mt){
      #pragma unroll
      for (int nt=0;nt<4;++nt){
        int ccl = wn*64 + nt*16 + mrow;
        #pragma unroll
        for (int r2=0;r2<4;++r2){
          int e = wm*32 + mt*16 + quad*4 + r2;
          Wt[(size_t)(rbase + e)*512 + cc0 + ccl] = f2bf(acc[mt][nt][r2]);
        }
      }
    }
  } else if (bid < 4544){
    int idx = (bid-2496)*256 + tid;      // 524288
    int n = idx >> 6, l = idx & 63;
    const int* row = s1 + n*8;
    int cnt = 0;
    #pragma unroll
    for (int j=0;j<8;++j) cnt += ((row[j] & 63) == l);
    float f = (float)cnt;
    Cn[(size_t)n*64 + l] = f;
    int b = n >> 10, nl = n & 1023;
    Ct[(size_t)((b<<6) + l)*1024 + nl] = f;
  } else if (bid < 4556){
    int i = (bid-4544)*256 + tid;   // < 3072
    int l = i >> 10, side = (i >> 9) & 1, f = i & 511;
    float v = bq[(l*2+side)*512 + f];
    if (side==0) bias_op[l*CQ + f] = v; else bias_m[l*CM + f] = v;
  } else {
    if (tid >= 64) return;
    int gx = bid - 4556; int e = tid;
    int l = gx/48; int rem = gx - l*48; int s = rem >> 3; int h = rem & 7;
    int side = (s < 4) ? 0 : 1;
    int r = (s < 4) ? (s+1) : (s-3);
    int useK = side==0 ? (s==0 || s==2) : (s==4);
    int rel  = side==0 ? ((s<2)?0:2) : 1;
    const float* bb  = (useK ? bk : bv) + (size_t)(l*2+side)*512 + h*64;
    const float* Rel = (useK ? Ar : Mr) + ((size_t)(l*3+rel)*8 + h)*4096;
    float acc = 0.f;
    for (int d=0; d<64; ++d) acc += bb[d]*Rel[d*64 + e];
    float* bias = side ? (bias_m + l*CM) : (bias_op + l*CQ);
    bias[r*512 + h*64 + e] = acc;
  }
}

// ---------------- LN fold: u=w@Wc, bias+=b@Wc, Wt *= w (in place) ----------------
__global__ __launch_bounds__(256) void foldk(u16* __restrict__ Wc_op_t, u16* __restrict__ Wc_m_t,
                                             float* __restrict__ bias_op, float* __restrict__ bias_m,
                                             float* __restrict__ u_op, float* __restrict__ u_m,
                                             const float* __restrict__ opn_w, const float* __restrict__ opn_b,
                                             const float* __restrict__ mn_w, const float* __restrict__ mn_b,
                                             const float* __restrict__ ln_w, const float* __restrict__ ln_b){
  int bid = blockIdx.x, tid = threadIdx.x;
  int rloc = tid >> 2, t = tid & 3;
  int side, l; u16* Wt; float* bias; float* u;
  if (bid < 120){
    int row = bid*64 + rloc; side = 0; l = row/2560; int j = row - l*2560;
    Wt = Wc_op_t + ((size_t)l*CQ + j)*512; bias = bias_op + l*CQ + j; u = u_op + l*CQ + j;
  } else {
    int row = (bid-120)*64 + rloc; side = 1; l = row/1536; int j = row - l*1536;
    Wt = Wc_m_t + ((size_t)l*CM + j)*512; bias = bias_m + l*CM + j; u = u_m + l*CM + j;
  }
  const float* w = side ? (l==0 ? mn_w : ln_w + (l-1)*512) : (l==0 ? opn_w : ln_w + (l-1)*512);
  const float* b = side ? (l==0 ? mn_b : ln_b + (l-1)*512) : (l==0 ? opn_b : ln_b + (l-1)*512);
  float up = 0.f, vp = 0.f;
  for (int k = t*128; k < t*128 + 128; k += 8){
    shortx8 wv = *(shortx8*)(Wt + k);
    #pragma unroll
    for (int e=0;e<8;++e){
      float x = bf2f((u16)wv[e]);
      float wk = w[k+e];
      up += wk*x; vp += b[k+e]*x;
      wv[e] = (short)f2bf(x*wk);
    }
    *(shortx8*)(Wt + k) = wv;
  }
  up += __shfl_xor(up,1,64); up += __shfl_xor(up,2,64);
  vp += __shfl_xor(vp,1,64); vp += __shfl_xor(vp,2,64);
  if (t == 0){ *u = up; *bias += vp; }
}

// ---------------- final graph-LN apply (used once, writes `out`) ----------------
__global__ __launch_bounds__(256) void ln2_k(const float* __restrict__ src_op, float* __restrict__ dst_op,
                                             const float* __restrict__ w_op, const float* __restrict__ b_op,
                                             const float* __restrict__ src_m, float* __restrict__ dst_m,
                                             const float* __restrict__ w_m, const float* __restrict__ b_m,
                                             const float* __restrict__ pstat, const float* __restrict__ pstat_m,
                                             int nbo, int nbm){
  int bid = blockIdx.x;
  const float *src, *w, *b, *ps; float* dst; int total4, nb, lb, nblk; float inv_n;
  if (bid < 1024){ src=src_op; dst=dst_op; w=w_op; b=b_op; ps=pstat;
                   total4=TOPC/4; nb=1024; lb=bid; nblk=nbo; inv_n=1.f/TOPC; }
  else           { src=src_m;  dst=dst_m;  w=w_m;  b=b_m;  ps=pstat_m;
                   total4=TMC/4;  nb=128;  lb=bid-1024; nblk=nbm; inv_n=1.f/TMC; }
  __shared__ float sb[8];
  __shared__ float mr[2];
  float s = 0.f, s2 = 0.f;
  for (int i = threadIdx.x; i < nblk; i += 256){ s += ps[2*i]; s2 += ps[2*i+1]; }
  s = wred(s); s2 = wred(s2);
  int wv = threadIdx.x >> 6;
  if ((threadIdx.x & 63) == 0){ sb[wv*2] = s; sb[wv*2+1] = s2; }
  __syncthreads();
  if (threadIdx.x == 0){
    float a = 0.f, bsum = 0.f;
    for (int i=0;i<4;++i){ a += sb[i*2]; bsum += sb[i*2+1]; }
    float mean = a * inv_n;
    float var  = fmaxf(bsum * inv_n - mean*mean, 0.f);
    mr[0] = mean;
    mr[1] = 1.f/(sqrtf(var) + 1e-5f);
  }
  __syncthreads();
  float mean = mr[0], rinv = mr[1];
  const floatx4* s4 = (const floatx4*)src;
  floatx4* d4 = (floatx4*)dst;
  const floatx4* w4 = (const floatx4*)w;
  const floatx4* b4 = (const floatx4*)b;
  for (int i = lb*256 + threadIdx.x; i < total4; i += nb*256){
    int f = i & 127;
    floatx4 v = s4[i], wv2 = w4[f], bv = b4[f];
    #pragma unroll
    for (int e=0;e<4;++e) v[e] = (v[e]-mean)*rinv*wv2[e] + bv[e];
    d4[i] = v;
  }
}

// ---------------- W_out GEMM + gated residual (LN-affine on x) + f32/bf16 out + LN partials ----------------
__device__ __forceinline__ void gemm_gate_core(u16* As, u16* Bs, float* stb,
                                               const u16* __restrict__ A, const u16* __restrict__ Bt,
                                               const float* __restrict__ xr, const float* __restrict__ bo,
                                               const float* __restrict__ sk,
                                               const float* __restrict__ lnw, const float* __restrict__ lnb,
                                               const float* __restrict__ psr, int np, float inv_n,
                                               float* __restrict__ Y, u16* __restrict__ Ybf,
                                               float* pstat, int slot, int bx, int by){
  const int tid = threadIdx.x;
  const int lane = tid & 63, wave = tid >> 6;
  // ---- stats of previous-layer pre-LN tensor ----
  {
    float s = 0.f, s2 = 0.f;
    for (int i = tid; i < np; i += 256){ s += psr[2*i]; s2 += psr[2*i+1]; }
    s = wred(s); s2 = wred(s2);
    if (lane == 0){ stb[wave*2] = s; stb[wave*2+1] = s2; }
    __syncthreads();
    if (tid == 0){
      float a = 0.f, bb = 0.f;
      for (int i=0;i<4;++i){ a += stb[2*i]; bb += stb[2*i+1]; }
      float mean = a * inv_n;
      float var = fmaxf(bb * inv_n - mean*mean, 0.f);
      stb[8] = mean;
      stb[9] = 1.f/(sqrtf(var) + 1e-5f);
    }
    __syncthreads();
  }
  const float mean = stb[8], rinv = stb[9];
  const int bm = by * 128, bn = bx * 128;
  const int wm = wave & 1, wn = wave >> 1;
  const int mrow = lane & 15, quad = lane >> 4;
  const u16* Ab = A + (size_t)bm*512;
  const u16* Bb = Bt + (size_t)bn*512;
  floatx4 acc[4][4];
  #pragma unroll
  for (int a=0;a<4;++a)
    #pragma unroll
    for (int b=0;b<4;++b) acc[a][b] = (floatx4){0.f,0.f,0.f,0.f};
  const int r0 = tid >> 2, c0 = (tid & 3) * 8;
  const int r1 = (tid+256) >> 2, c1 = ((tid+256) & 3) * 8;
  const int lds0 = wave*512;
  const int lds1 = wave*512 + 2048;
  for (int k0 = 0; k0 < 512; k0 += 32){
    __builtin_amdgcn_global_load_lds((const __attribute__((address_space(1))) void*)(Ab + (size_t)r0*512 + k0 + c0),
                                     (__attribute__((address_space(3))) void*)(As + lds0), 16, 0, 0);
    __builtin_amdgcn_global_load_lds((const __attribute__((address_space(1))) void*)(Ab + (size_t)r1*512 + k0 + c1),
                                     (__attribute__((address_space(3))) void*)(As + lds1), 16, 0, 0);
    __builtin_amdgcn_global_load_lds((const __attribute__((address_space(1))) void*)(Bb + (size_t)r0*512 + k0 + c0),
                                     (__attribute__((address_space(3))) void*)(Bs + lds0), 16, 0, 0);
    __builtin_amdgcn_global_load_lds((const __attribute__((address_space(1))) void*)(Bb + (size_t)r1*512 + k0 + c1),
                                     (__attribute__((address_space(3))) void*)(Bs + lds1), 16, 0, 0);
    __syncthreads();
    shortx8 af[4], bf[4];
    #pragma unroll
    for (int mt=0;mt<4;++mt) af[mt] = *(const shortx8*)(As + (wm*64 + mt*16 + mrow)*32 + quad*8);
    #pragma unroll
    for (int nt=0;nt<4;++nt) bf[nt] = *(const shortx8*)(Bs + (wn*64 + nt*16 + mrow)*32 + quad*8);
    #pragma unroll
    for (int mt=0;mt<4;++mt)
      #pragma unroll
      for (int nt=0;nt<4;++nt)
        acc[mt][nt] = __builtin_amdgcn_mfma_f32_16x16x32_bf16(af[mt], bf[nt], acc[mt][nt], 0, 0, 0);
    __syncthreads();
  }
  float g = 1.f/(1.f+expf(-(*sk)));
  float s = 0.f, s2 = 0.f;
  #pragma unroll
  for (int mt=0;mt<4;++mt){
    #pragma unroll
    for (int nt=0;nt<4;++nt){
      int col = bn + wn*64 + nt*16 + mrow;
      float bval = bo[col];
      float lw = lnw[col]*rinv, lb = lnb[col];
      #pragma unroll
      for (int r2=0;r2<4;++r2){
        int row = bm + wm*64 + mt*16 + quad*4 + r2;
        float v = acc[mt][nt][r2] + bval;
        float xv = (xr[(size_t)row*512 + col] - mean)*lw + lb;   // x = LN(prev)
        float o = g*v + (2.f-g)*xv;
        Y[(size_t)row*512 + col] = o;
        Ybf[(size_t)row*512 + col] = f2bf(o);
        s += o; s2 += o*o;
      }
    }
  }
  block_stat_out2(s, s2, pstat, slot);
}
__global__ __launch_bounds__(256) void gemmgate2_k(
    const u16* A1, const u16* B1, const float* x1, const float* bo1, const float* sk1,
    const float* lnw1, const float* lnb1, float* Y1, u16* Yb1, float* ps1w, int nblk1,
    const u16* A2, const u16* B2, const float* x2, const float* bo2, const float* sk2,
    const float* lnw2, const float* lnb2, float* Y2, u16* Yb2, float* ps2w,
    const float* ps1r, int np1, const float* ps2r, int np2){
  __shared__ u16 As[128*32];
  __shared__ u16 Bs[128*32];
  __shared__ float stb[12];
  int id = blockIdx.x;
  if (id < nblk1)
    gemm_gate_core(As, Bs, stb, A1, B1, x1, bo1, sk1, lnw1, lnb1, ps1r, np1, 1.f/TOPC,
                   Y1, Yb1, ps1w, id, id % 4, id / 4);
  else {
    int j = id - nblk1;
    gemm_gate_core(As, Bs, stb, A2, B2, x2, bo2, sk2, lnw2, lnb2, ps2r, np2, 1.f/TMC,
                   Y2, Yb2, ps2w, j, j % 4, j / 4);
  }
}

// ---------------- 256x256 8-phase GEMM (QKV projections), K=512, LN folded ----------------
__device__ __forceinline__ void stage_half8(const u16* __restrict__ src, int kc, u16* region, int tid){
  int wave = tid >> 6;
  #pragma unroll
  for (int j=0;j<2;++j){
    int idx = j*512 + tid;
    int row = idx >> 2, qp2 = idx & 3;
    int qs = qp2 ^ (((row >> 3) & 1) << 1);   // st_16x32 pre-swizzled global source
    __builtin_amdgcn_global_load_lds(
      (const __attribute__((address_space(1))) void*)(src + (size_t)row*512 + kc + qs*8),
      (__attribute__((address_space(3))) void*)(region + (j*512 + wave*64)*8),
      16, 0, 0);
  }
}

#define MFMA_QUAD(MH) do { \
  __builtin_amdgcn_s_barrier(); \
  asm volatile("s_waitcnt lgkmcnt(0)" ::: "memory"); \
  __builtin_amdgcn_sched_barrier(0); \
  __builtin_amdgcn_s_setprio(1); \
  _Pragma("unroll") \
  for (int mt=0;mt<4;++mt){ \
    _Pragma("unroll") \
    for (int nt=0;nt<4;++nt) \
      acc[(MH)*4+mt][nt] = __builtin_amdgcn_mfma_f32_16x16x32_bf16(af[mt], bf[nt], acc[(MH)*4+mt][nt], 0, 0, 0); \
  } \
  __builtin_amdgcn_s_setprio(0); \
} while(0)

__global__ __launch_bounds__(512, 2) void gemm8_k(
    const u16* __restrict__ A1, const u16* __restrict__ B1, const float* __restrict__ bias1,
    const float* __restrict__ u1, u16* __restrict__ C1, int N1, int nbx1, int nblk1,
    const u16* __restrict__ A2, const u16* __restrict__ B2, const float* __restrict__ bias2p,
    const float* __restrict__ u2, u16* __restrict__ C2, int N2, int nbx2,
    const float* __restrict__ ps1, int np1, const float* __restrict__ ps2, int np2){
  extern __shared__ u16 lds[];      // 131072 B staging + 64 B stats scratch
  float* statsh = (float*)(lds + 65536);
  int id = blockIdx.x;
  const u16 *A, *Bt; const float *bias, *uvec, *ps; u16* C; int N, bx, by, np; float inv_n;
  if (id < nblk1){
    int xcd = id & 7, loc = id >> 3;
    int wg = xcd * (nblk1 >> 3) + loc;
    A=A1; Bt=B1; bias=bias1; uvec=u1; C=C1; N=N1; bx=wg%nbx1; by=wg/nbx1;
    ps=ps1; np=np1; inv_n=1.f/TOPC;
  }
  else { int j=id-nblk1; A=A2; Bt=B2; bias=bias2p; uvec=u2; C=C2; N=N2; bx=j%nbx2; by=j/nbx2;
    ps=ps2; np=np2; inv_n=1.f/TMC; }
  const int tid = threadIdx.x, lane = tid & 63, wave = tid >> 6;
  // ---- stats (mean/rinv of pre-LN A tensor) ----
  {
    float s = 0.f, s2 = 0.f;
    for (int i = tid; i < np; i += 512){ s += ps[2*i]; s2 += ps[2*i+1]; }
    s = wred(s); s2 = wred(s2);
    if (lane == 0){ statsh[wave*2] = s; statsh[wave*2+1] = s2; }
    __syncthreads();
    if (tid == 0){
      float a = 0.f, bb = 0.f;
      for (int i=0;i<8;++i){ a += statsh[2*i]; bb += statsh[2*i+1]; }
      float mean = a * inv_n;
      float var = fmaxf(bb * inv_n - mean*mean, 0.f);
      statsh[16] = mean;
      statsh[17] = 1.f/(sqrtf(var) + 1e-5f);
    }
    __syncthreads();
  }
  const float mean = statsh[16], rinv = statsh[17];
  const int wm = wave & 1, wn = wave >> 1;
  const int mrow = lane & 15, quad = lane >> 4;
  const int qp = quad ^ ((mrow & 8) ? 2 : 0);
  const u16* Ab = A + (size_t)(by*256)*512;
  const u16* Bb = Bt + (size_t)(bx*256)*512;

  floatx4 acc[8][4];
  #pragma unroll
  for (int a=0;a<8;++a)
    #pragma unroll
    for (int b=0;b<4;++b) acc[a][b] = (floatx4){0.f,0.f,0.f,0.f};

  stage_half8(Ab, 0,  lds,          tid);
  stage_half8(Bb, 0,  lds + 16384,  tid);
  stage_half8(Ab, 32, lds + 8192,   tid);
  stage_half8(Bb, 32, lds + 24576,  tid);
  stage_half8(Ab, 64, lds + 32768,  tid);
  stage_half8(Bb, 64, lds + 49152,  tid);
  asm volatile("s_waitcnt vmcnt(8)" ::: "memory");
  __builtin_amdgcn_s_barrier();

  for (int t = 0; t < 8; ++t){
    const int s = t & 1;
    u16* Sbase = lds + s*32768;
    u16* Obase = lds + (s^1)*32768;
    const u16* a0 = Sbase + (wm*128 + mrow)*32 + qp*8;
    const u16* b0 = Sbase + 16384 + (wn*64 + mrow)*32 + qp*8;
    const int kc1 = ((t < 7) ? (t+1) : 7)*64 + 32;
    const int kc2 = ((t < 6) ? (t+2) : 7)*64;
    shortx8 af[4], bf[4];

    #pragma unroll
    for (int mt=0;mt<4;++mt) af[mt] = *(const shortx8*)(a0 + mt*512);
    #pragma unroll
    for (int nt=0;nt<4;++nt) bf[nt] = *(const shortx8*)(b0 + nt*512);
    stage_half8(Ab, kc1, Obase + 8192, tid);
    MFMA_QUAD(0);
    __builtin_amdgcn_s_barrier();

    #pragma unroll
    for (int mt=0;mt<4;++mt) af[mt] = *(const shortx8*)(a0 + 2048 + mt*512);
    stage_half8(Bb, kc1, Obase + 24576, tid);
    MFMA_QUAD(1);
    asm volatile("s_waitcnt vmcnt(8)" ::: "memory");
    __builtin_amdgcn_s_barrier();

    #pragma unroll
    for (int mt=0;mt<4;++mt) af[mt] = *(const shortx8*)(a0 + 8192 + mt*512);
    #pragma unroll
    for (int nt=0;nt<4;++nt) bf[nt] = *(const shortx8*)(b0 + 8192 + nt*512);
    stage_half8(Ab, kc2, Sbase, tid);
    MFMA_QUAD(0);
    __builtin_amdgcn_s_barrier();

    #pragma unroll
    for (int mt=0;mt<4;++mt) af[mt] = *(const shortx8*)(a0 + 8192 + 2048 + mt*512);
    stage_half8(Bb, kc2, Sbase + 16384, tid);
    MFMA_QUAD(1);
    asm volatile("s_waitcnt vmcnt(8)" ::: "memory");
    __builtin_amdgcn_s_barrier();
  }

  // epilogue: qkv = rinv*acc + bias2[col] - rinv*mean*u[col]
  const float rm = rinv*mean;
  const int crow0 = by*256 + wm*128 + quad*4;
  const int ccol0 = bx*256 + wn*64 + mrow;
  float bv[4], uv[4];
  #pragma unroll
  for (int nt=0;nt<4;++nt){
    int col = ccol0 + nt*16;
    bv[nt] = bias[col];
    uv[nt] = uvec[col];
  }
  #pragma unroll
  for (int mh=0;mh<2;++mh){
    #pragma unroll
    for (int mt=0;mt<4;++mt){
      int row = crow0 + mh*64 + mt*16;
      #pragma unroll
      for (int nt=0;nt<4;++nt){
        int col = ccol0 + nt*16;
        #pragma unroll
        for (int r2=0;r2<4;++r2)
          C[(size_t)(row+r2)*N + col] = f2bf(rinv*acc[mh*4+mt][nt][r2] + bv[nt] - rm*uv[nt]);
      }
    }
  }
}

// ---------------- merged attention: [0,256) machine ONLINE flash (long pole, scheduled first);
//                  [256,1280) op-side fused attn ----------------
__global__ __launch_bounds__(256) void attn_k(const u16* __restrict__ qkv_op, const u16* __restrict__ qkv_m,
                                              const float* __restrict__ prel, const float* __restrict__ Cn,
                                              const float* __restrict__ Ct,
                                              u16* __restrict__ agg_op, u16* __restrict__ agg_m){
  __shared__ __align__(16) char smem[43520];
  int id = blockIdx.x;
  int tid = threadIdx.x, lane = tid & 63, wave = tid >> 6;
  int mrow = lane & 15, quad = lane >> 4;
  if (id < 256){
    // ---- machine-side ONLINE flash (single pass, running max + rescale) ----
    u16* qs  = (u16*)smem;                 // 16*72 -> 2304B
    u16* ks  = (u16*)(smem + 2304);        // 128*72 -> 18432B
    u16* vsT = (u16*)(smem + 20736);       // 64*136 -> 17408B
    u16* Ps  = (u16*)(smem + 38144);       // 16*136 -> 4352B
    float (*redv)[4][16] = (float(*)[4][16])(smem + 42496);  // 2*4*16 f32
    int g = id & 3; int bh = id >> 2; int b = bh >> 3, h = bh & 7;
    int w = wave;
    float p2 = prel[16 + h] * 0.125f;
    if (tid < 128){
      int r = tid >> 3, cg = (tid & 7) * 8;
      *(shortx8*)(qs + r*72 + cg) = *(const shortx8*)(qkv_m + (size_t)(b*64 + g*16 + r)*CM + h*64 + cg);
    }
    const float* ctbase = Ct + (size_t)(b*64 + g*16 + mrow)*1024;
    float mold_m = -1e30f;                     // running max for P-row mrow
    float mold4[4] = {-1e30f,-1e30f,-1e30f,-1e30f};  // running max for O-rows quad*4+r2
    float L = 0.f;
    floatx4 O = (floatx4){0,0,0,0};
    for (int ch = 0; ch < 8; ++ch){
      int nb = ch*128;
      #pragma unroll
      for (int i=0;i<4;++i){
        int idx = i*256 + tid;
        int r = idx >> 3, cg = (idx & 7) * 8;
        *(shortx8*)(ks + r*72 + cg) =
          *(const shortx8*)(qkv_op + (size_t)(b*1024 + nb + r)*CQ + 1536 + h*64 + cg);
        shortx8 vv = *(const shortx8*)(qkv_op + (size_t)(b*1024 + nb + r)*CQ + 2048 + h*64 + cg);
        #pragma unroll
        for (int e=0;e<8;++e) vsT[(cg+e)*136 + r] = (u16)vv[e];
      }
      __syncthreads();   // ks/vsT (and qs on ch0) visible
      floatx4 sa[2], cv[2];
      #pragma unroll
      for (int nt=0; nt<2; ++nt){
        floatx4 acc = (floatx4){0,0,0,0};
        #pragma unroll
        for (int kk=0; kk<2; ++kk){
          shortx8 af = *(const shortx8*)(ks + (w*32 + nt*16 + mrow)*72 + kk*32 + quad*8);
          shortx8 bf = *(const shortx8*)(qs + mrow*72 + kk*32 + quad*8);
          acc = __builtin_amdgcn_mfma_f32_16x16x32_bf16(af, bf, acc, 0, 0, 0);
        }
        int nloc = w*32 + nt*16 + quad*4;
        cv[nt] = *(const floatx4*)(ctbase + nb + nloc);
        #pragma unroll
        for (int r2=0;r2<4;++r2) acc[r2] *= p2;
        sa[nt] = acc;
      }
      // masked chunk row-max
      float cm = -1e30f;
      #pragma unroll
      for (int nt=0;nt<2;++nt)
        #pragma unroll
        for (int r2=0;r2<4;++r2)
          if (cv[nt][r2] > 0.f) cm = fmaxf(cm, sa[nt][r2]);
      cm = fmaxf(cm, __shfl_xor(cm, 16, 64));
      cm = fmaxf(cm, __shfl_xor(cm, 32, 64));
      if (lane < 16) redv[0][w][lane] = cm;
      __syncthreads();   // redv visible
      float mnew_m = fmaxf(fmaxf(redv[0][0][mrow], redv[0][1][mrow]),
                           fmaxf(redv[0][2][mrow], redv[0][3][mrow]));
      mnew_m = fmaxf(mnew_m, mold_m);
      float sL = expf(mold_m - mnew_m);
      mold_m = mnew_m;
      float sO[4];
      #pragma unroll
      for (int r2=0;r2<4;++r2){
        int r = quad*4 + r2;
        float mn = fmaxf(fmaxf(redv[0][0][r], redv[0][1][r]),
                         fmaxf(redv[0][2][r], redv[0][3][r]));
        mn = fmaxf(mn, mold4[r2]);
        sO[r2] = expf(mold4[r2] - mn);
        mold4[r2] = mn;
      }
      float Lsum = 0.f;
      #pragma unroll
      for (int nt=0;nt<2;++nt){
        int nloc = w*32 + nt*16 + quad*4;
        shortx4 pv;
        #pragma unroll
        for (int r2=0;r2<4;++r2){
          float e = (cv[nt][r2] > 0.f) ? cv[nt][r2]*expf(sa[nt][r2] - mnew_m) : 0.f;
          Lsum += e;
          pv[r2] = (short)f2bf(e);
        }
        *(shortx4*)(Ps + mrow*136 + nloc) = pv;
      }
      L = L*sL + Lsum;
      __syncthreads();   // Ps visible (written cross-wave)
      #pragma unroll
      for (int r2=0;r2<4;++r2) O[r2] *= sO[r2];
      #pragma unroll
      for (int kk=0; kk<4; ++kk){
        shortx8 af = *(const shortx8*)(Ps + mrow*136 + kk*32 + quad*8);
        shortx8 bf = *(const shortx8*)(vsT + (w*16 + mrow)*136 + kk*32 + quad*8);
        O = __builtin_amdgcn_mfma_f32_16x16x32_bf16(af, bf, O, 0, 0, 0);
      }
      __syncthreads();   // before next chunk overwrites ks/vsT/Ps/redv
    }
    L += __shfl_xor(L, 16, 64);
    L += __shfl_xor(L, 32, 64);
    if (lane < 16) redv[1][w][lane] = L;
    __syncthreads();
    #pragma unroll
    for (int r2=0;r2<4;++r2){
      int m = quad*4 + r2;
      float Ls = redv[1][0][m] + redv[1][1][m] + redv[1][2][m] + redv[1][3][m];
      float v = O[r2] / (Ls + 1e-16f);
      agg_m[(size_t)(b*64 + g*16 + m)*512 + h*64 + w*16 + mrow] = f2bf(geluf(v));
    }
  } else {
    // ---- op-side: S-GEMM + wave-parallel softmax + PV, QBLK=64 ----
    u16* smem16 = (u16*)smem;
    u16* As = smem16;                        // 64*72 u16
    u16* Bs = smem16 + 4608;                 // 64*72 u16
    float* Sbuf = (float*)smem;              // 64*66 f32, aliases As/Bs after S-GEMM
    u16* P   = smem16 + 9216;                // 64*72 u16
    u16* v1T = smem16 + 13824;               // 64*72 u16
    float* wpreS = (float*)(smem + 36864);   // 64 f32
    float* linvS = (float*)(smem + 37120);   // 64 f32
    int id2 = id - 256;
    int bh = id2 >> 4; int b = bh >> 3, h = bh & 7;
    int n0 = (id2 & 15) * 64;
    int wm = wave & 1, wn = wave >> 1;
    int srow = tid >> 2, scol = (tid & 3) * 16;
    float p1 = prel[8 + h] * 0.125f;
    { // q_op rows n0..n0+63
      const u16* src = qkv_op + (size_t)(b*1024 + n0 + srow)*CQ + h*64 + scol;
      *(shortx8*)(As + srow*72 + scol)     = *(const shortx8*)(src);
      *(shortx8*)(As + srow*72 + scol + 8) = *(const shortx8*)(src + 8);
    }
    { // k1 (64 machines)
      const u16* src = qkv_m + (size_t)(b*64 + srow)*CM + 512 + h*64 + scol;
      *(shortx8*)(Bs + srow*72 + scol)     = *(const shortx8*)(src);
      *(shortx8*)(Bs + srow*72 + scol + 8) = *(const shortx8*)(src + 8);
    }
    { // v1^T: v1T[d][m] = v1[m][d]
      const u16* src = qkv_m + (size_t)(b*64 + srow)*CM + 1024 + h*64 + scol;
      shortx8 v0 = *(const shortx8*)(src);
      shortx8 v1 = *(const shortx8*)(src + 8);
      #pragma unroll
      for (int e=0;e<8;++e){ v1T[(scol+e)*72 + srow] = (u16)v0[e]; v1T[(scol+8+e)*72 + srow] = (u16)v1[e]; }
    }
    __syncthreads();
    floatx4 acc[2][2];
    #pragma unroll
    for (int a=0;a<2;++a){ acc[a][0] = (floatx4){0,0,0,0}; acc[a][1] = (floatx4){0,0,0,0}; }
    #pragma unroll
    for (int ks=0; ks<2; ++ks){
      shortx8 af[2], bf[2];
      #pragma unroll
      for (int mt=0;mt<2;++mt) af[mt] = *(const shortx8*)(As + (wm*32 + mt*16 + mrow)*72 + ks*32 + quad*8);
      #pragma unroll
      for (int nt=0;nt<2;++nt) bf[nt] = *(const shortx8*)(Bs + (wn*32 + nt*16 + mrow)*72 + ks*32 + quad*8);
      #pragma unroll
      for (int mt=0;mt<2;++mt)
        #pragma unroll
        for (int nt=0;nt<2;++nt)
          acc[mt][nt] = __builtin_amdgcn_mfma_f32_16x16x32_bf16(af[mt], bf[nt], acc[mt][nt], 0, 0, 0);
    }
    __syncthreads();
    #pragma unroll
    for (int mt=0;mt<2;++mt){
      #pragma unroll
      for (int nt=0;nt<2;++nt){
        int m = wn*32 + nt*16 + mrow;
        #pragma unroll
        for (int r2=0;r2<4;++r2){
          int nl = wm*32 + mt*16 + quad*4 + r2;
          Sbuf[nl*66 + m] = acc[mt][nt][r2] * p1;
        }
      }
    }
    __syncthreads();
    { // wave-parallel softmax: 4 threads per row
      int row = srow;
      int mb  = scol;
      int n_g = b*1024 + n0 + row;
      int nl  = n0 + row;
      float sp = -1e30f;
      if (nl > 0){
        float p0 = prel[h] * 0.125f;
        const u16* qp = qkv_op + (size_t)n_g*CQ + h*64 + mb;
        const u16* kp = qkv_op + (size_t)(n_g-1)*CQ + 512 + h*64 + mb;
        shortx8 qa = *(const shortx8*)(qp), qb2 = *(const shortx8*)(qp + 8);
        shortx8 ka = *(const shortx8*)(kp), kb2 = *(const shortx8*)(kp + 8);
        float d = 0.f;
        #pragma unroll
        for (int e=0;e<8;++e) d += bf2f((u16)qa[e])*bf2f((u16)ka[e]) + bf2f((u16)qb2[e])*bf2f((u16)kb2[e]);
        d += __shfl_xor(d, 1, 64);
        d += __shfl_xor(d, 2, 64);
        sp = d * p0;
      }
      const float* crow = Cn + (size_t)n_g*64 + mb;
      float cv[16];
      float mx = sp;
      #pragma unroll
      for (int j=0;j<16;++j){
        cv[j] = crow[j];
        if (cv[j] > 0.f) mx = fmaxf(mx, Sbuf[row*66 + mb + j]);
      }
      mx = fmaxf(mx, __shfl_xor(mx, 1, 64));
      mx = fmaxf(mx, __shfl_xor(mx, 2, 64));
      float L = 0.f;
      #pragma unroll
      for (int j=0;j<16;j+=4){
        shortx4 pv;
        #pragma unroll
        for (int e=0;e<4;++e){
          float w = (cv[j+e] > 0.f) ? cv[j+e]*expf(Sbuf[row*66 + mb + j + e] - mx) : 0.f;
          L += w;
          pv[e] = (short)f2bf(w);
        }
        *(shortx4*)(P + row*72 + mb + j) = pv;
      }
      L += __shfl_xor(L, 1, 64);
      L += __shfl_xor(L, 2, 64);
      float ep = (nl > 0) ? expf(sp - mx) : 0.f;
      L += ep;
      if ((tid & 3) == 0){ wpreS[row] = ep; linvS[row] = 1.f/(L + 1e-16f); }
    }
    __syncthreads();
    floatx4 po[2][2];
    #pragma unroll
    for (int a=0;a<2;++a){ po[a][0] = (floatx4){0,0,0,0}; po[a][1] = (floatx4){0,0,0,0}; }
    #pragma unroll
    for (int ks=0; ks<2; ++ks){
      shortx8 paf[2], pbf[2];
      #pragma unroll
      for (int mt=0;mt<2;++mt) paf[mt] = *(const shortx8*)(P + (wm*32 + mt*16 + mrow)*72 + ks*32 + quad*8);
      #pragma unroll
      for (int nt=0;nt<2;++nt) pbf[nt] = *(const shortx8*)(v1T + (wn*32 + nt*16 + mrow)*72 + ks*32 + quad*8);
      #pragma unroll
      for (int mt=0;mt<2;++mt)
        #pragma unroll
        for (int nt=0;nt<2;++nt)
          po[mt][nt] = __builtin_amdgcn_mfma_f32_16x16x32_bf16(paf[mt], pbf[nt], po[mt][nt], 0, 0, 0);
    }
    #pragma unroll
    for (int mt=0;mt<2;++mt){
      #pragma unroll
      for (int nt=0;nt<2;++nt){
        int d = wn*32 + nt*16 + mrow;
        #pragma unroll
        for (int r2=0;r2<4;++r2){
          int rl = wm*32 + mt*16 + quad*4 + r2;
          int n = n0 + rl;
          size_t ng = (size_t)b*1024 + n;
          float v = po[mt][nt][r2];
          if (n > 0) v += wpreS[rl] * bf2f(qkv_op[(ng-1)*CQ + 1024 + h*64 + d]);
          v *= linvS[rl];
          agg_op[ng*512 + h*64 + d] = f2bf(geluf(v));
        }
      }
    }
  }
}

// ---------------- means: partials (no atomics) + final merged ----------------
__global__ __launch_bounds__(512) void meanj_part_k(const float* __restrict__ xo, float* scratchJ){
  int b = blockIdx.x, chunk = blockIdx.y, f = threadIdx.x;
  float s = 0.f;
  for (int r=0;r<128;++r){
    int row = b*1024 + chunk*128 + r;
    s += xo[(size_t)row*512 + f];
  }
  scratchJ[(b*8 + chunk)*512 + f] = s;
}
__global__ __launch_bounds__(512) void mean2_k(const float* __restrict__ scratchJ, float* __restrict__ out){
  int i = blockIdx.x*512 + threadIdx.x;   // 8192
  if (i < 4096){
    int b = i >> 9, f = i & 511;
    float s = 0.f;
    #pragma unroll
    for (int c=0;c<8;++c) s += scratchJ[(b*8+c)*512 + f];
    out[4456448 + i] = s * (1.f/1024.f);
  } else {
    int j = i - 4096;
    int b = j >> 9, f = j & 511;
    float s = 0.f;
    for (int r=0;r<64;++r) s += out[(size_t)TOPC + (size_t)(b*64+r)*512 + f];
    out[4460544 + j] = s * (1.f/64.f);
  }
}

extern "C" void kernel_launch(void* const* d_in, const int* in_sizes, int n_in,
                              void* d_out, int out_size, void* d_ws, size_t ws_size,
                              hipStream_t stream){
  const float* op_x      = (const float*)d_in[0];
  const float* machine_x = (const float*)d_in[1];
  const float* W_emb_op  = (const float*)d_in[2];
  const float* b_emb_op  = (const float*)d_in[3];
  const float* W_emb_m   = (const float*)d_in[4];
  const float* b_emb_m   = (const float*)d_in[5];
  const float* opn_w     = (const float*)d_in[6];
  const float* opn_b     = (const float*)d_in[7];
  const float* mn_w      = (const float*)d_in[8];
  const float* mn_b      = (const float*)d_in[9];
  const float* Wk        = (const float*)d_in[10];
  const float* bk        = (const float*)d_in[11];
  const float* Wq        = (const float*)d_in[12];
  const float* bq        = (const float*)d_in[13];
  const float* Wv        = (const float*)d_in[14];
  const float* bv        = (const float*)d_in[15];
  const float* A_rel     = (const float*)d_in[16];
  const float* M_rel     = (const float*)d_in[17];
  const float* p_rel     = (const float*)d_in[18];
  const float* W_out     = (const float*)d_in[19];
  const float* b_out     = (const float*)d_in[20];
  const float* skip      = (const float*)d_in[21];
  const float* ln_w      = (const float*)d_in[22];
  const float* ln_b      = (const float*)d_in[23];
  const int* s1          = (const int*)d_in[25];
  float* out = (float*)d_out;

  char* ws = (char*)d_ws;
  size_t off = 0;
  auto alloc = [&](size_t bytes)->void*{
    void* p = ws + off;
    off = (off + bytes + 255) & ~(size_t)255;
    return p;
  };
  float* pstat     = (float*)alloc(8192*4);       // A: op@0(2048f) m@2048 ; B: op@4096 m@6144
  float* scratchJ  = (float*)alloc(32768*4);
  float* Ct        = (float*)alloc((size_t)NMS*1024*4);
  float* Cn        = (float*)alloc((size_t)NOPS*64*4);
  float* x_op      = (float*)alloc((size_t)NOPS*512*4);   // rolling pre-LN tensor (y, o0, o1, o2)
  u16*   x_op_bf   = (u16*)  alloc((size_t)NOPS*512*2);   // bf16 of same
  float* x_m       = (float*)alloc((size_t)NMS*512*4);
  u16*   x_m_bf    = (u16*)  alloc((size_t)NMS*512*2);
  u16*   qkv_op    = (u16*)  alloc((size_t)NOPS*CQ*2);
  u16*   qkv_m     = (u16*)  alloc((size_t)NMS*CM*2);
  u16*   agg_op    = (u16*)  alloc((size_t)NOPS*512*2);
  u16*   agg_m     = (u16*)  alloc((size_t)NMS*512*2);
  u16*   Wc_op_t   = (u16*)  alloc((size_t)3*CQ*512*2);
  float* bias_op   = (float*)alloc((size_t)3*CQ*4);
  u16*   Wc_m_t    = (u16*)  alloc((size_t)3*CM*512*2);
  float* bias_m    = (float*)alloc((size_t)3*CM*4);
  float* u_op      = (float*)alloc((size_t)3*CQ*4);
  float* u_m       = (float*)alloc((size_t)3*CM*4);
  u16*   Wout_t    = (u16*)  alloc((size_t)6*262144*2);
  float* psA   = pstat;          float* psA_m = pstat + 2048;
  float* psB   = pstat + 4096;   float* psB_m = pstat + 6144;

  // mega setup (long-pole segments first), then the weight fold
  setup_all_k<<<4700,256,0,stream>>>(s1, Ct, Cn, bq, bias_op, bias_m, bk, bv, A_rel, M_rel,
                                     W_out, Wq, Wout_t, Wc_op_t, Wc_m_t, Wk, Wv,
                                     op_x, W_emb_op, b_emb_op, x_op, x_op_bf,
                                     machine_x, W_emb_m, b_emb_m, x_m, x_m_bf, psA, psA_m);
  foldk<<<192,256,0,stream>>>(Wc_op_t, Wc_m_t, bias_op, bias_m, u_op, u_m,
                              opn_w, opn_b, mn_w, mn_b, ln_w, ln_b);

  for (int l=0; l<3; ++l){
    // ping-pong: layer reads stats of prev pre-LN tensor, gate writes new partials
    float *psR, *psR_m, *psW, *psW_m; int npo, npm;
    if (l == 0){ psR=psA; psR_m=psA_m; psW=psB; psW_m=psB_m; npo=1024; npm=128; }
    else if (l == 1){ psR=psB; psR_m=psB_m; psW=psA; psW_m=psA_m; npo=256; npm=16; }
    else { psR=psA; psR_m=psA_m; psW=psB; psW_m=psB_m; npo=256; npm=16; }
    const float* lnw_o = (l==0) ? opn_w : ln_w + (l-1)*512;
    const float* lnb_o = (l==0) ? opn_b : ln_b + (l-1)*512;
    const float* lnw_m2 = (l==0) ? mn_w : ln_w + (l-1)*512;
    const float* lnb_m2 = (l==0) ? mn_b : ln_b + (l-1)*512;
    // QKV GEMM with LN folded (reads pre-LN bf16 A + stats)
    gemm8_k<<<332,512,131136,stream>>>(x_op_bf, Wc_op_t + (size_t)l*CQ*512, bias_op + l*CQ, u_op + l*CQ,
                                       qkv_op, CQ, 10, 320,
                                       x_m_bf, Wc_m_t + (size_t)l*CM*512, bias_m + l*CM, u_m + l*CM,
                                       qkv_m, CM, 6,
                                       psR, npo, psR_m, npm);
    // merged attention: machine flash first (long pole), op-side fills around it
    attn_k<<<1280,256,0,stream>>>(qkv_op, qkv_m, p_rel + l*24, Cn, Ct, agg_op, agg_m);
    // W_out GEMM + gated residual (LN-affine) -> new pre-LN tensor (f32+bf16) + stats
    gemmgate2_k<<<272,256,0,stream>>>(agg_op, Wout_t + (size_t)(l*2+0)*262144, x_op,
                                      b_out + (size_t)(l*2+0)*512, skip + l*2+0,
                                      lnw_o, lnb_o, x_op, x_op_bf, psW, 256,
                                      agg_m, Wout_t + (size_t)(l*2+1)*262144, x_m,
                                      b_out + (size_t)(l*2+1)*512, skip + l*2+1,
                                      lnw_m2, lnb_m2, x_m, x_m_bf, psW_m,
                                      psR, npo, psR_m, npm);
  }

  // final graph-LN -> out (stats in psB from layer 2)
  ln2_k<<<1152,256,0,stream>>>(x_op, out, ln_w + 1024, ln_b + 1024,
                               x_m, out + TOPC, ln_w + 1024, ln_b + 1024,
                               psB, psB_m, 256, 16);

  meanj_part_k<<<dim3(8,8),512,0,stream>>>(out, scratchJ);
  mean2_k<<<16,512,0,stream>>>(scratchJ, out);
}

// Round 11
// 523.335 us; speedup vs baseline: 1.1243x; 1.0001x over previous
//
#include <hip/hip_runtime.h>

typedef unsigned short u16;
typedef __attribute__((ext_vector_type(4))) float floatx4;
typedef __attribute__((ext_vector_type(8))) short shortx8;
typedef __attribute__((ext_vector_type(4))) short shortx4;

#define NOPS 8192
#define NMS  512
#define CQ   2560   // op qkv cols: q | k0 | v0 | k2 | v2
#define CM   1536   // machine qkv cols: q | k1 | v1
#define TOPC (NOPS*512)
#define TMC  (NMS*512)

__device__ __forceinline__ float bf2f(u16 u){ return __uint_as_float(((unsigned)u)<<16); }
__device__ __forceinline__ u16 f2bf(float f){
  unsigned u = __float_as_uint(f);
  u += 0x7FFFu + ((u>>16)&1u);
  return (u16)(u>>16);
}
__device__ __forceinline__ float wred(float v){
  #pragma unroll
  for (int o=32;o;o>>=1) v += __shfl_xor(v,o,64);
  return v;
}
__device__ __forceinline__ float geluf(float x){
  return 0.5f*x*(1.f+erff(x*0.70710678118654752f));
}
// block (s,s2) reduction -> one pair at pstat[slot]
__device__ __forceinline__ void block_stat_out2(float s, float s2, float* pstat, int slot){
  __shared__ float sb[8];
  s = wred(s); s2 = wred(s2);
  int wv = threadIdx.x >> 6;
  if ((threadIdx.x & 63) == 0){ sb[wv*2] = s; sb[wv*2+1] = s2; }
  __syncthreads();
  if (threadIdx.x == 0){
    float a = 0.f, b = 0.f;
    int nw = blockDim.x >> 6;
    for (int i=0;i<nw;++i){ a += sb[i*2]; b += sb[i*2+1]; }
    pstat[slot*2]   = a;
    pstat[slot*2+1] = b;
  }
}

// ---------------- mega setup, LONG-POLE-FIRST ordering ----------------
// blocks: [0,1152) embed ; [1152,1920) tw ; [1920,2496) combine3 ;
//         [2496,4544) cnt2 ; [4544,4556) qb ; [4556,4700) cbias
__global__ __launch_bounds__(256) void setup_all_k(
    const int* __restrict__ s1, float* __restrict__ Ct, float* __restrict__ Cn,
    const float* __restrict__ bq, float* bias_op, float* bias_m,
    const float* __restrict__ bk, const float* __restrict__ bv,
    const float* __restrict__ Ar, const float* __restrict__ Mr,
    const float* __restrict__ Wout, const float* __restrict__ Wq,
    u16* __restrict__ Wout_t, u16* __restrict__ Wc_op_t, u16* __restrict__ Wc_m_t,
    const float* __restrict__ Wk, const float* __restrict__ Wv,
    const float* __restrict__ Xop, const float* __restrict__ Wop, const float* __restrict__ bop,
    float* __restrict__ Yop, u16* __restrict__ Yop_bf,
    const float* __restrict__ Xm, const float* __restrict__ Wm, const float* __restrict__ bm_,
    float* __restrict__ Ym, u16* __restrict__ Ym_bf,
    float* pstat, float* pstat_m){
  __shared__ __align__(16) char smem[27648];
  int bid = blockIdx.x;
  int tid = threadIdx.x;
  if (bid < 1152){
    // embed (longest blocks first): op [0,1024) / m [1024,1152)
    int eb = bid;
    const float *X, *W, *bias; float *Y, *ps; u16* Yb; int K, total, nb, lb;
    if (eb < 1024){ X=Xop; W=Wop; bias=bop; Y=Yop; Yb=Yop_bf; ps=pstat;   K=16; total=TOPC; nb=1024; lb=eb; }
    else          { X=Xm;  W=Wm;  bias=bm_; Y=Ym;  Yb=Ym_bf;  ps=pstat_m; K=8;  total=TMC;  nb=128;  lb=eb-1024; }
    float s = 0.f, s2 = 0.f;
    for (int idx = lb*256 + tid; idx < total; idx += nb*256){
      int n = idx >> 9, f = idx & 511;
      float v = bias[f];
      for (int c=0;c<K;++c) v += X[n*K+c] * W[c*512+f];
      Y[idx] = v;
      Yb[idx] = f2bf(v);
      s += v; s2 += v*v;
    }
    block_stat_out2(s, s2, ps, lb);
  } else if (bid < 1920){
    // tw: transpose W_out (6 slabs) + Wq (6 slabs)
    u16 (*t)[65] = (u16(*)[65])smem;
    int id2 = bid - 1152;
    int g = id2 >> 6; int rem = id2 & 63;
    int kb = (rem >> 3) * 64, nb = (rem & 7) * 64;
    const float* s; u16* d;
    if (g < 6){
      s = Wout + (size_t)g*262144;
      d = Wout_t + (size_t)g*262144;
    } else {
      int blk = g - 6; int l = blk >> 1, side = blk & 1;
      s = Wq + (size_t)blk*262144;
      d = side ? (Wc_m_t + (size_t)l*CM*512) : (Wc_op_t + (size_t)l*CQ*512);
    }
    int tx = tid & 63, ty4 = tid >> 6;
    #pragma unroll 4
    for (int p=0;p<16;++p){
      int k = ty4 + p*4;
      t[k][tx] = f2bf(s[(size_t)(kb+k)*512 + nb + tx]);
    }
    __syncthreads();
    #pragma unroll 4
    for (int p=0;p<16;++p){
      int n = ty4 + p*4;
      d[(size_t)(nb+n)*512 + kb + tx] = t[tx][n];
    }
  } else if (bid < 2496){
    // combine3: relation combine via MFMA
    u16* As = (u16*)smem;          // 64*72
    u16* Bs = As + 64*72;          // 128*72
    int id3 = bid - 1920;
    int gx = id3 >> 2;
    int cc0 = (id3 & 3) * 128;
    int l = gx/48; int rem = gx - l*48; int s = rem >> 3; int h = rem & 7;
    int side = (s < 4) ? 0 : 1;
    int r = (s < 4) ? (s+1) : (s-3);
    int useK = side==0 ? (s==0 || s==2) : (s==4);
    int rel  = side==0 ? ((s<2)?0:2) : 1;
    const float* W   = (useK ? Wk : Wv) + (size_t)(l*2+side)*262144;
    const float* Rel = (useK ? Ar : Mr) + ((size_t)(l*3+rel)*8 + h)*4096;
    int h64 = h*64;
    u16* Wt = side ? (Wc_m_t + (size_t)l*CM*512) : (Wc_op_t + (size_t)l*CQ*512);
    int rbase = r*512 + h64;
    int lane = tid & 63, wave = tid >> 6;
    {
      int d = tid >> 2, e0 = (tid & 3) * 16;
      #pragma unroll
      for (int j=0;j<16;++j) As[(e0+j)*72 + d] = f2bf(Rel[d*64 + e0 + j]);
    }
    {
      int ccl = tid >> 1, d0 = (tid & 1) * 32;
      const float* src = W + (size_t)(cc0+ccl)*512 + h64 + d0;
      #pragma unroll
      for (int j=0;j<32;j+=4){
        floatx4 v = *(const floatx4*)(src + j);
        shortx4 sv;
        #pragma unroll
        for (int e=0;e<4;++e) sv[e] = (short)f2bf(v[e]);
        *(shortx4*)(Bs + ccl*72 + d0 + j) = sv;
      }
    }
    __syncthreads();
    int wm = wave & 1, wn = wave >> 1;
    int mrow = lane & 15, quad = lane >> 4;
    floatx4 acc[2][4];
    #pragma unroll
    for (int a=0;a<2;++a)
      #pragma unroll
      for (int b=0;b<4;++b) acc[a][b] = (floatx4){0.f,0.f,0.f,0.f};
    #pragma unroll
    for (int ks=0; ks<2; ++ks){
      shortx8 af[2], bf[4];
      #pragma unroll
      for (int mt=0;mt<2;++mt) af[mt] = *(const shortx8*)(As + (wm*32 + mt*16 + mrow)*72 + ks*32 + quad*8);
      #pragma unroll
      for (int nt=0;nt<4;++nt) bf[nt] = *(const shortx8*)(Bs + (wn*64 + nt*16 + mrow)*72 + ks*32 + quad*8);
      #pragma unroll
      for (int mt=0;mt<2;++mt)
        #pragma unroll
        for (int nt=0;nt<4;++nt)
          acc[mt][nt] = __builtin_amdgcn_mfma_f32_16x16x32_bf16(af[mt], bf[nt], acc[mt][nt], 0, 0, 0);
    }
    #pragma unroll
    for (int mt=0;mt<2;++mt){
      #pragma unroll
      for (int nt=0;nt<4;++nt){
        int ccl = wn*64 + nt*16 + mrow;
        #pragma unroll
        for (int r2=0;r2<4;++r2){
          int e = wm*32 + mt*16 + quad*4 + r2;
          Wt[(size_t)(rbase + e)*512 + cc0 + ccl] = f2bf(acc[mt][nt][r2]);
        }
      }
    }
  } else if (bid < 4544){
    int idx = (bid-2496)*256 + tid;      // 524288
    int n = idx >> 6, l = idx & 63;
    const int* row = s1 + n*8;
    int cnt = 0;
    #pragma unroll
    for (int j=0;j<8;++j) cnt += ((row[j] & 63) == l);
    float f = (float)cnt;
    Cn[(size_t)n*64 + l] = f;
    int b = n >> 10, nl = n & 1023;
    Ct[(size_t)((b<<6) + l)*1024 + nl] = f;
  } else if (bid < 4556){
    int i = (bid-4544)*256 + tid;   // < 3072
    int l = i >> 10, side = (i >> 9) & 1, f = i & 511;
    float v = bq[(l*2+side)*512 + f];
    if (side==0) bias_op[l*CQ + f] = v; else bias_m[l*CM + f] = v;
  } else {
    if (tid >= 64) return;
    int gx = bid - 4556; int e = tid;
    int l = gx/48; int rem = gx - l*48; int s = rem >> 3; int h = rem & 7;
    int side = (s < 4) ? 0 : 1;
    int r = (s < 4) ? (s+1) : (s-3);
    int useK = side==0 ? (s==0 || s==2) : (s==4);
    int rel  = side==0 ? ((s<2)?0:2) : 1;
    const float* bb  = (useK ? bk : bv) + (size_t)(l*2+side)*512 + h*64;
    const float* Rel = (useK ? Ar : Mr) + ((size_t)(l*3+rel)*8 + h)*4096;
    float acc = 0.f;
    for (int d=0; d<64; ++d) acc += bb[d]*Rel[d*64 + e];
    float* bias = side ? (bias_m + l*CM) : (bias_op + l*CQ);
    bias[r*512 + h*64 + e] = acc;
  }
}

// ---------------- LN fold: u=w@Wc, bias+=b@Wc, Wt *= w (in place) ----------------
__global__ __launch_bounds__(256) void foldk(u16* __restrict__ Wc_op_t, u16* __restrict__ Wc_m_t,
                                             float* __restrict__ bias_op, float* __restrict__ bias_m,
                                             float* __restrict__ u_op, float* __restrict__ u_m,
                                             const float* __restrict__ opn_w, const float* __restrict__ opn_b,
                                             const float* __restrict__ mn_w, const float* __restrict__ mn_b,
                                             const float* __restrict__ ln_w, const float* __restrict__ ln_b){
  int bid = blockIdx.x, tid = threadIdx.x;
  int rloc = tid >> 2, t = tid & 3;
  int side, l; u16* Wt; float* bias; float* u;
  if (bid < 120){
    int row = bid*64 + rloc; side = 0; l = row/2560; int j = row - l*2560;
    Wt = Wc_op_t + ((size_t)l*CQ + j)*512; bias = bias_op + l*CQ + j; u = u_op + l*CQ + j;
  } else {
    int row = (bid-120)*64 + rloc; side = 1; l = row/1536; int j = row - l*1536;
    Wt = Wc_m_t + ((size_t)l*CM + j)*512; bias = bias_m + l*CM + j; u = u_m + l*CM + j;
  }
  const float* w = side ? (l==0 ? mn_w : ln_w + (l-1)*512) : (l==0 ? opn_w : ln_w + (l-1)*512);
  const float* b = side ? (l==0 ? mn_b : ln_b + (l-1)*512) : (l==0 ? opn_b : ln_b + (l-1)*512);
  float up = 0.f, vp = 0.f;
  for (int k = t*128; k < t*128 + 128; k += 8){
    shortx8 wv = *(shortx8*)(Wt + k);
    #pragma unroll
    for (int e=0;e<8;++e){
      float x = bf2f((u16)wv[e]);
      float wk = w[k+e];
      up += wk*x; vp += b[k+e]*x;
      wv[e] = (short)f2bf(x*wk);
    }
    *(shortx8*)(Wt + k) = wv;
  }
  up += __shfl_xor(up,1,64); up += __shfl_xor(up,2,64);
  vp += __shfl_xor(vp,1,64); vp += __shfl_xor(vp,2,64);
  if (t == 0){ *u = up; *bias += vp; }
}

// ---------------- final graph-LN apply (used once, writes `out`) ----------------
__global__ __launch_bounds__(256) void ln2_k(const float* __restrict__ src_op, float* __restrict__ dst_op,
                                             const float* __restrict__ w_op, const float* __restrict__ b_op,
                                             const float* __restrict__ src_m, float* __restrict__ dst_m,
                                             const float* __restrict__ w_m, const float* __restrict__ b_m,
                                             const float* __restrict__ pstat, const float* __restrict__ pstat_m,
                                             int nbo, int nbm){
  int bid = blockIdx.x;
  const float *src, *w, *b, *ps; float* dst; int total4, nb, lb, nblk; float inv_n;
  if (bid < 1024){ src=src_op; dst=dst_op; w=w_op; b=b_op; ps=pstat;
                   total4=TOPC/4; nb=1024; lb=bid; nblk=nbo; inv_n=1.f/TOPC; }
  else           { src=src_m;  dst=dst_m;  w=w_m;  b=b_m;  ps=pstat_m;
                   total4=TMC/4;  nb=128;  lb=bid-1024; nblk=nbm; inv_n=1.f/TMC; }
  __shared__ float sb[8];
  __shared__ float mr[2];
  float s = 0.f, s2 = 0.f;
  for (int i = threadIdx.x; i < nblk; i += 256){ s += ps[2*i]; s2 += ps[2*i+1]; }
  s = wred(s); s2 = wred(s2);
  int wv = threadIdx.x >> 6;
  if ((threadIdx.x & 63) == 0){ sb[wv*2] = s; sb[wv*2+1] = s2; }
  __syncthreads();
  if (threadIdx.x == 0){
    float a = 0.f, bsum = 0.f;
    for (int i=0;i<4;++i){ a += sb[i*2]; bsum += sb[i*2+1]; }
    float mean = a * inv_n;
    float var  = fmaxf(bsum * inv_n - mean*mean, 0.f);
    mr[0] = mean;
    mr[1] = 1.f/(sqrtf(var) + 1e-5f);
  }
  __syncthreads();
  float mean = mr[0], rinv = mr[1];
  const floatx4* s4 = (const floatx4*)src;
  floatx4* d4 = (floatx4*)dst;
  const floatx4* w4 = (const floatx4*)w;
  const floatx4* b4 = (const floatx4*)b;
  for (int i = lb*256 + threadIdx.x; i < total4; i += nb*256){
    int f = i & 127;
    floatx4 v = s4[i], wv2 = w4[f], bv = b4[f];
    #pragma unroll
    for (int e=0;e<4;++e) v[e] = (v[e]-mean)*rinv*wv2[e] + bv[e];
    d4[i] = v;
  }
}

// ---------------- W_out GEMM + gated residual (LN-affine on x) + f32/bf16 out + LN partials ----------------
__device__ __forceinline__ void gemm_gate_core(u16* As, u16* Bs, float* stb,
                                               const u16* __restrict__ A, const u16* __restrict__ Bt,
                                               const float* __restrict__ xr, const float* __restrict__ bo,
                                               const float* __restrict__ sk,
                                               const float* __restrict__ lnw, const float* __restrict__ lnb,
                                               const float* __restrict__ psr, int np, float inv_n,
                                               float* __restrict__ Y, u16* __restrict__ Ybf,
                                               float* pstat, int slot, int bx, int by){
  const int tid = threadIdx.x;
  const int lane = tid & 63, wave = tid >> 6;
  // ---- stats of previous-layer pre-LN tensor ----
  {
    float s = 0.f, s2 = 0.f;
    for (int i = tid; i < np; i += 256){ s += psr[2*i]; s2 += psr[2*i+1]; }
    s = wred(s); s2 = wred(s2);
    if (lane == 0){ stb[wave*2] = s; stb[wave*2+1] = s2; }
    __syncthreads();
    if (tid == 0){
      float a = 0.f, bb = 0.f;
      for (int i=0;i<4;++i){ a += stb[2*i]; bb += stb[2*i+1]; }
      float mean = a * inv_n;
      float var = fmaxf(bb * inv_n - mean*mean, 0.f);
      stb[8] = mean;
      stb[9] = 1.f/(sqrtf(var) + 1e-5f);
    }
    __syncthreads();
  }
  const float mean = stb[8], rinv = stb[9];
  const int bm = by * 128, bn = bx * 128;
  const int wm = wave & 1, wn = wave >> 1;
  const int mrow = lane & 15, quad = lane >> 4;
  const u16* Ab = A + (size_t)bm*512;
  const u16* Bb = Bt + (size_t)bn*512;
  floatx4 acc[4][4];
  #pragma unroll
  for (int a=0;a<4;++a)
    #pragma unroll
    for (int b=0;b<4;++b) acc[a][b] = (floatx4){0.f,0.f,0.f,0.f};
  const int r0 = tid >> 2, c0 = (tid & 3) * 8;
  const int r1 = (tid+256) >> 2, c1 = ((tid+256) & 3) * 8;
  const int lds0 = wave*512;
  const int lds1 = wave*512 + 2048;
  for (int k0 = 0; k0 < 512; k0 += 32){
    __builtin_amdgcn_global_load_lds((const __attribute__((address_space(1))) void*)(Ab + (size_t)r0*512 + k0 + c0),
                                     (__attribute__((address_space(3))) void*)(As + lds0), 16, 0, 0);
    __builtin_amdgcn_global_load_lds((const __attribute__((address_space(1))) void*)(Ab + (size_t)r1*512 + k0 + c1),
                                     (__attribute__((address_space(3))) void*)(As + lds1), 16, 0, 0);
    __builtin_amdgcn_global_load_lds((const __attribute__((address_space(1))) void*)(Bb + (size_t)r0*512 + k0 + c0),
                                     (__attribute__((address_space(3))) void*)(Bs + lds0), 16, 0, 0);
    __builtin_amdgcn_global_load_lds((const __attribute__((address_space(1))) void*)(Bb + (size_t)r1*512 + k0 + c1),
                                     (__attribute__((address_space(3))) void*)(Bs + lds1), 16, 0, 0);
    __syncthreads();
    shortx8 af[4], bf[4];
    #pragma unroll
    for (int mt=0;mt<4;++mt) af[mt] = *(const shortx8*)(As + (wm*64 + mt*16 + mrow)*32 + quad*8);
    #pragma unroll
    for (int nt=0;nt<4;++nt) bf[nt] = *(const shortx8*)(Bs + (wn*64 + nt*16 + mrow)*32 + quad*8);
    #pragma unroll
    for (int mt=0;mt<4;++mt)
      #pragma unroll
      for (int nt=0;nt<4;++nt)
        acc[mt][nt] = __builtin_amdgcn_mfma_f32_16x16x32_bf16(af[mt], bf[nt], acc[mt][nt], 0, 0, 0);
    __syncthreads();
  }
  float g = 1.f/(1.f+expf(-(*sk)));
  float s = 0.f, s2 = 0.f;
  #pragma unroll
  for (int mt=0;mt<4;++mt){
    #pragma unroll
    for (int nt=0;nt<4;++nt){
      int col = bn + wn*64 + nt*16 + mrow;
      float bval = bo[col];
      float lw = lnw[col]*rinv, lb = lnb[col];
      #pragma unroll
      for (int r2=0;r2<4;++r2){
        int row = bm + wm*64 + mt*16 + quad*4 + r2;
        float v = acc[mt][nt][r2] + bval;
        float xv = (xr[(size_t)row*512 + col] - mean)*lw + lb;   // x = LN(prev)
        float o = g*v + (2.f-g)*xv;
        Y[(size_t)row*512 + col] = o;
        Ybf[(size_t)row*512 + col] = f2bf(o);
        s += o; s2 += o*o;
      }
    }
  }
  block_stat_out2(s, s2, pstat, slot);
}
__global__ __launch_bounds__(256) void gemmgate2_k(
    const u16* A1, const u16* B1, const float* x1, const float* bo1, const float* sk1,
    const float* lnw1, const float* lnb1, float* Y1, u16* Yb1, float* ps1w, int nblk1,
    const u16* A2, const u16* B2, const float* x2, const float* bo2, const float* sk2,
    const float* lnw2, const float* lnb2, float* Y2, u16* Yb2, float* ps2w,
    const float* ps1r, int np1, const float* ps2r, int np2){
  __shared__ u16 As[128*32];
  __shared__ u16 Bs[128*32];
  __shared__ float stb[12];
  int id = blockIdx.x;
  if (id < nblk1)
    gemm_gate_core(As, Bs, stb, A1, B1, x1, bo1, sk1, lnw1, lnb1, ps1r, np1, 1.f/TOPC,
                   Y1, Yb1, ps1w, id, id % 4, id / 4);
  else {
    int j = id - nblk1;
    gemm_gate_core(As, Bs, stb, A2, B2, x2, bo2, sk2, lnw2, lnb2, ps2r, np2, 1.f/TMC,
                   Y2, Yb2, ps2w, j, j % 4, j / 4);
  }
}

// ---------------- 256x256 8-phase GEMM (QKV projections), K=512, LN folded ----------------
__device__ __forceinline__ void stage_half8(const u16* __restrict__ src, int kc, u16* region, int tid){
  int wave = tid >> 6;
  #pragma unroll
  for (int j=0;j<2;++j){
    int idx = j*512 + tid;
    int row = idx >> 2, qp2 = idx & 3;
    int qs = qp2 ^ (((row >> 3) & 1) << 1);   // st_16x32 pre-swizzled global source
    __builtin_amdgcn_global_load_lds(
      (const __attribute__((address_space(1))) void*)(src + (size_t)row*512 + kc + qs*8),
      (__attribute__((address_space(3))) void*)(region + (j*512 + wave*64)*8),
      16, 0, 0);
  }
}

#define MFMA_QUAD(MH) do { \
  __builtin_amdgcn_s_barrier(); \
  asm volatile("s_waitcnt lgkmcnt(0)" ::: "memory"); \
  __builtin_amdgcn_sched_barrier(0); \
  __builtin_amdgcn_s_setprio(1); \
  _Pragma("unroll") \
  for (int mt=0;mt<4;++mt){ \
    _Pragma("unroll") \
    for (int nt=0;nt<4;++nt) \
      acc[(MH)*4+mt][nt] = __builtin_amdgcn_mfma_f32_16x16x32_bf16(af[mt], bf[nt], acc[(MH)*4+mt][nt], 0, 0, 0); \
  } \
  __builtin_amdgcn_s_setprio(0); \
} while(0)

__global__ __launch_bounds__(512, 2) void gemm8_k(
    const u16* __restrict__ A1, const u16* __restrict__ B1, const float* __restrict__ bias1,
    const float* __restrict__ u1, u16* __restrict__ C1, int N1, int nbx1, int nblk1,
    const u16* __restrict__ A2, const u16* __restrict__ B2, const float* __restrict__ bias2p,
    const float* __restrict__ u2, u16* __restrict__ C2, int N2, int nbx2,
    const float* __restrict__ ps1, int np1, const float* __restrict__ ps2, int np2){
  extern __shared__ u16 lds[];      // 131072 B staging + 64 B stats scratch
  float* statsh = (float*)(lds + 65536);
  int id = blockIdx.x;
  const u16 *A, *Bt; const float *bias, *uvec, *ps; u16* C; int N, bx, by, np; float inv_n;
  if (id < nblk1){
    int xcd = id & 7, loc = id >> 3;
    int wg = xcd * (nblk1 >> 3) + loc;
    A=A1; Bt=B1; bias=bias1; uvec=u1; C=C1; N=N1; bx=wg%nbx1; by=wg/nbx1;
    ps=ps1; np=np1; inv_n=1.f/TOPC;
  }
  else { int j=id-nblk1; A=A2; Bt=B2; bias=bias2p; uvec=u2; C=C2; N=N2; bx=j%nbx2; by=j/nbx2;
    ps=ps2; np=np2; inv_n=1.f/TMC; }
  const int tid = threadIdx.x, lane = tid & 63, wave = tid >> 6;
  // ---- stats (mean/rinv of pre-LN A tensor) ----
  {
    float s = 0.f, s2 = 0.f;
    for (int i = tid; i < np; i += 512){ s += ps[2*i]; s2 += ps[2*i+1]; }
    s = wred(s); s2 = wred(s2);
    if (lane == 0){ statsh[wave*2] = s; statsh[wave*2+1] = s2; }
    __syncthreads();
    if (tid == 0){
      float a = 0.f, bb = 0.f;
      for (int i=0;i<8;++i){ a += statsh[2*i]; bb += statsh[2*i+1]; }
      float mean = a * inv_n;
      float var = fmaxf(bb * inv_n - mean*mean, 0.f);
      statsh[16] = mean;
      statsh[17] = 1.f/(sqrtf(var) + 1e-5f);
    }
    __syncthreads();
  }
  const float mean = statsh[16], rinv = statsh[17];
  const int wm = wave & 1, wn = wave >> 1;
  const int mrow = lane & 15, quad = lane >> 4;
  const int qp = quad ^ ((mrow & 8) ? 2 : 0);
  const u16* Ab = A + (size_t)(by*256)*512;
  const u16* Bb = Bt + (size_t)(bx*256)*512;

  floatx4 acc[8][4];
  #pragma unroll
  for (int a=0;a<8;++a)
    #pragma unroll
    for (int b=0;b<4;++b) acc[a][b] = (floatx4){0.f,0.f,0.f,0.f};

  stage_half8(Ab, 0,  lds,          tid);
  stage_half8(Bb, 0,  lds + 16384,  tid);
  stage_half8(Ab, 32, lds + 8192,   tid);
  stage_half8(Bb, 32, lds + 24576,  tid);
  stage_half8(Ab, 64, lds + 32768,  tid);
  stage_half8(Bb, 64, lds + 49152,  tid);
  asm volatile("s_waitcnt vmcnt(8)" ::: "memory");
  __builtin_amdgcn_s_barrier();

  for (int t = 0; t < 8; ++t){
    const int s = t & 1;
    u16* Sbase = lds + s*32768;
    u16* Obase = lds + (s^1)*32768;
    const u16* a0 = Sbase + (wm*128 + mrow)*32 + qp*8;
    const u16* b0 = Sbase + 16384 + (wn*64 + mrow)*32 + qp*8;
    const int kc1 = ((t < 7) ? (t+1) : 7)*64 + 32;
    const int kc2 = ((t < 6) ? (t+2) : 7)*64;
    shortx8 af[4], bf[4];

    #pragma unroll
    for (int mt=0;mt<4;++mt) af[mt] = *(const shortx8*)(a0 + mt*512);
    #pragma unroll
    for (int nt=0;nt<4;++nt) bf[nt] = *(const shortx8*)(b0 + nt*512);
    stage_half8(Ab, kc1, Obase + 8192, tid);
    MFMA_QUAD(0);
    __builtin_amdgcn_s_barrier();

    #pragma unroll
    for (int mt=0;mt<4;++mt) af[mt] = *(const shortx8*)(a0 + 2048 + mt*512);
    stage_half8(Bb, kc1, Obase + 24576, tid);
    MFMA_QUAD(1);
    asm volatile("s_waitcnt vmcnt(8)" ::: "memory");
    __builtin_amdgcn_s_barrier();

    #pragma unroll
    for (int mt=0;mt<4;++mt) af[mt] = *(const shortx8*)(a0 + 8192 + mt*512);
    #pragma unroll
    for (int nt=0;nt<4;++nt) bf[nt] = *(const shortx8*)(b0 + 8192 + nt*512);
    stage_half8(Ab, kc2, Sbase, tid);
    MFMA_QUAD(0);
    __builtin_amdgcn_s_barrier();

    #pragma unroll
    for (int mt=0;mt<4;++mt) af[mt] = *(const shortx8*)(a0 + 8192 + 2048 + mt*512);
    stage_half8(Bb, kc2, Sbase + 16384, tid);
    MFMA_QUAD(1);
    asm volatile("s_waitcnt vmcnt(8)" ::: "memory");
    __builtin_amdgcn_s_barrier();
  }

  // epilogue: qkv = rinv*acc + bias2[col] - rinv*mean*u[col]
  const float rm = rinv*mean;
  const int crow0 = by*256 + wm*128 + quad*4;
  const int ccol0 = bx*256 + wn*64 + mrow;
  float bv[4], uv[4];
  #pragma unroll
  for (int nt=0;nt<4;++nt){
    int col = ccol0 + nt*16;
    bv[nt] = bias[col];
    uv[nt] = uvec[col];
  }
  #pragma unroll
  for (int mh=0;mh<2;++mh){
    #pragma unroll
    for (int mt=0;mt<4;++mt){
      int row = crow0 + mh*64 + mt*16;
      #pragma unroll
      for (int nt=0;nt<4;++nt){
        int col = ccol0 + nt*16;
        #pragma unroll
        for (int r2=0;r2<4;++r2)
          C[(size_t)(row+r2)*N + col] = f2bf(rinv*acc[mh*4+mt][nt][r2] + bv[nt] - rm*uv[nt]);
      }
    }
  }
}

// ---------------- merged attention: [0,256) machine ONLINE flash (64-row chunks, 23.5KB LDS);
//                  [256,1280) op-side fused attn. Static smem 37376 -> 4 blocks/CU ----------------
__global__ __launch_bounds__(256) void attn_k(const u16* __restrict__ qkv_op, const u16* __restrict__ qkv_m,
                                              const float* __restrict__ prel, const float* __restrict__ Cn,
                                              const float* __restrict__ Ct,
                                              u16* __restrict__ agg_op, u16* __restrict__ agg_m){
  __shared__ __align__(16) char smem[37376];
  int id = blockIdx.x;
  int tid = threadIdx.x, lane = tid & 63, wave = tid >> 6;
  int mrow = lane & 15, quad = lane >> 4;
  if (id < 256){
    // ---- machine-side ONLINE flash, CH=64 rows/chunk ----
    u16* qs  = (u16*)smem;                 // 16*72 -> [0,2304)
    u16* ks  = (u16*)(smem + 2304);        // 64*72 -> [2304,11520)
    u16* vsT = (u16*)(smem + 11520);       // 64*72 -> [11520,20736)
    u16* Ps  = (u16*)(smem + 20736);       // 16*72 -> [20736,23040)
    float (*redv)[4][16] = (float(*)[4][16])(smem + 23040);  // 2*4*16 f32 -> [23040,23552)
    int g = id & 3; int bh = id >> 2; int b = bh >> 3, h = bh & 7;
    int w = wave;
    float p2 = prel[16 + h] * 0.125f;
    if (tid < 128){
      int r = tid >> 3, cg = (tid & 7) * 8;
      *(shortx8*)(qs + r*72 + cg) = *(const shortx8*)(qkv_m + (size_t)(b*64 + g*16 + r)*CM + h*64 + cg);
    }
    const float* ctbase = Ct + (size_t)(b*64 + g*16 + mrow)*1024;
    float mold_m = -1e30f;                     // running max for P-row mrow
    float mold4[4] = {-1e30f,-1e30f,-1e30f,-1e30f};  // running max for O-rows quad*4+r2
    float L = 0.f;
    floatx4 O = (floatx4){0,0,0,0};
    for (int ch = 0; ch < 16; ++ch){
      int nb = ch*64;
      #pragma unroll
      for (int i=0;i<2;++i){
        int idx = i*256 + tid;
        int r = idx >> 3, cg = (idx & 7) * 8;
        *(shortx8*)(ks + r*72 + cg) =
          *(const shortx8*)(qkv_op + (size_t)(b*1024 + nb + r)*CQ + 1536 + h*64 + cg);
        shortx8 vv = *(const shortx8*)(qkv_op + (size_t)(b*1024 + nb + r)*CQ + 2048 + h*64 + cg);
        #pragma unroll
        for (int e=0;e<8;++e) vsT[(cg+e)*72 + r] = (u16)vv[e];
      }
      __syncthreads();   // ks/vsT (and qs on ch0) visible
      floatx4 sa, cv;
      {
        floatx4 acc = (floatx4){0,0,0,0};
        #pragma unroll
        for (int kk=0; kk<2; ++kk){
          shortx8 af = *(const shortx8*)(ks + (w*16 + mrow)*72 + kk*32 + quad*8);
          shortx8 bf = *(const shortx8*)(qs + mrow*72 + kk*32 + quad*8);
          acc = __builtin_amdgcn_mfma_f32_16x16x32_bf16(af, bf, acc, 0, 0, 0);
        }
        int nloc = w*16 + quad*4;
        cv = *(const floatx4*)(ctbase + nb + nloc);
        #pragma unroll
        for (int r2=0;r2<4;++r2) acc[r2] *= p2;
        sa = acc;
      }
      // masked chunk row-max
      float cm = -1e30f;
      #pragma unroll
      for (int r2=0;r2<4;++r2)
        if (cv[r2] > 0.f) cm = fmaxf(cm, sa[r2]);
      cm = fmaxf(cm, __shfl_xor(cm, 16, 64));
      cm = fmaxf(cm, __shfl_xor(cm, 32, 64));
      if (lane < 16) redv[0][w][lane] = cm;
      __syncthreads();   // redv visible
      float mnew_m = fmaxf(fmaxf(redv[0][0][mrow], redv[0][1][mrow]),
                           fmaxf(redv[0][2][mrow], redv[0][3][mrow]));
      mnew_m = fmaxf(mnew_m, mold_m);
      float sL = expf(mold_m - mnew_m);
      mold_m = mnew_m;
      float sO[4];
      #pragma unroll
      for (int r2=0;r2<4;++r2){
        int r = quad*4 + r2;
        float mn = fmaxf(fmaxf(redv[0][0][r], redv[0][1][r]),
                         fmaxf(redv[0][2][r], redv[0][3][r]));
        mn = fmaxf(mn, mold4[r2]);
        sO[r2] = expf(mold4[r2] - mn);
        mold4[r2] = mn;
      }
      float Lsum = 0.f;
      {
        int nloc = w*16 + quad*4;
        shortx4 pv;
        #pragma unroll
        for (int r2=0;r2<4;++r2){
          float e = (cv[r2] > 0.f) ? cv[r2]*expf(sa[r2] - mnew_m) : 0.f;
          Lsum += e;
          pv[r2] = (short)f2bf(e);
        }
        *(shortx4*)(Ps + mrow*72 + nloc) = pv;
      }
      L = L*sL + Lsum;
      __syncthreads();   // Ps visible (written cross-wave)
      #pragma unroll
      for (int r2=0;r2<4;++r2) O[r2] *= sO[r2];
      #pragma unroll
      for (int kk=0; kk<2; ++kk){
        shortx8 af = *(const shortx8*)(Ps + mrow*72 + kk*32 + quad*8);
        shortx8 bf = *(const shortx8*)(vsT + (w*16 + mrow)*72 + kk*32 + quad*8);
        O = __builtin_amdgcn_mfma_f32_16x16x32_bf16(af, bf, O, 0, 0, 0);
      }
      __syncthreads();   // before next chunk overwrites ks/vsT/Ps/redv
    }
    L += __shfl_xor(L, 16, 64);
    L += __shfl_xor(L, 32, 64);
    if (lane < 16) redv[1][w][lane] = L;
    __syncthreads();
    #pragma unroll
    for (int r2=0;r2<4;++r2){
      int m = quad*4 + r2;
      float Ls = redv[1][0][m] + redv[1][1][m] + redv[1][2][m] + redv[1][3][m];
      float v = O[r2] / (Ls + 1e-16f);
      agg_m[(size_t)(b*64 + g*16 + m)*512 + h*64 + w*16 + mrow] = f2bf(geluf(v));
    }
  } else {
    // ---- op-side: S-GEMM + wave-parallel softmax + PV, QBLK=64 ----
    u16* smem16 = (u16*)smem;
    u16* As = smem16;                        // 64*72 u16
    u16* Bs = smem16 + 4608;                 // 64*72 u16
    float* Sbuf = (float*)smem;              // 64*66 f32, aliases As/Bs after S-GEMM
    u16* P   = smem16 + 9216;                // 64*72 u16
    u16* v1T = smem16 + 13824;               // 64*72 u16
    float* wpreS = (float*)(smem + 36864);   // 64 f32
    float* linvS = (float*)(smem + 37120);   // 64 f32
    int id2 = id - 256;
    int bh = id2 >> 4; int b = bh >> 3, h = bh & 7;
    int n0 = (id2 & 15) * 64;
    int wm = wave & 1, wn = wave >> 1;
    int srow = tid >> 2, scol = (tid & 3) * 16;
    float p1 = prel[8 + h] * 0.125f;
    { // q_op rows n0..n0+63
      const u16* src = qkv_op + (size_t)(b*1024 + n0 + srow)*CQ + h*64 + scol;
      *(shortx8*)(As + srow*72 + scol)     = *(const shortx8*)(src);
      *(shortx8*)(As + srow*72 + scol + 8) = *(const shortx8*)(src + 8);
    }
    { // k1 (64 machines)
      const u16* src = qkv_m + (size_t)(b*64 + srow)*CM + 512 + h*64 + scol;
      *(shortx8*)(Bs + srow*72 + scol)     = *(const shortx8*)(src);
      *(shortx8*)(Bs + srow*72 + scol + 8) = *(const shortx8*)(src + 8);
    }
    { // v1^T: v1T[d][m] = v1[m][d]
      const u16* src = qkv_m + (size_t)(b*64 + srow)*CM + 1024 + h*64 + scol;
      shortx8 v0 = *(const shortx8*)(src);
      shortx8 v1 = *(const shortx8*)(src + 8);
      #pragma unroll
      for (int e=0;e<8;++e){ v1T[(scol+e)*72 + srow] = (u16)v0[e]; v1T[(scol+8+e)*72 + srow] = (u16)v1[e]; }
    }
    __syncthreads();
    floatx4 acc[2][2];
    #pragma unroll
    for (int a=0;a<2;++a){ acc[a][0] = (floatx4){0,0,0,0}; acc[a][1] = (floatx4){0,0,0,0}; }
    #pragma unroll
    for (int ks=0; ks<2; ++ks){
      shortx8 af[2], bf[2];
      #pragma unroll
      for (int mt=0;mt<2;++mt) af[mt] = *(const shortx8*)(As + (wm*32 + mt*16 + mrow)*72 + ks*32 + quad*8);
      #pragma unroll
      for (int nt=0;nt<2;++nt) bf[nt] = *(const shortx8*)(Bs + (wn*32 + nt*16 + mrow)*72 + ks*32 + quad*8);
      #pragma unroll
      for (int mt=0;mt<2;++mt)
        #pragma unroll
        for (int nt=0;nt<2;++nt)
          acc[mt][nt] = __builtin_amdgcn_mfma_f32_16x16x32_bf16(af[mt], bf[nt], acc[mt][nt], 0, 0, 0);
    }
    __syncthreads();
    #pragma unroll
    for (int mt=0;mt<2;++mt){
      #pragma unroll
      for (int nt=0;nt<2;++nt){
        int m = wn*32 + nt*16 + mrow;
        #pragma unroll
        for (int r2=0;r2<4;++r2){
          int nl = wm*32 + mt*16 + quad*4 + r2;
          Sbuf[nl*66 + m] = acc[mt][nt][r2] * p1;
        }
      }
    }
    __syncthreads();
    { // wave-parallel softmax: 4 threads per row
      int row = srow;
      int mb  = scol;
      int n_g = b*1024 + n0 + row;
      int nl  = n0 + row;
      float sp = -1e30f;
      if (nl > 0){
        float p0 = prel[h] * 0.125f;
        const u16* qp = qkv_op + (size_t)n_g*CQ + h*64 + mb;
        const u16* kp = qkv_op + (size_t)(n_g-1)*CQ + 512 + h*64 + mb;
        shortx8 qa = *(const shortx8*)(qp), qb2 = *(const shortx8*)(qp + 8);
        shortx8 ka = *(const shortx8*)(kp), kb2 = *(const shortx8*)(kp + 8);
        float d = 0.f;
        #pragma unroll
        for (int e=0;e<8;++e) d += bf2f((u16)qa[e])*bf2f((u16)ka[e]) + bf2f((u16)qb2[e])*bf2f((u16)kb2[e]);
        d += __shfl_xor(d, 1, 64);
        d += __shfl_xor(d, 2, 64);
        sp = d * p0;
      }
      const float* crow = Cn + (size_t)n_g*64 + mb;
      float cv[16];
      float mx = sp;
      #pragma unroll
      for (int j=0;j<16;++j){
        cv[j] = crow[j];
        if (cv[j] > 0.f) mx = fmaxf(mx, Sbuf[row*66 + mb + j]);
      }
      mx = fmaxf(mx, __shfl_xor(mx, 1, 64));
      mx = fmaxf(mx, __shfl_xor(mx, 2, 64));
      float L = 0.f;
      #pragma unroll
      for (int j=0;j<16;j+=4){
        shortx4 pv;
        #pragma unroll
        for (int e=0;e<4;++e){
          float w = (cv[j+e] > 0.f) ? cv[j+e]*expf(Sbuf[row*66 + mb + j + e] - mx) : 0.f;
          L += w;
          pv[e] = (short)f2bf(w);
        }
        *(shortx4*)(P + row*72 + mb + j) = pv;
      }
      L += __shfl_xor(L, 1, 64);
      L += __shfl_xor(L, 2, 64);
      float ep = (nl > 0) ? expf(sp - mx) : 0.f;
      L += ep;
      if ((tid & 3) == 0){ wpreS[row] = ep; linvS[row] = 1.f/(L + 1e-16f); }
    }
    __syncthreads();
    floatx4 po[2][2];
    #pragma unroll
    for (int a=0;a<2;++a){ po[a][0] = (floatx4){0,0,0,0}; po[a][1] = (floatx4){0,0,0,0}; }
    #pragma unroll
    for (int ks=0; ks<2; ++ks){
      shortx8 paf[2], pbf[2];
      #pragma unroll
      for (int mt=0;mt<2;++mt) paf[mt] = *(const shortx8*)(P + (wm*32 + mt*16 + mrow)*72 + ks*32 + quad*8);
      #pragma unroll
      for (int nt=0;nt<2;++nt) pbf[nt] = *(const shortx8*)(v1T + (wn*32 + nt*16 + mrow)*72 + ks*32 + quad*8);
      #pragma unroll
      for (int mt=0;mt<2;++mt)
        #pragma unroll
        for (int nt=0;nt<2;++nt)
          po[mt][nt] = __builtin_amdgcn_mfma_f32_16x16x32_bf16(paf[mt], pbf[nt], po[mt][nt], 0, 0, 0);
    }
    #pragma unroll
    for (int mt=0;mt<2;++mt){
      #pragma unroll
      for (int nt=0;nt<2;++nt){
        int d = wn*32 + nt*16 + mrow;
        #pragma unroll
        for (int r2=0;r2<4;++r2){
          int rl = wm*32 + mt*16 + quad*4 + r2;
          int n = n0 + rl;
          size_t ng = (size_t)b*1024 + n;
          float v = po[mt][nt][r2];
          if (n > 0) v += wpreS[rl] * bf2f(qkv_op[(ng-1)*CQ + 1024 + h*64 + d]);
          v *= linvS[rl];
          agg_op[ng*512 + h*64 + d] = f2bf(geluf(v));
        }
      }
    }
  }
}

// ---------------- means: partials (no atomics) + final merged ----------------
__global__ __launch_bounds__(512) void meanj_part_k(const float* __restrict__ xo, float* scratchJ){
  int b = blockIdx.x, chunk = blockIdx.y, f = threadIdx.x;
  float s = 0.f;
  for (int r=0;r<128;++r){
    int row = b*1024 + chunk*128 + r;
    s += xo[(size_t)row*512 + f];
  }
  scratchJ[(b*8 + chunk)*512 + f] = s;
}
__global__ __launch_bounds__(512) void mean2_k(const float* __restrict__ scratchJ, float* __restrict__ out){
  int i = blockIdx.x*512 + threadIdx.x;   // 8192
  if (i < 4096){
    int b = i >> 9, f = i & 511;
    float s = 0.f;
    #pragma unroll
    for (int c=0;c<8;++c) s += scratchJ[(b*8+c)*512 + f];
    out[4456448 + i] = s * (1.f/1024.f);
  } else {
    int j = i - 4096;
    int b = j >> 9, f = j & 511;
    float s = 0.f;
    for (int r=0;r<64;++r) s += out[(size_t)TOPC + (size_t)(b*64+r)*512 + f];
    out[4460544 + j] = s * (1.f/64.f);
  }
}

extern "C" void kernel_launch(void* const* d_in, const int* in_sizes, int n_in,
                              void* d_out, int out_size, void* d_ws, size_t ws_size,
                              hipStream_t stream){
  const float* op_x      = (const float*)d_in[0];
  const float* machine_x = (const float*)d_in[1];
  const float* W_emb_op  = (const float*)d_in[2];
  const float* b_emb_op  = (const float*)d_in[3];
  const float* W_emb_m   = (const float*)d_in[4];
  const float* b_emb_m   = (const float*)d_in[5];
  const float* opn_w     = (const float*)d_in[6];
  const float* opn_b     = (const float*)d_in[7];
  const float* mn_w      = (const float*)d_in[8];
  const float* mn_b      = (const float*)d_in[9];
  const float* Wk        = (const float*)d_in[10];
  const float* bk        = (const float*)d_in[11];
  const float* Wq        = (const float*)d_in[12];
  const float* bq        = (const float*)d_in[13];
  const float* Wv        = (const float*)d_in[14];
  const float* bv        = (const float*)d_in[15];
  const float* A_rel     = (const float*)d_in[16];
  const float* M_rel     = (const float*)d_in[17];
  const float* p_rel     = (const float*)d_in[18];
  const float* W_out     = (const float*)d_in[19];
  const float* b_out     = (const float*)d_in[20];
  const float* skip      = (const float*)d_in[21];
  const float* ln_w      = (const float*)d_in[22];
  const float* ln_b      = (const float*)d_in[23];
  const int* s1          = (const int*)d_in[25];
  float* out = (float*)d_out;

  char* ws = (char*)d_ws;
  size_t off = 0;
  auto alloc = [&](size_t bytes)->void*{
    void* p = ws + off;
    off = (off + bytes + 255) & ~(size_t)255;
    return p;
  };
  float* pstat     = (float*)alloc(8192*4);       // A: op@0(2048f) m@2048 ; B: op@4096 m@6144
  float* scratchJ  = (float*)alloc(32768*4);
  float* Ct        = (float*)alloc((size_t)NMS*1024*4);
  float* Cn        = (float*)alloc((size_t)NOPS*64*4);
  float* x_op      = (float*)alloc((size_t)NOPS*512*4);   // rolling pre-LN tensor (y, o0, o1, o2)
  u16*   x_op_bf   = (u16*)  alloc((size_t)NOPS*512*2);   // bf16 of same
  float* x_m       = (float*)alloc((size_t)NMS*512*4);
  u16*   x_m_bf    = (u16*)  alloc((size_t)NMS*512*2);
  u16*   qkv_op    = (u16*)  alloc((size_t)NOPS*CQ*2);
  u16*   qkv_m     = (u16*)  alloc((size_t)NMS*CM*2);
  u16*   agg_op    = (u16*)  alloc((size_t)NOPS*512*2);
  u16*   agg_m     = (u16*)  alloc((size_t)NMS*512*2);
  u16*   Wc_op_t   = (u16*)  alloc((size_t)3*CQ*512*2);
  float* bias_op   = (float*)alloc((size_t)3*CQ*4);
  u16*   Wc_m_t    = (u16*)  alloc((size_t)3*CM*512*2);
  float* bias_m    = (float*)alloc((size_t)3*CM*4);
  float* u_op      = (float*)alloc((size_t)3*CQ*4);
  float* u_m       = (float*)alloc((size_t)3*CM*4);
  u16*   Wout_t    = (u16*)  alloc((size_t)6*262144*2);
  float* psA   = pstat;          float* psA_m = pstat + 2048;
  float* psB   = pstat + 4096;   float* psB_m = pstat + 6144;

  // mega setup (long-pole segments first), then the weight fold
  setup_all_k<<<4700,256,0,stream>>>(s1, Ct, Cn, bq, bias_op, bias_m, bk, bv, A_rel, M_rel,
                                     W_out, Wq, Wout_t, Wc_op_t, Wc_m_t, Wk, Wv,
                                     op_x, W_emb_op, b_emb_op, x_op, x_op_bf,
                                     machine_x, W_emb_m, b_emb_m, x_m, x_m_bf, psA, psA_m);
  foldk<<<192,256,0,stream>>>(Wc_op_t, Wc_m_t, bias_op, bias_m, u_op, u_m,
                              opn_w, opn_b, mn_w, mn_b, ln_w, ln_b);

  for (int l=0; l<3; ++l){
    // ping-pong: layer reads stats of prev pre-LN tensor, gate writes new partials
    float *psR, *psR_m, *psW, *psW_m; int npo, npm;
    if (l == 0){ psR=psA; psR_m=psA_m; psW=psB; psW_m=psB_m; npo=1024; npm=128; }
    else if (l == 1){ psR=psB; psR_m=psB_m; psW=psA; psW_m=psA_m; npo=256; npm=16; }
    else { psR=psA; psR_m=psA_m; psW=psB; psW_m=psB_m; npo=256; npm=16; }
    const float* lnw_o = (l==0) ? opn_w : ln_w + (l-1)*512;
    const float* lnb_o = (l==0) ? opn_b : ln_b + (l-1)*512;
    const float* lnw_m2 = (l==0) ? mn_w : ln_w + (l-1)*512;
    const float* lnb_m2 = (l==0) ? mn_b : ln_b + (l-1)*512;
    // QKV GEMM with LN folded (reads pre-LN bf16 A + stats)
    gemm8_k<<<332,512,131136,stream>>>(x_op_bf, Wc_op_t + (size_t)l*CQ*512, bias_op + l*CQ, u_op + l*CQ,
                                       qkv_op, CQ, 10, 320,
                                       x_m_bf, Wc_m_t + (size_t)l*CM*512, bias_m + l*CM, u_m + l*CM,
                                       qkv_m, CM, 6,
                                       psR, npo, psR_m, npm);
    // merged attention: machine flash first (long pole), op-side fills around it
    attn_k<<<1280,256,0,stream>>>(qkv_op, qkv_m, p_rel + l*24, Cn, Ct, agg_op, agg_m);
    // W_out GEMM + gated residual (LN-affine) -> new pre-LN tensor (f32+bf16) + stats
    gemmgate2_k<<<272,256,0,stream>>>(agg_op, Wout_t + (size_t)(l*2+0)*262144, x_op,
                                      b_out + (size_t)(l*2+0)*512, skip + l*2+0,
                                      lnw_o, lnb_o, x_op, x_op_bf, psW, 256,
                                      agg_m, Wout_t + (size_t)(l*2+1)*262144, x_m,
                                      b_out + (size_t)(l*2+1)*512, skip + l*2+1,
                                      lnw_m2, lnb_m2, x_m, x_m_bf, psW_m,
                                      psR, npo, psR_m, npm);
  }

  // final graph-LN -> out (stats in psB from layer 2)
  ln2_k<<<1152,256,0,stream>>>(x_op, out, ln_w + 1024, ln_b + 1024,
                               x_m, out + TOPC, ln_w + 1024, ln_b + 1024,
                               psB, psB_m, 256, 16);

  meanj_part_k<<<dim3(8,8),512,0,stream>>>(out, scratchJ);
  mean2_k<<<16,512,0,stream>>>(scratchJ, out);
}

// Round 12
// 505.036 us; speedup vs baseline: 1.1651x; 1.0362x over previous
//
#include <hip/hip_runtime.h>

typedef unsigned short u16;
typedef __attribute__((ext_vector_type(4))) float floatx4;
typedef __attribute__((ext_vector_type(8))) short shortx8;
typedef __attribute__((ext_vector_type(4))) short shortx4;

#define NOPS 8192
#define NMS  512
#define CQ   2560   // op qkv cols: q | k0 | v0 | k2 | v2
#define CM   1536   // machine qkv cols: q | k1 | v1
#define TOPC (NOPS*512)
#define TMC  (NMS*512)

__device__ __forceinline__ float bf2f(u16 u){ return __uint_as_float(((unsigned)u)<<16); }
__device__ __forceinline__ u16 f2bf(float f){
  unsigned u = __float_as_uint(f);
  u += 0x7FFFu + ((u>>16)&1u);
  return (u16)(u>>16);
}
__device__ __forceinline__ float wred(float v){
  #pragma unroll
  for (int o=32;o;o>>=1) v += __shfl_xor(v,o,64);
  return v;
}
__device__ __forceinline__ float geluf(float x){
  return 0.5f*x*(1.f+erff(x*0.70710678118654752f));
}
// block (s,s2) reduction -> one pair at pstat[slot]
__device__ __forceinline__ void block_stat_out2(float s, float s2, float* pstat, int slot){
  __shared__ float sb[8];
  s = wred(s); s2 = wred(s2);
  int wv = threadIdx.x >> 6;
  if ((threadIdx.x & 63) == 0){ sb[wv*2] = s; sb[wv*2+1] = s2; }
  __syncthreads();
  if (threadIdx.x == 0){
    float a = 0.f, b = 0.f;
    int nw = blockDim.x >> 6;
    for (int i=0;i<nw;++i){ a += sb[i*2]; b += sb[i*2+1]; }
    pstat[slot*2]   = a;
    pstat[slot*2+1] = b;
  }
}

// ---------------- mega setup, LONG-POLE-FIRST ordering, embed vectorized x4 ----------------
// blocks: [0,1152) embed ; [1152,1920) tw ; [1920,2496) combine3 ;
//         [2496,4544) cnt2 ; [4544,4556) qb ; [4556,4700) cbias
__global__ __launch_bounds__(256) void setup_all_k(
    const int* __restrict__ s1, float* __restrict__ Ct, float* __restrict__ Cn,
    const float* __restrict__ bq, float* bias_op, float* bias_m,
    const float* __restrict__ bk, const float* __restrict__ bv,
    const float* __restrict__ Ar, const float* __restrict__ Mr,
    const float* __restrict__ Wout, const float* __restrict__ Wq,
    u16* __restrict__ Wout_t, u16* __restrict__ Wc_op_t, u16* __restrict__ Wc_m_t,
    const float* __restrict__ Wk, const float* __restrict__ Wv,
    const float* __restrict__ Xop, const float* __restrict__ Wop, const float* __restrict__ bop,
    float* __restrict__ Yop, u16* __restrict__ Yop_bf,
    const float* __restrict__ Xm, const float* __restrict__ Wm, const float* __restrict__ bm_,
    float* __restrict__ Ym, u16* __restrict__ Ym_bf,
    float* pstat, float* pstat_m){
  __shared__ __align__(16) char smem[27648];
  int bid = blockIdx.x;
  int tid = threadIdx.x;
  if (bid < 1152){
    // embed (longest blocks first), 4-wide: op [0,1024) / m [1024,1152)
    int eb = bid;
    const float *X, *W, *bias; float *Y, *ps; u16* Yb; int K, total4, nb, lb;
    if (eb < 1024){ X=Xop; W=Wop; bias=bop; Y=Yop; Yb=Yop_bf; ps=pstat;   K=16; total4=TOPC/4; nb=1024; lb=eb; }
    else          { X=Xm;  W=Wm;  bias=bm_; Y=Ym;  Yb=Ym_bf;  ps=pstat_m; K=8;  total4=TMC/4;  nb=128;  lb=eb-1024; }
    float s = 0.f, s2 = 0.f;
    for (int idx = lb*256 + tid; idx < total4; idx += nb*256){
      int n = idx >> 7, f4 = idx & 127;
      floatx4 v = *(const floatx4*)(bias + f4*4);
      const float* xrow = X + n*K;
      for (int c=0;c<K;++c){
        float xc = xrow[c];
        floatx4 wv = *(const floatx4*)(W + c*512 + f4*4);
        #pragma unroll
        for (int e=0;e<4;++e) v[e] += xc*wv[e];
      }
      shortx4 sv;
      #pragma unroll
      for (int e=0;e<4;++e){ sv[e] = (short)f2bf(v[e]); s += v[e]; s2 += v[e]*v[e]; }
      *(floatx4*)(Y + (size_t)idx*4) = v;
      *(shortx4*)(Yb + (size_t)idx*4) = sv;
    }
    block_stat_out2(s, s2, ps, lb);
  } else if (bid < 1920){
    // tw: transpose W_out (6 slabs) + Wq (6 slabs)
    u16 (*t)[65] = (u16(*)[65])smem;
    int id2 = bid - 1152;
    int g = id2 >> 6; int rem = id2 & 63;
    int kb = (rem >> 3) * 64, nb = (rem & 7) * 64;
    const float* s; u16* d;
    if (g < 6){
      s = Wout + (size_t)g*262144;
      d = Wout_t + (size_t)g*262144;
    } else {
      int blk = g - 6; int l = blk >> 1, side = blk & 1;
      s = Wq + (size_t)blk*262144;
      d = side ? (Wc_m_t + (size_t)l*CM*512) : (Wc_op_t + (size_t)l*CQ*512);
    }
    int tx = tid & 63, ty4 = tid >> 6;
    #pragma unroll 4
    for (int p=0;p<16;++p){
      int k = ty4 + p*4;
      t[k][tx] = f2bf(s[(size_t)(kb+k)*512 + nb + tx]);
    }
    __syncthreads();
    #pragma unroll 4
    for (int p=0;p<16;++p){
      int n = ty4 + p*4;
      d[(size_t)(nb+n)*512 + kb + tx] = t[tx][n];
    }
  } else if (bid < 2496){
    // combine3: relation combine via MFMA
    u16* As = (u16*)smem;          // 64*72
    u16* Bs = As + 64*72;          // 128*72
    int id3 = bid - 1920;
    int gx = id3 >> 2;
    int cc0 = (id3 & 3) * 128;
    int l = gx/48; int rem = gx - l*48; int s = rem >> 3; int h = rem & 7;
    int side = (s < 4) ? 0 : 1;
    int r = (s < 4) ? (s+1) : (s-3);
    int useK = side==0 ? (s==0 || s==2) : (s==4);
    int rel  = side==0 ? ((s<2)?0:2) : 1;
    const float* W   = (useK ? Wk : Wv) + (size_t)(l*2+side)*262144;
    const float* Rel = (useK ? Ar : Mr) + ((size_t)(l*3+rel)*8 + h)*4096;
    int h64 = h*64;
    u16* Wt = side ? (Wc_m_t + (size_t)l*CM*512) : (Wc_op_t + (size_t)l*CQ*512);
    int rbase = r*512 + h64;
    int lane = tid & 63, wave = tid >> 6;
    {
      int d = tid >> 2, e0 = (tid & 3) * 16;
      #pragma unroll
      for (int j=0;j<16;++j) As[(e0+j)*72 + d] = f2bf(Rel[d*64 + e0 + j]);
    }
    {
      int ccl = tid >> 1, d0 = (tid & 1) * 32;
      const float* src = W + (size_t)(cc0+ccl)*512 + h64 + d0;
      #pragma unroll
      for (int j=0;j<32;j+=4){
        floatx4 v = *(const floatx4*)(src + j);
        shortx4 sv;
        #pragma unroll
        for (int e=0;e<4;++e) sv[e] = (short)f2bf(v[e]);
        *(shortx4*)(Bs + ccl*72 + d0 + j) = sv;
      }
    }
    __syncthreads();
    int wm = wave & 1, wn = wave >> 1;
    int mrow = lane & 15, quad = lane >> 4;
    floatx4 acc[2][4];
    #pragma unroll
    for (int a=0;a<2;++a)
      #pragma unroll
      for (int b=0;b<4;++b) acc[a][b] = (floatx4){0.f,0.f,0.f,0.f};
    #pragma unroll
    for (int ks=0; ks<2; ++ks){
      shortx8 af[2], bf[4];
      #pragma unroll
      for (int mt=0;mt<2;++mt) af[mt] = *(const shortx8*)(As + (wm*32 + mt*16 + mrow)*72 + ks*32 + quad*8);
      #pragma unroll
      for (int nt=0;nt<4;++nt) bf[nt] = *(const shortx8*)(Bs + (wn*64 + nt*16 + mrow)*72 + ks*32 + quad*8);
      #pragma unroll
      for (int mt=0;mt<2;++mt)
        #pragma unroll
        for (int nt=0;nt<4;++nt)
          acc[mt][nt] = __builtin_amdgcn_mfma_f32_16x16x32_bf16(af[mt], bf[nt], acc[mt][nt], 0, 0, 0);
    }
    #pragma unroll
    for (int mt=0;mt<2;++mt){
      #pragma unroll
      for (int nt=0;nt<4;++nt){
        int ccl = wn*64 + nt*16 + mrow;
        #pragma unroll
        for (int r2=0;r2<4;++r2){
          int e = wm*32 + mt*16 + quad*4 + r2;
          Wt[(size_t)(rbase + e)*512 + cc0 + ccl] = f2bf(acc[mt][nt][r2]);
        }
      }
    }
  } else if (bid < 4544){
    int idx = (bid-2496)*256 + tid;      // 524288
    int n = idx >> 6, l = idx & 63;
    const int* row = s1 + n*8;
    int cnt = 0;
    #pragma unroll
    for (int j=0;j<8;++j) cnt += ((row[j] & 63) == l);
    float f = (float)cnt;
    Cn[(size_t)n*64 + l] = f;
    int b = n >> 10, nl = n & 1023;
    Ct[(size_t)((b<<6) + l)*1024 + nl] = f;
  } else if (bid < 4556){
    int i = (bid-4544)*256 + tid;   // < 3072
    int l = i >> 10, side = (i >> 9) & 1, f = i & 511;
    float v = bq[(l*2+side)*512 + f];
    if (side==0) bias_op[l*CQ + f] = v; else bias_m[l*CM + f] = v;
  } else {
    if (tid >= 64) return;
    int gx = bid - 4556; int e = tid;
    int l = gx/48; int rem = gx - l*48; int s = rem >> 3; int h = rem & 7;
    int side = (s < 4) ? 0 : 1;
    int r = (s < 4) ? (s+1) : (s-3);
    int useK = side==0 ? (s==0 || s==2) : (s==4);
    int rel  = side==0 ? ((s<2)?0:2) : 1;
    const float* bb  = (useK ? bk : bv) + (size_t)(l*2+side)*512 + h*64;
    const float* Rel = (useK ? Ar : Mr) + ((size_t)(l*3+rel)*8 + h)*4096;
    float acc = 0.f;
    for (int d=0; d<64; ++d) acc += bb[d]*Rel[d*64 + e];
    float* bias = side ? (bias_m + l*CM) : (bias_op + l*CQ);
    bias[r*512 + h*64 + e] = acc;
  }
}

// ---------------- LN fold: u=w@Wc, bias+=b@Wc, Wt *= w (in place) ----------------
__global__ __launch_bounds__(256) void foldk(u16* __restrict__ Wc_op_t, u16* __restrict__ Wc_m_t,
                                             float* __restrict__ bias_op, float* __restrict__ bias_m,
                                             float* __restrict__ u_op, float* __restrict__ u_m,
                                             const float* __restrict__ opn_w, const float* __restrict__ opn_b,
                                             const float* __restrict__ mn_w, const float* __restrict__ mn_b,
                                             const float* __restrict__ ln_w, const float* __restrict__ ln_b){
  int bid = blockIdx.x, tid = threadIdx.x;
  int rloc = tid >> 2, t = tid & 3;
  int side, l; u16* Wt; float* bias; float* u;
  if (bid < 120){
    int row = bid*64 + rloc; side = 0; l = row/2560; int j = row - l*2560;
    Wt = Wc_op_t + ((size_t)l*CQ + j)*512; bias = bias_op + l*CQ + j; u = u_op + l*CQ + j;
  } else {
    int row = (bid-120)*64 + rloc; side = 1; l = row/1536; int j = row - l*1536;
    Wt = Wc_m_t + ((size_t)l*CM + j)*512; bias = bias_m + l*CM + j; u = u_m + l*CM + j;
  }
  const float* w = side ? (l==0 ? mn_w : ln_w + (l-1)*512) : (l==0 ? opn_w : ln_w + (l-1)*512);
  const float* b = side ? (l==0 ? mn_b : ln_b + (l-1)*512) : (l==0 ? opn_b : ln_b + (l-1)*512);
  float up = 0.f, vp = 0.f;
  for (int k = t*128; k < t*128 + 128; k += 8){
    shortx8 wv = *(shortx8*)(Wt + k);
    #pragma unroll
    for (int e=0;e<8;++e){
      float x = bf2f((u16)wv[e]);
      float wk = w[k+e];
      up += wk*x; vp += b[k+e]*x;
      wv[e] = (short)f2bf(x*wk);
    }
    *(shortx8*)(Wt + k) = wv;
  }
  up += __shfl_xor(up,1,64); up += __shfl_xor(up,2,64);
  vp += __shfl_xor(vp,1,64); vp += __shfl_xor(vp,2,64);
  if (t == 0){ *u = up; *bias += vp; }
}

// ---------------- final graph-LN apply (used once, writes `out`) ----------------
__global__ __launch_bounds__(256) void ln2_k(const float* __restrict__ src_op, float* __restrict__ dst_op,
                                             const float* __restrict__ w_op, const float* __restrict__ b_op,
                                             const float* __restrict__ src_m, float* __restrict__ dst_m,
                                             const float* __restrict__ w_m, const float* __restrict__ b_m,
                                             const float* __restrict__ pstat, const float* __restrict__ pstat_m,
                                             int nbo, int nbm){
  int bid = blockIdx.x;
  const float *src, *w, *b, *ps; float* dst; int total4, nb, lb, nblk; float inv_n;
  if (bid < 1024){ src=src_op; dst=dst_op; w=w_op; b=b_op; ps=pstat;
                   total4=TOPC/4; nb=1024; lb=bid; nblk=nbo; inv_n=1.f/TOPC; }
  else           { src=src_m;  dst=dst_m;  w=w_m;  b=b_m;  ps=pstat_m;
                   total4=TMC/4;  nb=128;  lb=bid-1024; nblk=nbm; inv_n=1.f/TMC; }
  __shared__ float sb[8];
  __shared__ float mr[2];
  float s = 0.f, s2 = 0.f;
  for (int i = threadIdx.x; i < nblk; i += 256){ s += ps[2*i]; s2 += ps[2*i+1]; }
  s = wred(s); s2 = wred(s2);
  int wv = threadIdx.x >> 6;
  if ((threadIdx.x & 63) == 0){ sb[wv*2] = s; sb[wv*2+1] = s2; }
  __syncthreads();
  if (threadIdx.x == 0){
    float a = 0.f, bsum = 0.f;
    for (int i=0;i<4;++i){ a += sb[i*2]; bsum += sb[i*2+1]; }
    float mean = a * inv_n;
    float var  = fmaxf(bsum * inv_n - mean*mean, 0.f);
    mr[0] = mean;
    mr[1] = 1.f/(sqrtf(var) + 1e-5f);
  }
  __syncthreads();
  float mean = mr[0], rinv = mr[1];
  const floatx4* s4 = (const floatx4*)src;
  floatx4* d4 = (floatx4*)dst;
  const floatx4* w4 = (const floatx4*)w;
  const floatx4* b4 = (const floatx4*)b;
  for (int i = lb*256 + threadIdx.x; i < total4; i += nb*256){
    int f = i & 127;
    floatx4 v = s4[i], wv2 = w4[f], bv = b4[f];
    #pragma unroll
    for (int e=0;e<4;++e) v[e] = (v[e]-mean)*rinv*wv2[e] + bv[e];
    d4[i] = v;
  }
}

// ---------------- W_out GEMM + gated residual (LN-affine on x) + f32/bf16 out + LN partials ----------------
__device__ __forceinline__ void gemm_gate_core(u16* As, u16* Bs, float* stb,
                                               const u16* __restrict__ A, const u16* __restrict__ Bt,
                                               const float* __restrict__ xr, const float* __restrict__ bo,
                                               const float* __restrict__ sk,
                                               const float* __restrict__ lnw, const float* __restrict__ lnb,
                                               const float* __restrict__ psr, int np, float inv_n,
                                               float* __restrict__ Y, u16* __restrict__ Ybf,
                                               float* pstat, int slot, int bx, int by){
  const int tid = threadIdx.x;
  const int lane = tid & 63, wave = tid >> 6;
  // ---- stats of previous-layer pre-LN tensor ----
  {
    float s = 0.f, s2 = 0.f;
    for (int i = tid; i < np; i += 256){ s += psr[2*i]; s2 += psr[2*i+1]; }
    s = wred(s); s2 = wred(s2);
    if (lane == 0){ stb[wave*2] = s; stb[wave*2+1] = s2; }
    __syncthreads();
    if (tid == 0){
      float a = 0.f, bb = 0.f;
      for (int i=0;i<4;++i){ a += stb[2*i]; bb += stb[2*i+1]; }
      float mean = a * inv_n;
      float var = fmaxf(bb * inv_n - mean*mean, 0.f);
      stb[8] = mean;
      stb[9] = 1.f/(sqrtf(var) + 1e-5f);
    }
    __syncthreads();
  }
  const float mean = stb[8], rinv = stb[9];
  const int bm = by * 128, bn = bx * 128;
  const int wm = wave & 1, wn = wave >> 1;
  const int mrow = lane & 15, quad = lane >> 4;
  const u16* Ab = A + (size_t)bm*512;
  const u16* Bb = Bt + (size_t)bn*512;
  floatx4 acc[4][4];
  #pragma unroll
  for (int a=0;a<4;++a)
    #pragma unroll
    for (int b=0;b<4;++b) acc[a][b] = (floatx4){0.f,0.f,0.f,0.f};
  const int r0 = tid >> 2, c0 = (tid & 3) * 8;
  const int r1 = (tid+256) >> 2, c1 = ((tid+256) & 3) * 8;
  const int lds0 = wave*512;
  const int lds1 = wave*512 + 2048;
  for (int k0 = 0; k0 < 512; k0 += 32){
    __builtin_amdgcn_global_load_lds((const __attribute__((address_space(1))) void*)(Ab + (size_t)r0*512 + k0 + c0),
                                     (__attribute__((address_space(3))) void*)(As + lds0), 16, 0, 0);
    __builtin_amdgcn_global_load_lds((const __attribute__((address_space(1))) void*)(Ab + (size_t)r1*512 + k0 + c1),
                                     (__attribute__((address_space(3))) void*)(As + lds1), 16, 0, 0);
    __builtin_amdgcn_global_load_lds((const __attribute__((address_space(1))) void*)(Bb + (size_t)r0*512 + k0 + c0),
                                     (__attribute__((address_space(3))) void*)(Bs + lds0), 16, 0, 0);
    __builtin_amdgcn_global_load_lds((const __attribute__((address_space(1))) void*)(Bb + (size_t)r1*512 + k0 + c1),
                                     (__attribute__((address_space(3))) void*)(Bs + lds1), 16, 0, 0);
    __syncthreads();
    shortx8 af[4], bf[4];
    #pragma unroll
    for (int mt=0;mt<4;++mt) af[mt] = *(const shortx8*)(As + (wm*64 + mt*16 + mrow)*32 + quad*8);
    #pragma unroll
    for (int nt=0;nt<4;++nt) bf[nt] = *(const shortx8*)(Bs + (wn*64 + nt*16 + mrow)*32 + quad*8);
    #pragma unroll
    for (int mt=0;mt<4;++mt)
      #pragma unroll
      for (int nt=0;nt<4;++nt)
        acc[mt][nt] = __builtin_amdgcn_mfma_f32_16x16x32_bf16(af[mt], bf[nt], acc[mt][nt], 0, 0, 0);
    __syncthreads();
  }
  float g = 1.f/(1.f+expf(-(*sk)));
  float s = 0.f, s2 = 0.f;
  #pragma unroll
  for (int mt=0;mt<4;++mt){
    #pragma unroll
    for (int nt=0;nt<4;++nt){
      int col = bn + wn*64 + nt*16 + mrow;
      float bval = bo[col];
      float lw = lnw[col]*rinv, lb = lnb[col];
      #pragma unroll
      for (int r2=0;r2<4;++r2){
        int row = bm + wm*64 + mt*16 + quad*4 + r2;
        float v = acc[mt][nt][r2] + bval;
        float xv = (xr[(size_t)row*512 + col] - mean)*lw + lb;   // x = LN(prev)
        float o = g*v + (2.f-g)*xv;
        Y[(size_t)row*512 + col] = o;
        Ybf[(size_t)row*512 + col] = f2bf(o);
        s += o; s2 += o*o;
      }
    }
  }
  block_stat_out2(s, s2, pstat, slot);
}
__global__ __launch_bounds__(256) void gemmgate2_k(
    const u16* A1, const u16* B1, const float* x1, const float* bo1, const float* sk1,
    const float* lnw1, const float* lnb1, float* Y1, u16* Yb1, float* ps1w, int nblk1,
    const u16* A2, const u16* B2, const float* x2, const float* bo2, const float* sk2,
    const float* lnw2, const float* lnb2, float* Y2, u16* Yb2, float* ps2w,
    const float* ps1r, int np1, const float* ps2r, int np2){
  __shared__ u16 As[128*32];
  __shared__ u16 Bs[128*32];
  __shared__ float stb[12];
  int id = blockIdx.x;
  if (id < nblk1)
    gemm_gate_core(As, Bs, stb, A1, B1, x1, bo1, sk1, lnw1, lnb1, ps1r, np1, 1.f/TOPC,
                   Y1, Yb1, ps1w, id, id % 4, id / 4);
  else {
    int j = id - nblk1;
    gemm_gate_core(As, Bs, stb, A2, B2, x2, bo2, sk2, lnw2, lnb2, ps2r, np2, 1.f/TMC,
                   Y2, Yb2, ps2w, j, j % 4, j / 4);
  }
}

// ---------------- 256x256 8-phase GEMM (QKV projections), K=512, LN folded ----------------
__device__ __forceinline__ void stage_half8(const u16* __restrict__ src, int kc, u16* region, int tid){
  int wave = tid >> 6;
  #pragma unroll
  for (int j=0;j<2;++j){
    int idx = j*512 + tid;
    int row = idx >> 2, qp2 = idx & 3;
    int qs = qp2 ^ (((row >> 3) & 1) << 1);   // st_16x32 pre-swizzled global source
    __builtin_amdgcn_global_load_lds(
      (const __attribute__((address_space(1))) void*)(src + (size_t)row*512 + kc + qs*8),
      (__attribute__((address_space(3))) void*)(region + (j*512 + wave*64)*8),
      16, 0, 0);
  }
}

#define MFMA_QUAD(MH) do { \
  __builtin_amdgcn_s_barrier(); \
  asm volatile("s_waitcnt lgkmcnt(0)" ::: "memory"); \
  __builtin_amdgcn_sched_barrier(0); \
  __builtin_amdgcn_s_setprio(1); \
  _Pragma("unroll") \
  for (int mt=0;mt<4;++mt){ \
    _Pragma("unroll") \
    for (int nt=0;nt<4;++nt) \
      acc[(MH)*4+mt][nt] = __builtin_amdgcn_mfma_f32_16x16x32_bf16(af[mt], bf[nt], acc[(MH)*4+mt][nt], 0, 0, 0); \
  } \
  __builtin_amdgcn_s_setprio(0); \
} while(0)

__global__ __launch_bounds__(512, 2) void gemm8_k(
    const u16* __restrict__ A1, const u16* __restrict__ B1, const float* __restrict__ bias1,
    const float* __restrict__ u1, u16* __restrict__ C1, int N1, int nbx1, int nblk1,
    const u16* __restrict__ A2, const u16* __restrict__ B2, const float* __restrict__ bias2p,
    const float* __restrict__ u2, u16* __restrict__ C2, int N2, int nbx2,
    const float* __restrict__ ps1, int np1, const float* __restrict__ ps2, int np2){
  extern __shared__ u16 lds[];      // 131072 B staging + 64 B stats scratch
  float* statsh = (float*)(lds + 65536);
  int id = blockIdx.x;
  const u16 *A, *Bt; const float *bias, *uvec, *ps; u16* C; int N, bx, by, np; float inv_n;
  if (id < nblk1){
    int xcd = id & 7, loc = id >> 3;
    int wg = xcd * (nblk1 >> 3) + loc;
    A=A1; Bt=B1; bias=bias1; uvec=u1; C=C1; N=N1; bx=wg%nbx1; by=wg/nbx1;
    ps=ps1; np=np1; inv_n=1.f/TOPC;
  }
  else { int j=id-nblk1; A=A2; Bt=B2; bias=bias2p; uvec=u2; C=C2; N=N2; bx=j%nbx2; by=j/nbx2;
    ps=ps2; np=np2; inv_n=1.f/TMC; }
  const int tid = threadIdx.x, lane = tid & 63, wave = tid >> 6;
  // ---- stats (mean/rinv of pre-LN A tensor) ----
  {
    float s = 0.f, s2 = 0.f;
    for (int i = tid; i < np; i += 512){ s += ps[2*i]; s2 += ps[2*i+1]; }
    s = wred(s); s2 = wred(s2);
    if (lane == 0){ statsh[wave*2] = s; statsh[wave*2+1] = s2; }
    __syncthreads();
    if (tid == 0){
      float a = 0.f, bb = 0.f;
      for (int i=0;i<8;++i){ a += statsh[2*i]; bb += statsh[2*i+1]; }
      float mean = a * inv_n;
      float var = fmaxf(bb * inv_n - mean*mean, 0.f);
      statsh[16] = mean;
      statsh[17] = 1.f/(sqrtf(var) + 1e-5f);
    }
    __syncthreads();
  }
  const float mean = statsh[16], rinv = statsh[17];
  const int wm = wave & 1, wn = wave >> 1;
  const int mrow = lane & 15, quad = lane >> 4;
  const int qp = quad ^ ((mrow & 8) ? 2 : 0);
  const u16* Ab = A + (size_t)(by*256)*512;
  const u16* Bb = Bt + (size_t)(bx*256)*512;

  floatx4 acc[8][4];
  #pragma unroll
  for (int a=0;a<8;++a)
    #pragma unroll
    for (int b=0;b<4;++b) acc[a][b] = (floatx4){0.f,0.f,0.f,0.f};

  stage_half8(Ab, 0,  lds,          tid);
  stage_half8(Bb, 0,  lds + 16384,  tid);
  stage_half8(Ab, 32, lds + 8192,   tid);
  stage_half8(Bb, 32, lds + 24576,  tid);
  stage_half8(Ab, 64, lds + 32768,  tid);
  stage_half8(Bb, 64, lds + 49152,  tid);
  asm volatile("s_waitcnt vmcnt(8)" ::: "memory");
  __builtin_amdgcn_s_barrier();

  for (int t = 0; t < 8; ++t){
    const int s = t & 1;
    u16* Sbase = lds + s*32768;
    u16* Obase = lds + (s^1)*32768;
    const u16* a0 = Sbase + (wm*128 + mrow)*32 + qp*8;
    const u16* b0 = Sbase + 16384 + (wn*64 + mrow)*32 + qp*8;
    const int kc1 = ((t < 7) ? (t+1) : 7)*64 + 32;
    const int kc2 = ((t < 6) ? (t+2) : 7)*64;
    shortx8 af[4], bf[4];

    #pragma unroll
    for (int mt=0;mt<4;++mt) af[mt] = *(const shortx8*)(a0 + mt*512);
    #pragma unroll
    for (int nt=0;nt<4;++nt) bf[nt] = *(const shortx8*)(b0 + nt*512);
    stage_half8(Ab, kc1, Obase + 8192, tid);
    MFMA_QUAD(0);
    __builtin_amdgcn_s_barrier();

    #pragma unroll
    for (int mt=0;mt<4;++mt) af[mt] = *(const shortx8*)(a0 + 2048 + mt*512);
    stage_half8(Bb, kc1, Obase + 24576, tid);
    MFMA_QUAD(1);
    asm volatile("s_waitcnt vmcnt(8)" ::: "memory");
    __builtin_amdgcn_s_barrier();

    #pragma unroll
    for (int mt=0;mt<4;++mt) af[mt] = *(const shortx8*)(a0 + 8192 + mt*512);
    #pragma unroll
    for (int nt=0;nt<4;++nt) bf[nt] = *(const shortx8*)(b0 + 8192 + nt*512);
    stage_half8(Ab, kc2, Sbase, tid);
    MFMA_QUAD(0);
    __builtin_amdgcn_s_barrier();

    #pragma unroll
    for (int mt=0;mt<4;++mt) af[mt] = *(const shortx8*)(a0 + 8192 + 2048 + mt*512);
    stage_half8(Bb, kc2, Sbase + 16384, tid);
    MFMA_QUAD(1);
    asm volatile("s_waitcnt vmcnt(8)" ::: "memory");
    __builtin_amdgcn_s_barrier();
  }

  // epilogue: qkv = rinv*acc + bias2[col] - rinv*mean*u[col]
  const float rm = rinv*mean;
  const int crow0 = by*256 + wm*128 + quad*4;
  const int ccol0 = bx*256 + wn*64 + mrow;
  float bv[4], uv[4];
  #pragma unroll
  for (int nt=0;nt<4;++nt){
    int col = ccol0 + nt*16;
    bv[nt] = bias[col];
    uv[nt] = uvec[col];
  }
  #pragma unroll
  for (int mh=0;mh<2;++mh){
    #pragma unroll
    for (int mt=0;mt<4;++mt){
      int row = crow0 + mh*64 + mt*16;
      #pragma unroll
      for (int nt=0;nt<4;++nt){
        int col = ccol0 + nt*16;
        #pragma unroll
        for (int r2=0;r2<4;++r2)
          C[(size_t)(row+r2)*N + col] = f2bf(rinv*acc[mh*4+mt][nt][r2] + bv[nt] - rm*uv[nt]);
      }
    }
  }
}

// ---------------- merged attention: [0,256) machine ONLINE flash (64-row chunks, 23.5KB LDS);
//                  [256,1280) op-side fused attn. Static smem 37376 -> 4 blocks/CU ----------------
__global__ __launch_bounds__(256) void attn_k(const u16* __restrict__ qkv_op, const u16* __restrict__ qkv_m,
                                              const float* __restrict__ prel, const float* __restrict__ Cn,
                                              const float* __restrict__ Ct,
                                              u16* __restrict__ agg_op, u16* __restrict__ agg_m){
  __shared__ __align__(16) char smem[37376];
  int id = blockIdx.x;
  int tid = threadIdx.x, lane = tid & 63, wave = tid >> 6;
  int mrow = lane & 15, quad = lane >> 4;
  if (id < 256){
    // ---- machine-side ONLINE flash, CH=64 rows/chunk ----
    u16* qs  = (u16*)smem;                 // 16*72 -> [0,2304)
    u16* ks  = (u16*)(smem + 2304);        // 64*72 -> [2304,11520)
    u16* vsT = (u16*)(smem + 11520);       // 64*72 -> [11520,20736)
    u16* Ps  = (u16*)(smem + 20736);       // 16*72 -> [20736,23040)
    float (*redv)[4][16] = (float(*)[4][16])(smem + 23040);  // 2*4*16 f32 -> [23040,23552)
    int g = id & 3; int bh = id >> 2; int b = bh >> 3, h = bh & 7;
    int w = wave;
    float p2 = prel[16 + h] * 0.125f;
    if (tid < 128){
      int r = tid >> 3, cg = (tid & 7) * 8;
      *(shortx8*)(qs + r*72 + cg) = *(const shortx8*)(qkv_m + (size_t)(b*64 + g*16 + r)*CM + h*64 + cg);
    }
    const float* ctbase = Ct + (size_t)(b*64 + g*16 + mrow)*1024;
    float mold_m = -1e30f;                     // running max for P-row mrow
    float mold4[4] = {-1e30f,-1e30f,-1e30f,-1e30f};  // running max for O-rows quad*4+r2
    float L = 0.f;
    floatx4 O = (floatx4){0,0,0,0};
    for (int ch = 0; ch < 16; ++ch){
      int nb = ch*64;
      #pragma unroll
      for (int i=0;i<2;++i){
        int idx = i*256 + tid;
        int r = idx >> 3, cg = (idx & 7) * 8;
        *(shortx8*)(ks + r*72 + cg) =
          *(const shortx8*)(qkv_op + (size_t)(b*1024 + nb + r)*CQ + 1536 + h*64 + cg);
        shortx8 vv = *(const shortx8*)(qkv_op + (size_t)(b*1024 + nb + r)*CQ + 2048 + h*64 + cg);
        #pragma unroll
        for (int e=0;e<8;++e) vsT[(cg+e)*72 + r] = (u16)vv[e];
      }
      __syncthreads();   // ks/vsT (and qs on ch0) visible
      floatx4 sa, cv;
      {
        floatx4 acc = (floatx4){0,0,0,0};
        #pragma unroll
        for (int kk=0; kk<2; ++kk){
          shortx8 af = *(const shortx8*)(ks + (w*16 + mrow)*72 + kk*32 + quad*8);
          shortx8 bf = *(const shortx8*)(qs + mrow*72 + kk*32 + quad*8);
          acc = __builtin_amdgcn_mfma_f32_16x16x32_bf16(af, bf, acc, 0, 0, 0);
        }
        int nloc = w*16 + quad*4;
        cv = *(const floatx4*)(ctbase + nb + nloc);
        #pragma unroll
        for (int r2=0;r2<4;++r2) acc[r2] *= p2;
        sa = acc;
      }
      // masked chunk row-max
      float cm = -1e30f;
      #pragma unroll
      for (int r2=0;r2<4;++r2)
        if (cv[r2] > 0.f) cm = fmaxf(cm, sa[r2]);
      cm = fmaxf(cm, __shfl_xor(cm, 16, 64));
      cm = fmaxf(cm, __shfl_xor(cm, 32, 64));
      if (lane < 16) redv[0][w][lane] = cm;
      __syncthreads();   // redv visible
      float mnew_m = fmaxf(fmaxf(redv[0][0][mrow], redv[0][1][mrow]),
                           fmaxf(redv[0][2][mrow], redv[0][3][mrow]));
      mnew_m = fmaxf(mnew_m, mold_m);
      float sL = expf(mold_m - mnew_m);
      mold_m = mnew_m;
      float sO[4];
      #pragma unroll
      for (int r2=0;r2<4;++r2){
        int r = quad*4 + r2;
        float mn = fmaxf(fmaxf(redv[0][0][r], redv[0][1][r]),
                         fmaxf(redv[0][2][r], redv[0][3][r]));
        mn = fmaxf(mn, mold4[r2]);
        sO[r2] = expf(mold4[r2] - mn);
        mold4[r2] = mn;
      }
      float Lsum = 0.f;
      {
        int nloc = w*16 + quad*4;
        shortx4 pv;
        #pragma unroll
        for (int r2=0;r2<4;++r2){
          float e = (cv[r2] > 0.f) ? cv[r2]*expf(sa[r2] - mnew_m) : 0.f;
          Lsum += e;
          pv[r2] = (short)f2bf(e);
        }
        *(shortx4*)(Ps + mrow*72 + nloc) = pv;
      }
      L = L*sL + Lsum;
      __syncthreads();   // Ps visible (written cross-wave)
      #pragma unroll
      for (int r2=0;r2<4;++r2) O[r2] *= sO[r2];
      #pragma unroll
      for (int kk=0; kk<2; ++kk){
        shortx8 af = *(const shortx8*)(Ps + mrow*72 + kk*32 + quad*8);
        shortx8 bf = *(const shortx8*)(vsT + (w*16 + mrow)*72 + kk*32 + quad*8);
        O = __builtin_amdgcn_mfma_f32_16x16x32_bf16(af, bf, O, 0, 0, 0);
      }
      __syncthreads();   // before next chunk overwrites ks/vsT/Ps/redv
    }
    L += __shfl_xor(L, 16, 64);
    L += __shfl_xor(L, 32, 64);
    if (lane < 16) redv[1][w][lane] = L;
    __syncthreads();
    #pragma unroll
    for (int r2=0;r2<4;++r2){
      int m = quad*4 + r2;
      float Ls = redv[1][0][m] + redv[1][1][m] + redv[1][2][m] + redv[1][3][m];
      float v = O[r2] / (Ls + 1e-16f);
      agg_m[(size_t)(b*64 + g*16 + m)*512 + h*64 + w*16 + mrow] = f2bf(geluf(v));
    }
  } else {
    // ---- op-side: S-GEMM + wave-parallel softmax + PV, QBLK=64 ----
    u16* smem16 = (u16*)smem;
    u16* As = smem16;                        // 64*72 u16
    u16* Bs = smem16 + 4608;                 // 64*72 u16
    float* Sbuf = (float*)smem;              // 64*66 f32, aliases As/Bs after S-GEMM
    u16* P   = smem16 + 9216;                // 64*72 u16
    u16* v1T = smem16 + 13824;               // 64*72 u16
    float* wpreS = (float*)(smem + 36864);   // 64 f32
    float* linvS = (float*)(smem + 37120);   // 64 f32
    int id2 = id - 256;
    int bh = id2 >> 4; int b = bh >> 3, h = bh & 7;
    int n0 = (id2 & 15) * 64;
    int wm = wave & 1, wn = wave >> 1;
    int srow = tid >> 2, scol = (tid & 3) * 16;
    float p1 = prel[8 + h] * 0.125f;
    { // q_op rows n0..n0+63
      const u16* src = qkv_op + (size_t)(b*1024 + n0 + srow)*CQ + h*64 + scol;
      *(shortx8*)(As + srow*72 + scol)     = *(const shortx8*)(src);
      *(shortx8*)(As + srow*72 + scol + 8) = *(const shortx8*)(src + 8);
    }
    { // k1 (64 machines)
      const u16* src = qkv_m + (size_t)(b*64 + srow)*CM + 512 + h*64 + scol;
      *(shortx8*)(Bs + srow*72 + scol)     = *(const shortx8*)(src);
      *(shortx8*)(Bs + srow*72 + scol + 8) = *(const shortx8*)(src + 8);
    }
    { // v1^T: v1T[d][m] = v1[m][d]
      const u16* src = qkv_m + (size_t)(b*64 + srow)*CM + 1024 + h*64 + scol;
      shortx8 v0 = *(const shortx8*)(src);
      shortx8 v1 = *(const shortx8*)(src + 8);
      #pragma unroll
      for (int e=0;e<8;++e){ v1T[(scol+e)*72 + srow] = (u16)v0[e]; v1T[(scol+8+e)*72 + srow] = (u16)v1[e]; }
    }
    __syncthreads();
    floatx4 acc[2][2];
    #pragma unroll
    for (int a=0;a<2;++a){ acc[a][0] = (floatx4){0,0,0,0}; acc[a][1] = (floatx4){0,0,0,0}; }
    #pragma unroll
    for (int ks=0; ks<2; ++ks){
      shortx8 af[2], bf[2];
      #pragma unroll
      for (int mt=0;mt<2;++mt) af[mt] = *(const shortx8*)(As + (wm*32 + mt*16 + mrow)*72 + ks*32 + quad*8);
      #pragma unroll
      for (int nt=0;nt<2;++nt) bf[nt] = *(const shortx8*)(Bs + (wn*32 + nt*16 + mrow)*72 + ks*32 + quad*8);
      #pragma unroll
      for (int mt=0;mt<2;++mt)
        #pragma unroll
        for (int nt=0;nt<2;++nt)
          acc[mt][nt] = __builtin_amdgcn_mfma_f32_16x16x32_bf16(af[mt], bf[nt], acc[mt][nt], 0, 0, 0);
    }
    __syncthreads();
    #pragma unroll
    for (int mt=0;mt<2;++mt){
      #pragma unroll
      for (int nt=0;nt<2;++nt){
        int m = wn*32 + nt*16 + mrow;
        #pragma unroll
        for (int r2=0;r2<4;++r2){
          int nl = wm*32 + mt*16 + quad*4 + r2;
          Sbuf[nl*66 + m] = acc[mt][nt][r2] * p1;
        }
      }
    }
    __syncthreads();
    { // wave-parallel softmax: 4 threads per row
      int row = srow;
      int mb  = scol;
      int n_g = b*1024 + n0 + row;
      int nl  = n0 + row;
      float sp = -1e30f;
      if (nl > 0){
        float p0 = prel[h] * 0.125f;
        const u16* qp = qkv_op + (size_t)n_g*CQ + h*64 + mb;
        const u16* kp = qkv_op + (size_t)(n_g-1)*CQ + 512 + h*64 + mb;
        shortx8 qa = *(const shortx8*)(qp), qb2 = *(const shortx8*)(qp + 8);
        shortx8 ka = *(const shortx8*)(kp), kb2 = *(const shortx8*)(kp + 8);
        float d = 0.f;
        #pragma unroll
        for (int e=0;e<8;++e) d += bf2f((u16)qa[e])*bf2f((u16)ka[e]) + bf2f((u16)qb2[e])*bf2f((u16)kb2[e]);
        d += __shfl_xor(d, 1, 64);
        d += __shfl_xor(d, 2, 64);
        sp = d * p0;
      }
      const float* crow = Cn + (size_t)n_g*64 + mb;
      float cv[16];
      float mx = sp;
      #pragma unroll
      for (int j=0;j<16;++j){
        cv[j] = crow[j];
        if (cv[j] > 0.f) mx = fmaxf(mx, Sbuf[row*66 + mb + j]);
      }
      mx = fmaxf(mx, __shfl_xor(mx, 1, 64));
      mx = fmaxf(mx, __shfl_xor(mx, 2, 64));
      float L = 0.f;
      #pragma unroll
      for (int j=0;j<16;j+=4){
        shortx4 pv;
        #pragma unroll
        for (int e=0;e<4;++e){
          float w = (cv[j+e] > 0.f) ? cv[j+e]*expf(Sbuf[row*66 + mb + j + e] - mx) : 0.f;
          L += w;
          pv[e] = (short)f2bf(w);
        }
        *(shortx4*)(P + row*72 + mb + j) = pv;
      }
      L += __shfl_xor(L, 1, 64);
      L += __shfl_xor(L, 2, 64);
      float ep = (nl > 0) ? expf(sp - mx) : 0.f;
      L += ep;
      if ((tid & 3) == 0){ wpreS[row] = ep; linvS[row] = 1.f/(L + 1e-16f); }
    }
    __syncthreads();
    floatx4 po[2][2];
    #pragma unroll
    for (int a=0;a<2;++a){ po[a][0] = (floatx4){0,0,0,0}; po[a][1] = (floatx4){0,0,0,0}; }
    #pragma unroll
    for (int ks=0; ks<2; ++ks){
      shortx8 paf[2], pbf[2];
      #pragma unroll
      for (int mt=0;mt<2;++mt) paf[mt] = *(const shortx8*)(P + (wm*32 + mt*16 + mrow)*72 + ks*32 + quad*8);
      #pragma unroll
      for (int nt=0;nt<2;++nt) pbf[nt] = *(const shortx8*)(v1T + (wn*32 + nt*16 + mrow)*72 + ks*32 + quad*8);
      #pragma unroll
      for (int mt=0;mt<2;++mt)
        #pragma unroll
        for (int nt=0;nt<2;++nt)
          po[mt][nt] = __builtin_amdgcn_mfma_f32_16x16x32_bf16(paf[mt], pbf[nt], po[mt][nt], 0, 0, 0);
    }
    #pragma unroll
    for (int mt=0;mt<2;++mt){
      #pragma unroll
      for (int nt=0;nt<2;++nt){
        int d = wn*32 + nt*16 + mrow;
        #pragma unroll
        for (int r2=0;r2<4;++r2){
          int rl = wm*32 + mt*16 + quad*4 + r2;
          int n = n0 + rl;
          size_t ng = (size_t)b*1024 + n;
          float v = po[mt][nt][r2];
          if (n > 0) v += wpreS[rl] * bf2f(qkv_op[(ng-1)*CQ + 1024 + h*64 + d]);
          v *= linvS[rl];
          agg_op[ng*512 + h*64 + d] = f2bf(geluf(v));
        }
      }
    }
  }
}

// ---------------- means: partials (no atomics) + final merged ----------------
__global__ __launch_bounds__(512) void meanj_part_k(const float* __restrict__ xo, float* scratchJ){
  int b = blockIdx.x, chunk = blockIdx.y, f = threadIdx.x;
  float s = 0.f;
  for (int r=0;r<128;++r){
    int row = b*1024 + chunk*128 + r;
    s += xo[(size_t)row*512 + f];
  }
  scratchJ[(b*8 + chunk)*512 + f] = s;
}
__global__ __launch_bounds__(512) void mean2_k(const float* __restrict__ scratchJ, float* __restrict__ out){
  int i = blockIdx.x*512 + threadIdx.x;   // 8192
  if (i < 4096){
    int b = i >> 9, f = i & 511;
    float s = 0.f;
    #pragma unroll
    for (int c=0;c<8;++c) s += scratchJ[(b*8+c)*512 + f];
    out[4456448 + i] = s * (1.f/1024.f);
  } else {
    int j = i - 4096;
    int b = j >> 9, f = j & 511;
    float s = 0.f;
    for (int r=0;r<64;++r) s += out[(size_t)TOPC + (size_t)(b*64+r)*512 + f];
    out[4460544 + j] = s * (1.f/64.f);
  }
}

extern "C" void kernel_launch(void* const* d_in, const int* in_sizes, int n_in,
                              void* d_out, int out_size, void* d_ws, size_t ws_size,
                              hipStream_t stream){
  const float* op_x      = (const float*)d_in[0];
  const float* machine_x = (const float*)d_in[1];
  const float* W_emb_op  = (const float*)d_in[2];
  const float* b_emb_op  = (const float*)d_in[3];
  const float* W_emb_m   = (const float*)d_in[4];
  const float* b_emb_m   = (const float*)d_in[5];
  const float* opn_w     = (const float*)d_in[6];
  const float* opn_b     = (const float*)d_in[7];
  const float* mn_w      = (const float*)d_in[8];
  const float* mn_b      = (const float*)d_in[9];
  const float* Wk        = (const float*)d_in[10];
  const float* bk        = (const float*)d_in[11];
  const float* Wq        = (const float*)d_in[12];
  const float* bq        = (const float*)d_in[13];
  const float* Wv        = (const float*)d_in[14];
  const float* bv        = (const float*)d_in[15];
  const float* A_rel     = (const float*)d_in[16];
  const float* M_rel     = (const float*)d_in[17];
  const float* p_rel     = (const float*)d_in[18];
  const float* W_out     = (const float*)d_in[19];
  const float* b_out     = (const float*)d_in[20];
  const float* skip      = (const float*)d_in[21];
  const float* ln_w      = (const float*)d_in[22];
  const float* ln_b      = (const float*)d_in[23];
  const int* s1          = (const int*)d_in[25];
  float* out = (float*)d_out;

  char* ws = (char*)d_ws;
  size_t off = 0;
  auto alloc = [&](size_t bytes)->void*{
    void* p = ws + off;
    off = (off + bytes + 255) & ~(size_t)255;
    return p;
  };
  float* pstat     = (float*)alloc(8192*4);       // A: op@0(2048f) m@2048 ; B: op@4096 m@6144
  float* scratchJ  = (float*)alloc(32768*4);
  float* Ct        = (float*)alloc((size_t)NMS*1024*4);
  float* Cn        = (float*)alloc((size_t)NOPS*64*4);
  float* x_op      = (float*)alloc((size_t)NOPS*512*4);   // rolling pre-LN tensor (y, o0, o1, o2)
  u16*   x_op_bf   = (u16*)  alloc((size_t)NOPS*512*2);   // bf16 of same
  float* x_m       = (float*)alloc((size_t)NMS*512*4);
  u16*   x_m_bf    = (u16*)  alloc((size_t)NMS*512*2);
  u16*   qkv_op    = (u16*)  alloc((size_t)NOPS*CQ*2);
  u16*   qkv_m     = (u16*)  alloc((size_t)NMS*CM*2);
  u16*   agg_op    = (u16*)  alloc((size_t)NOPS*512*2);
  u16*   agg_m     = (u16*)  alloc((size_t)NMS*512*2);
  u16*   Wc_op_t   = (u16*)  alloc((size_t)3*CQ*512*2);
  float* bias_op   = (float*)alloc((size_t)3*CQ*4);
  u16*   Wc_m_t    = (u16*)  alloc((size_t)3*CM*512*2);
  float* bias_m    = (float*)alloc((size_t)3*CM*4);
  float* u_op      = (float*)alloc((size_t)3*CQ*4);
  float* u_m       = (float*)alloc((size_t)3*CM*4);
  u16*   Wout_t    = (u16*)  alloc((size_t)6*262144*2);
  float* psA   = pstat;          float* psA_m = pstat + 2048;
  float* psB   = pstat + 4096;   float* psB_m = pstat + 6144;

  // mega setup (long-pole segments first, embed vectorized), then the weight fold
  setup_all_k<<<4700,256,0,stream>>>(s1, Ct, Cn, bq, bias_op, bias_m, bk, bv, A_rel, M_rel,
                                     W_out, Wq, Wout_t, Wc_op_t, Wc_m_t, Wk, Wv,
                                     op_x, W_emb_op, b_emb_op, x_op, x_op_bf,
                                     machine_x, W_emb_m, b_emb_m, x_m, x_m_bf, psA, psA_m);
  foldk<<<192,256,0,stream>>>(Wc_op_t, Wc_m_t, bias_op, bias_m, u_op, u_m,
                              opn_w, opn_b, mn_w, mn_b, ln_w, ln_b);

  for (int l=0; l<3; ++l){
    // ping-pong: layer reads stats of prev pre-LN tensor, gate writes new partials
    float *psR, *psR_m, *psW, *psW_m; int npo, npm;
    if (l == 0){ psR=psA; psR_m=psA_m; psW=psB; psW_m=psB_m; npo=1024; npm=128; }
    else if (l == 1){ psR=psB; psR_m=psB_m; psW=psA; psW_m=psA_m; npo=256; npm=16; }
    else { psR=psA; psR_m=psA_m; psW=psB; psW_m=psB_m; npo=256; npm=16; }
    const float* lnw_o = (l==0) ? opn_w : ln_w + (l-1)*512;
    const float* lnb_o = (l==0) ? opn_b : ln_b + (l-1)*512;
    const float* lnw_m2 = (l==0) ? mn_w : ln_w + (l-1)*512;
    const float* lnb_m2 = (l==0) ? mn_b : ln_b + (l-1)*512;
    // QKV GEMM with LN folded (reads pre-LN bf16 A + stats)
    gemm8_k<<<332,512,131136,stream>>>(x_op_bf, Wc_op_t + (size_t)l*CQ*512, bias_op + l*CQ, u_op + l*CQ,
                                       qkv_op, CQ, 10, 320,
                                       x_m_bf, Wc_m_t + (size_t)l*CM*512, bias_m + l*CM, u_m + l*CM,
                                       qkv_m, CM, 6,
                                       psR, npo, psR_m, npm);
    // merged attention: machine flash first (long pole), op-side fills around it
    attn_k<<<1280,256,0,stream>>>(qkv_op, qkv_m, p_rel + l*24, Cn, Ct, agg_op, agg_m);
    // W_out GEMM + gated residual (LN-affine) -> new pre-LN tensor (f32+bf16) + stats
    gemmgate2_k<<<272,256,0,stream>>>(agg_op, Wout_t + (size_t)(l*2+0)*262144, x_op,
                                      b_out + (size_t)(l*2+0)*512, skip + l*2+0,
                                      lnw_o, lnb_o, x_op, x_op_bf, psW, 256,
                                      agg_m, Wout_t + (size_t)(l*2+1)*262144, x_m,
                                      b_out + (size_t)(l*2+1)*512, skip + l*2+1,
                                      lnw_m2, lnb_m2, x_m, x_m_bf, psW_m,
                                      psR, npo, psR_m, npm);
  }

  // final graph-LN -> out (stats in psB from layer 2)
  ln2_k<<<1152,256,0,stream>>>(x_op, out, ln_w + 1024, ln_b + 1024,
                               x_m, out + TOPC, ln_w + 1024, ln_b + 1024,
                               psB, psB_m, 256, 16);

  meanj_part_k<<<dim3(8,8),512,0,stream>>>(out, scratchJ);
  mean2_k<<<16,512,0,stream>>>(scratchJ, out);
}